// Round 1
// baseline (1089.315 us; speedup 1.0000x reference)
//
#include <hip/hip_runtime.h>

// MPNN: edge MLP (131->128->64) + scatter-mean + node MLP (128->128->64)
// N=50000, E=800000, all fp32. Round 1: correctness-first fp32 baseline,
// register-tiled MLPs with LDS edge staging, atomic scatter-add.

#define EB 32   // edges per block
#define NB 32   // nodes per block

__global__ __launch_bounds__(256) void mpnn_edge_kernel(
    const float* __restrict__ x, const float* __restrict__ pos,
    const int* __restrict__ ei0, const int* __restrict__ ei1,
    const float* __restrict__ W1, const float* __restrict__ b1,
    const float* __restrict__ W2, const float* __restrict__ b2,
    float* __restrict__ summed, float* __restrict__ counts, int E)
{
    __shared__ float s_in[EB][132];  // 131 used (pad to 132 floats; 16B-aligned rows)
    __shared__ float s_h[EB][132];   // 128 used
    __shared__ int   s_idx[EB];

    const int tid  = threadIdx.x;
    const int base = blockIdx.x * EB;
    const int wv   = tid >> 6;
    const int lane = tid & 63;

    // ---- stage msg_in = [x_i, x_j - x_i, pos_j - pos_i] into LDS
    for (int e = wv; e < EB; e += 4) {
        const int ei = base + e;
        if (ei < E) {
            const int i = ei0[ei];
            const int j = ei1[ei];
            const float xi = x[(size_t)i * 64 + lane];
            const float xj = x[(size_t)j * 64 + lane];
            s_in[e][lane]      = xi;
            s_in[e][64 + lane] = xj - xi;
            if (lane < 3)
                s_in[e][128 + lane] = pos[(size_t)j * 3 + lane] - pos[(size_t)i * 3 + lane];
            if (lane == 0) s_idx[e] = i;
        } else {
            s_in[e][lane]      = 0.f;
            s_in[e][64 + lane] = 0.f;
            if (lane < 3) s_in[e][128 + lane] = 0.f;
            if (lane == 0) s_idx[e] = -1;
        }
    }
    __syncthreads();

    // ---- layer 1: hmsg = relu(msg_in @ W1 + b1)   K=131, 128 cols
    {
        const int cg = tid & 31;   // cols 4*cg .. 4*cg+3
        const int er = tid >> 5;   // edges er + 8*t, t=0..3
        float acc[4][4];
        const float4 bb = *(const float4*)(b1 + 4 * cg);
        #pragma unroll
        for (int t = 0; t < 4; ++t) {
            acc[t][0] = bb.x; acc[t][1] = bb.y; acc[t][2] = bb.z; acc[t][3] = bb.w;
        }
        for (int k = 0; k < 128; k += 4) {
            float wv4[4][4];
            #pragma unroll
            for (int kk = 0; kk < 4; ++kk) {
                const float4 w = *(const float4*)(W1 + (size_t)(k + kk) * 128 + 4 * cg);
                wv4[kk][0] = w.x; wv4[kk][1] = w.y; wv4[kk][2] = w.z; wv4[kk][3] = w.w;
            }
            #pragma unroll
            for (int t = 0; t < 4; ++t) {
                const float4 m = *(const float4*)(&s_in[er + 8 * t][k]);
                const float mm[4] = {m.x, m.y, m.z, m.w};
                #pragma unroll
                for (int kk = 0; kk < 4; ++kk)
                    #pragma unroll
                    for (int c = 0; c < 4; ++c)
                        acc[t][c] += mm[kk] * wv4[kk][c];
            }
        }
        for (int k = 128; k < 131; ++k) {  // K tail (131 = 32*4 + 3)
            float wk[4];
            #pragma unroll
            for (int c = 0; c < 4; ++c) wk[c] = W1[(size_t)k * 128 + 4 * cg + c];
            #pragma unroll
            for (int t = 0; t < 4; ++t) {
                const float m = s_in[er + 8 * t][k];
                #pragma unroll
                for (int c = 0; c < 4; ++c) acc[t][c] += m * wk[c];
            }
        }
        #pragma unroll
        for (int t = 0; t < 4; ++t)
            #pragma unroll
            for (int c = 0; c < 4; ++c)
                s_h[er + 8 * t][4 * cg + c] = fmaxf(acc[t][c], 0.f);
    }
    __syncthreads();

    // ---- layer 2: msg = hmsg @ W2 + b2   K=128, 64 cols, then scatter-add
    {
        const int cg = tid & 15;   // cols 4*cg .. 4*cg+3
        const int er = tid >> 4;   // edges er, er+16
        float acc[2][4];
        const float4 bb = *(const float4*)(b2 + 4 * cg);
        #pragma unroll
        for (int t = 0; t < 2; ++t) {
            acc[t][0] = bb.x; acc[t][1] = bb.y; acc[t][2] = bb.z; acc[t][3] = bb.w;
        }
        for (int k = 0; k < 128; k += 4) {
            float wv4[4][4];
            #pragma unroll
            for (int kk = 0; kk < 4; ++kk) {
                const float4 w = *(const float4*)(W2 + (size_t)(k + kk) * 64 + 4 * cg);
                wv4[kk][0] = w.x; wv4[kk][1] = w.y; wv4[kk][2] = w.z; wv4[kk][3] = w.w;
            }
            #pragma unroll
            for (int t = 0; t < 2; ++t) {
                const float4 m = *(const float4*)(&s_h[er + 16 * t][k]);
                const float mm[4] = {m.x, m.y, m.z, m.w};
                #pragma unroll
                for (int kk = 0; kk < 4; ++kk)
                    #pragma unroll
                    for (int c = 0; c < 4; ++c)
                        acc[t][c] += mm[kk] * wv4[kk][c];
            }
        }
        #pragma unroll
        for (int t = 0; t < 2; ++t) {
            const int e = er + 16 * t;
            const int i = s_idx[e];
            if (i >= 0) {
                #pragma unroll
                for (int c = 0; c < 4; ++c)
                    atomicAdd(&summed[(size_t)i * 64 + 4 * cg + c], acc[t][c]);
            }
        }
    }
    if (tid < EB) {
        const int i = s_idx[tid];
        if (i >= 0) atomicAdd(&counts[i], 1.0f);
    }
}

__global__ __launch_bounds__(256) void mpnn_node_kernel(
    const float* __restrict__ x, const float* __restrict__ summed,
    const float* __restrict__ counts,
    const float* __restrict__ W3, const float* __restrict__ b3,
    const float* __restrict__ W4, const float* __restrict__ b4,
    float* __restrict__ out, int N)
{
    __shared__ float s_in[NB][132];  // 128 used
    __shared__ float s_h[NB][132];   // 128 used

    const int tid  = threadIdx.x;
    const int base = blockIdx.x * NB;
    const int wv   = tid >> 6;
    const int lane = tid & 63;

    // ---- stage upd_in = [x, aggr] into LDS
    for (int nl = wv; nl < NB; nl += 4) {
        const int n = base + nl;
        if (n < N) {
            s_in[nl][lane] = x[(size_t)n * 64 + lane];
            const float inv = 1.0f / fmaxf(counts[n], 1.0f);
            s_in[nl][64 + lane] = summed[(size_t)n * 64 + lane] * inv;
        } else {
            s_in[nl][lane] = 0.f;
            s_in[nl][64 + lane] = 0.f;
        }
    }
    __syncthreads();

    // ---- layer 3: hupd = relu(upd_in @ W3 + b3)   K=128, 128 cols
    {
        const int cg = tid & 31;
        const int er = tid >> 5;
        float acc[4][4];
        const float4 bb = *(const float4*)(b3 + 4 * cg);
        #pragma unroll
        for (int t = 0; t < 4; ++t) {
            acc[t][0] = bb.x; acc[t][1] = bb.y; acc[t][2] = bb.z; acc[t][3] = bb.w;
        }
        for (int k = 0; k < 128; k += 4) {
            float wv4[4][4];
            #pragma unroll
            for (int kk = 0; kk < 4; ++kk) {
                const float4 w = *(const float4*)(W3 + (size_t)(k + kk) * 128 + 4 * cg);
                wv4[kk][0] = w.x; wv4[kk][1] = w.y; wv4[kk][2] = w.z; wv4[kk][3] = w.w;
            }
            #pragma unroll
            for (int t = 0; t < 4; ++t) {
                const float4 m = *(const float4*)(&s_in[er + 8 * t][k]);
                const float mm[4] = {m.x, m.y, m.z, m.w};
                #pragma unroll
                for (int kk = 0; kk < 4; ++kk)
                    #pragma unroll
                    for (int c = 0; c < 4; ++c)
                        acc[t][c] += mm[kk] * wv4[kk][c];
            }
        }
        #pragma unroll
        for (int t = 0; t < 4; ++t)
            #pragma unroll
            for (int c = 0; c < 4; ++c)
                s_h[er + 8 * t][4 * cg + c] = fmaxf(acc[t][c], 0.f);
    }
    __syncthreads();

    // ---- layer 4: out = hupd @ W4 + b4   K=128, 64 cols
    {
        const int cg = tid & 15;
        const int er = tid >> 4;
        float acc[2][4];
        const float4 bb = *(const float4*)(b4 + 4 * cg);
        #pragma unroll
        for (int t = 0; t < 2; ++t) {
            acc[t][0] = bb.x; acc[t][1] = bb.y; acc[t][2] = bb.z; acc[t][3] = bb.w;
        }
        for (int k = 0; k < 128; k += 4) {
            float wv4[4][4];
            #pragma unroll
            for (int kk = 0; kk < 4; ++kk) {
                const float4 w = *(const float4*)(W4 + (size_t)(k + kk) * 64 + 4 * cg);
                wv4[kk][0] = w.x; wv4[kk][1] = w.y; wv4[kk][2] = w.z; wv4[kk][3] = w.w;
            }
            #pragma unroll
            for (int t = 0; t < 2; ++t) {
                const float4 m = *(const float4*)(&s_h[er + 16 * t][k]);
                const float mm[4] = {m.x, m.y, m.z, m.w};
                #pragma unroll
                for (int kk = 0; kk < 4; ++kk)
                    #pragma unroll
                    for (int c = 0; c < 4; ++c)
                        acc[t][c] += mm[kk] * wv4[kk][c];
            }
        }
        #pragma unroll
        for (int t = 0; t < 2; ++t) {
            const int n = base + er + 16 * t;
            if (n < N) {
                float4 o;
                o.x = acc[t][0]; o.y = acc[t][1]; o.z = acc[t][2]; o.w = acc[t][3];
                *(float4*)(out + (size_t)n * 64 + 4 * cg) = o;
            }
        }
    }
}

extern "C" void kernel_launch(void* const* d_in, const int* in_sizes, int n_in,
                              void* d_out, int out_size, void* d_ws, size_t ws_size,
                              hipStream_t stream) {
    const float* x    = (const float*)d_in[0];
    const float* pos  = (const float*)d_in[1];
    const int*   eidx = (const int*)d_in[2];
    const float* W1   = (const float*)d_in[3];
    const float* b1   = (const float*)d_in[4];
    const float* W2   = (const float*)d_in[5];
    const float* b2   = (const float*)d_in[6];
    const float* W3   = (const float*)d_in[7];
    const float* b3   = (const float*)d_in[8];
    const float* W4   = (const float*)d_in[9];
    const float* b4   = (const float*)d_in[10];

    const int N = in_sizes[0] / 64;
    const int E = in_sizes[2] / 2;
    const int* ei0 = eidx;       // edge_index[0] = aggregation node i
    const int* ei1 = eidx + E;   // edge_index[1] = neighbor j

    float* summed = (float*)d_ws;               // [N, 64]
    float* counts = summed + (size_t)N * 64;    // [N]

    hipMemsetAsync(d_ws, 0, ((size_t)N * 64 + N) * sizeof(float), stream);

    const int edge_blocks = (E + EB - 1) / EB;
    mpnn_edge_kernel<<<edge_blocks, 256, 0, stream>>>(
        x, pos, ei0, ei1, W1, b1, W2, b2, summed, counts, E);

    const int node_blocks = (N + NB - 1) / NB;
    mpnn_node_kernel<<<node_blocks, 256, 0, stream>>>(
        x, summed, counts, W3, b3, W4, b4, (float*)d_out, N);
}

// Round 3
// 1065.493 us; speedup vs baseline: 1.0224x; 1.0224x over previous
//
#include <hip/hip_runtime.h>

// MPNN: edge MLP (131->128->64) + scatter-mean + node MLP (128->128->64)
// N=50000, E=800000, fp32 in/out.
// R3: R2 (CSR two-phase aggregation, bf16 msg buffer, halved LDS) with the
// pos-staging bug fixed: rel_pos is now written for EVERY edge (gate on c<3
// only; r selects the edge, so gating on r==0 left 3/4 of edges with
// uninitialized LDS at k=128..130 -> absmax 3.6e35 in R2).

#define EB 32   // edges per block
#define NB 32   // nodes per block

static __device__ __forceinline__ unsigned short f2bf(float f) {
    union { float f; unsigned u; } v; v.f = f;
    unsigned u = v.u + 0x7FFFu + ((v.u >> 16) & 1u);  // round-to-nearest-even
    return (unsigned short)(u >> 16);
}
static __device__ __forceinline__ float bf2f(unsigned short h) {
    union { unsigned u; float f; } v; v.u = ((unsigned)h) << 16;
    return v.f;
}

// ---------------- CSR build ----------------

__global__ __launch_bounds__(256) void count_kernel(
    const int* __restrict__ ei0, int* __restrict__ cnt, int E)
{
    int e = blockIdx.x * 256 + threadIdx.x;
    if (e < E) atomicAdd(&cnt[ei0[e]], 1);
}

__global__ __launch_bounds__(1024) void scan_kernel(
    const int* __restrict__ cnt, int* __restrict__ off, int N)
{
    __shared__ int s[1024];
    __shared__ int carry;
    if (threadIdx.x == 0) carry = 0;
    __syncthreads();
    for (int b0 = 0; b0 < N; b0 += 1024) {
        int i = b0 + threadIdx.x;
        int v = (i < N) ? cnt[i] : 0;
        s[threadIdx.x] = v;
        __syncthreads();
        for (int d = 1; d < 1024; d <<= 1) {
            int t = (threadIdx.x >= d) ? s[threadIdx.x - d] : 0;
            __syncthreads();
            s[threadIdx.x] += t;
            __syncthreads();
        }
        if (i < N) off[i] = carry + s[threadIdx.x] - v;  // exclusive
        __syncthreads();
        if (threadIdx.x == 0) carry += s[1023];
        __syncthreads();
    }
}

__global__ __launch_bounds__(256) void fill_kernel(
    const int* __restrict__ ei0, const int* __restrict__ off,
    int* __restrict__ cur, int* __restrict__ elist, int E)
{
    int e = blockIdx.x * 256 + threadIdx.x;
    if (e < E) {
        int i = ei0[e];
        int p = atomicAdd(&cur[i], 1);
        elist[off[i] + p] = e;
    }
}

// ---------------- edge MLP -> bf16 msg buffer ----------------

__global__ __launch_bounds__(256) void edge_mlp_kernel(
    const float* __restrict__ x, const float* __restrict__ pos,
    const int* __restrict__ ei0, const int* __restrict__ ei1,
    const float* __restrict__ W1, const float* __restrict__ b1,
    const float* __restrict__ W2, const float* __restrict__ b2,
    unsigned short* __restrict__ msg, int E)
{
    __shared__ float s_in[EB][132];  // staged input, then reused for hidden layer

    const int tid  = threadIdx.x;
    const int base = blockIdx.x * EB;
    const int wv   = tid >> 6;
    const int lane = tid & 63;
    const int r    = lane >> 4;   // 0..3: edge sub-index within staging group
    const int c    = lane & 15;   // float4 column group

    // ---- stage msg_in = [x_i, x_j - x_i, pos_j - pos_i]; 4 edges per wave-iter
    #pragma unroll
    for (int it = 0; it < 2; ++it) {
        const int e  = (wv * 2 + it) * 4 + r;   // 0..31, each exactly once
        const int ei = base + e;
        if (ei < E) {
            const int i = ei0[ei];
            const int j = ei1[ei];
            const float4 xi = *(const float4*)(x + (size_t)i * 64 + 4 * c);
            const float4 xj = *(const float4*)(x + (size_t)j * 64 + 4 * c);
            *(float4*)(&s_in[e][4 * c]) = xi;
            float4 d;
            d.x = xj.x - xi.x; d.y = xj.y - xi.y; d.z = xj.z - xi.z; d.w = xj.w - xi.w;
            *(float4*)(&s_in[e][64 + 4 * c]) = d;
            if (c < 3)   // FIX: every 16-lane subgroup writes its OWN edge's pos
                s_in[e][128 + c] = pos[(size_t)j * 3 + c] - pos[(size_t)i * 3 + c];
        } else {
            *(float4*)(&s_in[e][4 * c]) = make_float4(0.f, 0.f, 0.f, 0.f);
            *(float4*)(&s_in[e][64 + 4 * c]) = make_float4(0.f, 0.f, 0.f, 0.f);
            if (c < 3) s_in[e][128 + c] = 0.f;
        }
    }
    __syncthreads();

    // ---- layer 1: hmsg = relu(msg_in @ W1 + b1)   K=131, 128 cols
    float acc1[4][4];
    {
        const int cg = tid & 31;
        const int er = tid >> 5;
        const float4 bb = *(const float4*)(b1 + 4 * cg);
        #pragma unroll
        for (int t = 0; t < 4; ++t) {
            acc1[t][0] = bb.x; acc1[t][1] = bb.y; acc1[t][2] = bb.z; acc1[t][3] = bb.w;
        }
        for (int k = 0; k < 128; k += 4) {
            float wv4[4][4];
            #pragma unroll
            for (int kk = 0; kk < 4; ++kk) {
                const float4 w = *(const float4*)(W1 + (size_t)(k + kk) * 128 + 4 * cg);
                wv4[kk][0] = w.x; wv4[kk][1] = w.y; wv4[kk][2] = w.z; wv4[kk][3] = w.w;
            }
            #pragma unroll
            for (int t = 0; t < 4; ++t) {
                const float4 m = *(const float4*)(&s_in[er + 8 * t][k]);
                const float mm[4] = {m.x, m.y, m.z, m.w};
                #pragma unroll
                for (int kk = 0; kk < 4; ++kk)
                    #pragma unroll
                    for (int cc = 0; cc < 4; ++cc)
                        acc1[t][cc] += mm[kk] * wv4[kk][cc];
            }
        }
        for (int k = 128; k < 131; ++k) {
            float wk[4];
            #pragma unroll
            for (int cc = 0; cc < 4; ++cc) wk[cc] = W1[(size_t)k * 128 + 4 * cg + cc];
            #pragma unroll
            for (int t = 0; t < 4; ++t) {
                const float m = s_in[er + 8 * t][k];
                #pragma unroll
                for (int cc = 0; cc < 4; ++cc) acc1[t][cc] += m * wk[cc];
            }
        }
    }
    __syncthreads();  // all reads of s_in complete before in-place overwrite

    {
        const int cg = tid & 31;
        const int er = tid >> 5;
        #pragma unroll
        for (int t = 0; t < 4; ++t)
            #pragma unroll
            for (int cc = 0; cc < 4; ++cc)
                s_in[er + 8 * t][4 * cg + cc] = fmaxf(acc1[t][cc], 0.f);
    }
    __syncthreads();

    // ---- layer 2: msg = hmsg @ W2 + b2   K=128, 64 cols, bf16 store
    {
        const int cg = tid & 15;
        const int er = tid >> 4;
        float acc[2][4];
        const float4 bb = *(const float4*)(b2 + 4 * cg);
        #pragma unroll
        for (int t = 0; t < 2; ++t) {
            acc[t][0] = bb.x; acc[t][1] = bb.y; acc[t][2] = bb.z; acc[t][3] = bb.w;
        }
        for (int k = 0; k < 128; k += 4) {
            float wv4[4][4];
            #pragma unroll
            for (int kk = 0; kk < 4; ++kk) {
                const float4 w = *(const float4*)(W2 + (size_t)(k + kk) * 64 + 4 * cg);
                wv4[kk][0] = w.x; wv4[kk][1] = w.y; wv4[kk][2] = w.z; wv4[kk][3] = w.w;
            }
            #pragma unroll
            for (int t = 0; t < 2; ++t) {
                const float4 m = *(const float4*)(&s_in[er + 16 * t][k]);
                const float mm[4] = {m.x, m.y, m.z, m.w};
                #pragma unroll
                for (int kk = 0; kk < 4; ++kk)
                    #pragma unroll
                    for (int cc = 0; cc < 4; ++cc)
                        acc[t][cc] += mm[kk] * wv4[kk][cc];
            }
        }
        #pragma unroll
        for (int t = 0; t < 2; ++t) {
            const int ei = base + er + 16 * t;
            if (ei < E) {
                ushort4 o;
                o.x = f2bf(acc[t][0]); o.y = f2bf(acc[t][1]);
                o.z = f2bf(acc[t][2]); o.w = f2bf(acc[t][3]);
                *(ushort4*)(msg + (size_t)ei * 64 + 4 * cg) = o;
            }
        }
    }
}

// ---------------- gather-mean + node MLP ----------------

__global__ __launch_bounds__(256) void node_kernel(
    const float* __restrict__ x, const unsigned short* __restrict__ msg,
    const int* __restrict__ off, const int* __restrict__ cnt,
    const int* __restrict__ elist,
    const float* __restrict__ W3, const float* __restrict__ b3,
    const float* __restrict__ W4, const float* __restrict__ b4,
    float* __restrict__ out, int N)
{
    __shared__ float s_in[NB][132];

    const int tid  = threadIdx.x;
    const int base = blockIdx.x * NB;
    const int wv   = tid >> 6;
    const int lane = tid & 63;

    // ---- stage upd_in = [x, mean(msg over CSR list)]
    for (int nl = wv; nl < NB; nl += 4) {
        const int n = base + nl;
        if (n < N) {
            s_in[nl][lane] = x[(size_t)n * 64 + lane];
            const int o0  = off[n];
            const int deg = cnt[n];
            float a = 0.f;
            int t = 0;
            for (; t + 4 <= deg; t += 4) {
                const int e0 = elist[o0 + t];
                const int e1 = elist[o0 + t + 1];
                const int e2 = elist[o0 + t + 2];
                const int e3 = elist[o0 + t + 3];
                const float m0 = bf2f(msg[(size_t)e0 * 64 + lane]);
                const float m1 = bf2f(msg[(size_t)e1 * 64 + lane]);
                const float m2 = bf2f(msg[(size_t)e2 * 64 + lane]);
                const float m3 = bf2f(msg[(size_t)e3 * 64 + lane]);
                a += (m0 + m1) + (m2 + m3);
            }
            for (; t < deg; ++t) {
                const int e = elist[o0 + t];
                a += bf2f(msg[(size_t)e * 64 + lane]);
            }
            s_in[nl][64 + lane] = a / (float)max(deg, 1);
        } else {
            s_in[nl][lane] = 0.f;
            s_in[nl][64 + lane] = 0.f;
        }
    }
    __syncthreads();

    // ---- layer 3: hupd = relu(upd_in @ W3 + b3)   K=128, 128 cols
    float acc1[4][4];
    {
        const int cg = tid & 31;
        const int er = tid >> 5;
        const float4 bb = *(const float4*)(b3 + 4 * cg);
        #pragma unroll
        for (int t = 0; t < 4; ++t) {
            acc1[t][0] = bb.x; acc1[t][1] = bb.y; acc1[t][2] = bb.z; acc1[t][3] = bb.w;
        }
        for (int k = 0; k < 128; k += 4) {
            float wv4[4][4];
            #pragma unroll
            for (int kk = 0; kk < 4; ++kk) {
                const float4 w = *(const float4*)(W3 + (size_t)(k + kk) * 128 + 4 * cg);
                wv4[kk][0] = w.x; wv4[kk][1] = w.y; wv4[kk][2] = w.z; wv4[kk][3] = w.w;
            }
            #pragma unroll
            for (int t = 0; t < 4; ++t) {
                const float4 m = *(const float4*)(&s_in[er + 8 * t][k]);
                const float mm[4] = {m.x, m.y, m.z, m.w};
                #pragma unroll
                for (int kk = 0; kk < 4; ++kk)
                    #pragma unroll
                    for (int cc = 0; cc < 4; ++cc)
                        acc1[t][cc] += mm[kk] * wv4[kk][cc];
            }
        }
    }
    __syncthreads();

    {
        const int cg = tid & 31;
        const int er = tid >> 5;
        #pragma unroll
        for (int t = 0; t < 4; ++t)
            #pragma unroll
            for (int cc = 0; cc < 4; ++cc)
                s_in[er + 8 * t][4 * cg + cc] = fmaxf(acc1[t][cc], 0.f);
    }
    __syncthreads();

    // ---- layer 4: out = hupd @ W4 + b4   K=128, 64 cols
    {
        const int cg = tid & 15;
        const int er = tid >> 4;
        float acc[2][4];
        const float4 bb = *(const float4*)(b4 + 4 * cg);
        #pragma unroll
        for (int t = 0; t < 2; ++t) {
            acc[t][0] = bb.x; acc[t][1] = bb.y; acc[t][2] = bb.z; acc[t][3] = bb.w;
        }
        for (int k = 0; k < 128; k += 4) {
            float wv4[4][4];
            #pragma unroll
            for (int kk = 0; kk < 4; ++kk) {
                const float4 w = *(const float4*)(W4 + (size_t)(k + kk) * 64 + 4 * cg);
                wv4[kk][0] = w.x; wv4[kk][1] = w.y; wv4[kk][2] = w.z; wv4[kk][3] = w.w;
            }
            #pragma unroll
            for (int t = 0; t < 2; ++t) {
                const float4 m = *(const float4*)(&s_in[er + 16 * t][k]);
                const float mm[4] = {m.x, m.y, m.z, m.w};
                #pragma unroll
                for (int kk = 0; kk < 4; ++kk)
                    #pragma unroll
                    for (int cc = 0; cc < 4; ++cc)
                        acc[t][cc] += mm[kk] * wv4[kk][cc];
            }
        }
        #pragma unroll
        for (int t = 0; t < 2; ++t) {
            const int n = base + er + 16 * t;
            if (n < N) {
                float4 o;
                o.x = acc[t][0]; o.y = acc[t][1]; o.z = acc[t][2]; o.w = acc[t][3];
                *(float4*)(out + (size_t)n * 64 + 4 * cg) = o;
            }
        }
    }
}

// ---------------- fallback (R1 atomic path, if ws too small) ----------------

__global__ __launch_bounds__(256) void mpnn_edge_atomic_kernel(
    const float* __restrict__ x, const float* __restrict__ pos,
    const int* __restrict__ ei0, const int* __restrict__ ei1,
    const float* __restrict__ W1, const float* __restrict__ b1,
    const float* __restrict__ W2, const float* __restrict__ b2,
    float* __restrict__ summed, float* __restrict__ counts, int E)
{
    __shared__ float s_in[EB][132];
    __shared__ int   s_idx[EB];

    const int tid  = threadIdx.x;
    const int base = blockIdx.x * EB;
    const int wv   = tid >> 6;
    const int lane = tid & 63;

    for (int e = wv; e < EB; e += 4) {
        const int ei = base + e;
        if (ei < E) {
            const int i = ei0[ei];
            const int j = ei1[ei];
            const float xi = x[(size_t)i * 64 + lane];
            const float xj = x[(size_t)j * 64 + lane];
            s_in[e][lane]      = xi;
            s_in[e][64 + lane] = xj - xi;
            if (lane < 3)
                s_in[e][128 + lane] = pos[(size_t)j * 3 + lane] - pos[(size_t)i * 3 + lane];
            if (lane == 0) s_idx[e] = i;
        } else {
            s_in[e][lane] = 0.f; s_in[e][64 + lane] = 0.f;
            if (lane < 3) s_in[e][128 + lane] = 0.f;
            if (lane == 0) s_idx[e] = -1;
        }
    }
    __syncthreads();

    float acc1[4][4];
    {
        const int cg = tid & 31;
        const int er = tid >> 5;
        const float4 bb = *(const float4*)(b1 + 4 * cg);
        #pragma unroll
        for (int t = 0; t < 4; ++t) {
            acc1[t][0] = bb.x; acc1[t][1] = bb.y; acc1[t][2] = bb.z; acc1[t][3] = bb.w;
        }
        for (int k = 0; k < 128; k += 4) {
            float wv4[4][4];
            #pragma unroll
            for (int kk = 0; kk < 4; ++kk) {
                const float4 w = *(const float4*)(W1 + (size_t)(k + kk) * 128 + 4 * cg);
                wv4[kk][0] = w.x; wv4[kk][1] = w.y; wv4[kk][2] = w.z; wv4[kk][3] = w.w;
            }
            #pragma unroll
            for (int t = 0; t < 4; ++t) {
                const float4 m = *(const float4*)(&s_in[er + 8 * t][k]);
                const float mm[4] = {m.x, m.y, m.z, m.w};
                #pragma unroll
                for (int kk = 0; kk < 4; ++kk)
                    #pragma unroll
                    for (int cc = 0; cc < 4; ++cc)
                        acc1[t][cc] += mm[kk] * wv4[kk][cc];
            }
        }
        for (int k = 128; k < 131; ++k) {
            float wk[4];
            #pragma unroll
            for (int cc = 0; cc < 4; ++cc) wk[cc] = W1[(size_t)k * 128 + 4 * cg + cc];
            #pragma unroll
            for (int t = 0; t < 4; ++t) {
                const float m = s_in[er + 8 * t][k];
                #pragma unroll
                for (int cc = 0; cc < 4; ++cc) acc1[t][cc] += m * wk[cc];
            }
        }
    }
    __syncthreads();
    {
        const int cg = tid & 31;
        const int er = tid >> 5;
        #pragma unroll
        for (int t = 0; t < 4; ++t)
            #pragma unroll
            for (int cc = 0; cc < 4; ++cc)
                s_in[er + 8 * t][4 * cg + cc] = fmaxf(acc1[t][cc], 0.f);
    }
    __syncthreads();
    {
        const int cg = tid & 15;
        const int er = tid >> 4;
        float acc[2][4];
        const float4 bb = *(const float4*)(b2 + 4 * cg);
        #pragma unroll
        for (int t = 0; t < 2; ++t) {
            acc[t][0] = bb.x; acc[t][1] = bb.y; acc[t][2] = bb.z; acc[t][3] = bb.w;
        }
        for (int k = 0; k < 128; k += 4) {
            float wv4[4][4];
            #pragma unroll
            for (int kk = 0; kk < 4; ++kk) {
                const float4 w = *(const float4*)(W2 + (size_t)(k + kk) * 64 + 4 * cg);
                wv4[kk][0] = w.x; wv4[kk][1] = w.y; wv4[kk][2] = w.z; wv4[kk][3] = w.w;
            }
            #pragma unroll
            for (int t = 0; t < 2; ++t) {
                const float4 m = *(const float4*)(&s_in[er + 16 * t][k]);
                const float mm[4] = {m.x, m.y, m.z, m.w};
                #pragma unroll
                for (int kk = 0; kk < 4; ++kk)
                    #pragma unroll
                    for (int cc = 0; cc < 4; ++cc)
                        acc[t][cc] += mm[kk] * wv4[kk][cc];
            }
        }
        #pragma unroll
        for (int t = 0; t < 2; ++t) {
            const int e = er + 16 * t;
            const int i = s_idx[e];
            if (i >= 0) {
                #pragma unroll
                for (int cc = 0; cc < 4; ++cc)
                    atomicAdd(&summed[(size_t)i * 64 + 4 * cg + cc], acc[t][cc]);
            }
        }
    }
    if (tid < EB) {
        const int i = s_idx[tid];
        if (i >= 0) atomicAdd(&counts[i], 1.0f);
    }
}

__global__ __launch_bounds__(256) void mpnn_node_legacy_kernel(
    const float* __restrict__ x, const float* __restrict__ summed,
    const float* __restrict__ counts,
    const float* __restrict__ W3, const float* __restrict__ b3,
    const float* __restrict__ W4, const float* __restrict__ b4,
    float* __restrict__ out, int N)
{
    __shared__ float s_in[NB][132];

    const int tid  = threadIdx.x;
    const int base = blockIdx.x * NB;
    const int wv   = tid >> 6;
    const int lane = tid & 63;

    for (int nl = wv; nl < NB; nl += 4) {
        const int n = base + nl;
        if (n < N) {
            s_in[nl][lane] = x[(size_t)n * 64 + lane];
            const float inv = 1.0f / fmaxf(counts[n], 1.0f);
            s_in[nl][64 + lane] = summed[(size_t)n * 64 + lane] * inv;
        } else {
            s_in[nl][lane] = 0.f; s_in[nl][64 + lane] = 0.f;
        }
    }
    __syncthreads();

    float acc1[4][4];
    {
        const int cg = tid & 31;
        const int er = tid >> 5;
        const float4 bb = *(const float4*)(b3 + 4 * cg);
        #pragma unroll
        for (int t = 0; t < 4; ++t) {
            acc1[t][0] = bb.x; acc1[t][1] = bb.y; acc1[t][2] = bb.z; acc1[t][3] = bb.w;
        }
        for (int k = 0; k < 128; k += 4) {
            float wv4[4][4];
            #pragma unroll
            for (int kk = 0; kk < 4; ++kk) {
                const float4 w = *(const float4*)(W3 + (size_t)(k + kk) * 128 + 4 * cg);
                wv4[kk][0] = w.x; wv4[kk][1] = w.y; wv4[kk][2] = w.z; wv4[kk][3] = w.w;
            }
            #pragma unroll
            for (int t = 0; t < 4; ++t) {
                const float4 m = *(const float4*)(&s_in[er + 8 * t][k]);
                const float mm[4] = {m.x, m.y, m.z, m.w};
                #pragma unroll
                for (int kk = 0; kk < 4; ++kk)
                    #pragma unroll
                    for (int cc = 0; cc < 4; ++cc)
                        acc1[t][cc] += mm[kk] * wv4[kk][cc];
            }
        }
    }
    __syncthreads();
    {
        const int cg = tid & 31;
        const int er = tid >> 5;
        #pragma unroll
        for (int t = 0; t < 4; ++t)
            #pragma unroll
            for (int cc = 0; cc < 4; ++cc)
                s_in[er + 8 * t][4 * cg + cc] = fmaxf(acc1[t][cc], 0.f);
    }
    __syncthreads();
    {
        const int cg = tid & 15;
        const int er = tid >> 4;
        float acc[2][4];
        const float4 bb = *(const float4*)(b4 + 4 * cg);
        #pragma unroll
        for (int t = 0; t < 2; ++t) {
            acc[t][0] = bb.x; acc[t][1] = bb.y; acc[t][2] = bb.z; acc[t][3] = bb.w;
        }
        for (int k = 0; k < 128; k += 4) {
            float wv4[4][4];
            #pragma unroll
            for (int kk = 0; kk < 4; ++kk) {
                const float4 w = *(const float4*)(W4 + (size_t)(k + kk) * 64 + 4 * cg);
                wv4[kk][0] = w.x; wv4[kk][1] = w.y; wv4[kk][2] = w.z; wv4[kk][3] = w.w;
            }
            #pragma unroll
            for (int t = 0; t < 2; ++t) {
                const float4 m = *(const float4*)(&s_in[er + 16 * t][k]);
                const float mm[4] = {m.x, m.y, m.z, m.w};
                #pragma unroll
                for (int kk = 0; kk < 4; ++kk)
                    #pragma unroll
                    for (int cc = 0; cc < 4; ++cc)
                        acc[t][cc] += mm[kk] * wv4[kk][cc];
            }
        }
        #pragma unroll
        for (int t = 0; t < 2; ++t) {
            const int n = base + er + 16 * t;
            if (n < N) {
                float4 o;
                o.x = acc[t][0]; o.y = acc[t][1]; o.z = acc[t][2]; o.w = acc[t][3];
                *(float4*)(out + (size_t)n * 64 + 4 * cg) = o;
            }
        }
    }
}

// ---------------- launch ----------------

extern "C" void kernel_launch(void* const* d_in, const int* in_sizes, int n_in,
                              void* d_out, int out_size, void* d_ws, size_t ws_size,
                              hipStream_t stream) {
    const float* x    = (const float*)d_in[0];
    const float* pos  = (const float*)d_in[1];
    const int*   eidx = (const int*)d_in[2];
    const float* W1   = (const float*)d_in[3];
    const float* b1   = (const float*)d_in[4];
    const float* W2   = (const float*)d_in[5];
    const float* b2   = (const float*)d_in[6];
    const float* W3   = (const float*)d_in[7];
    const float* b3   = (const float*)d_in[8];
    const float* W4   = (const float*)d_in[9];
    const float* b4   = (const float*)d_in[10];

    const int N = in_sizes[0] / 64;
    const int E = in_sizes[2] / 2;
    const int* ei0 = eidx;       // edge_index[0] = aggregation node i
    const int* ei1 = eidx + E;   // edge_index[1] = neighbor j

    // CSR-path workspace: msg bf16 [E,64] | cnt [N] | cur [N] | off [N+1] | elist [E]
    const size_t msg_bytes = (size_t)E * 64 * 2;
    const size_t need = msg_bytes + (size_t)N * 4 * 2 + (size_t)(N + 1) * 4 + (size_t)E * 4;

    if (ws_size >= need) {
        char* p = (char*)d_ws;
        unsigned short* msg = (unsigned short*)p;  p += msg_bytes;
        int* cnt   = (int*)p;  p += (size_t)N * 4;
        int* cur   = (int*)p;  p += (size_t)N * 4;
        int* off   = (int*)p;  p += (size_t)(N + 1) * 4;
        int* elist = (int*)p;

        hipMemsetAsync(cnt, 0, (size_t)N * 4 * 2, stream);  // cnt + cur (adjacent)

        const int eb256 = (E + 255) / 256;
        count_kernel<<<eb256, 256, 0, stream>>>(ei0, cnt, E);
        scan_kernel<<<1, 1024, 0, stream>>>(cnt, off, N);
        fill_kernel<<<eb256, 256, 0, stream>>>(ei0, off, cur, elist, E);

        edge_mlp_kernel<<<(E + EB - 1) / EB, 256, 0, stream>>>(
            x, pos, ei0, ei1, W1, b1, W2, b2, msg, E);

        node_kernel<<<(N + NB - 1) / NB, 256, 0, stream>>>(
            x, msg, off, cnt, elist, W3, b3, W4, b4, (float*)d_out, N);
    } else {
        // fallback: R1 atomic path
        float* summed = (float*)d_ws;
        float* counts = summed + (size_t)N * 64;
        hipMemsetAsync(d_ws, 0, ((size_t)N * 64 + N) * sizeof(float), stream);

        mpnn_edge_atomic_kernel<<<(E + EB - 1) / EB, 256, 0, stream>>>(
            x, pos, ei0, ei1, W1, b1, W2, b2, summed, counts, E);
        mpnn_node_legacy_kernel<<<(N + NB - 1) / NB, 256, 0, stream>>>(
            x, summed, counts, W3, b3, W4, b4, (float*)d_out, N);
    }
}

// Round 5
// 562.372 us; speedup vs baseline: 1.9370x; 1.8946x over previous
//
#include <hip/hip_runtime.h>

// MPNN: edge MLP (131->128->64) + scatter-mean + node MLP (128->128->64)
// N=50000, E=800000, fp32 in/out.
// R5: R4 (bf16 MFMA 16x16x32 MLPs, packed weights, CSR aggregation) with the
// msg copy-out bug fixed: each thread copies its FULL 32-short half-row
// (q<8 ushort4s; R4's q<4 left msg features 16-31/48-63 unwritten -> absmax 1.5).
// A-frag: A[m=lane&15][k=(lane>>4)*8+j]; B-frag: B[k=(lane>>4)*8+j][n=lane&15];
// C/D: col=lane&15, row=(lane>>4)*4+reg  (per guide, m89/m91-verified).

#define EPB 128  // edges per block (4 waves x M=32)
#define NPB 64   // nodes per block (4 waves x M=16)

typedef __attribute__((ext_vector_type(8))) short bf16x8;
typedef __attribute__((ext_vector_type(4))) float f32x4;

static __device__ __forceinline__ unsigned short f2bf(float f) {
    union { float f; unsigned u; } v; v.f = f;
    unsigned u = v.u + 0x7FFFu + ((v.u >> 16) & 1u);  // RNE
    return (unsigned short)(u >> 16);
}
static __device__ __forceinline__ float bf2f(unsigned short h) {
    union { unsigned u; float f; } v; v.u = ((unsigned)h) << 16;
    return v.f;
}

// ---------------- CSR build ----------------

__global__ __launch_bounds__(256) void count_kernel(
    const int* __restrict__ ei0, int* __restrict__ cnt, int E)
{
    int e = blockIdx.x * 256 + threadIdx.x;
    if (e < E) atomicAdd(&cnt[ei0[e]], 1);
}

__global__ __launch_bounds__(1024) void scan_kernel(
    const int* __restrict__ cnt, int* __restrict__ off, int N)
{
    __shared__ int s[1024];
    __shared__ int carry;
    if (threadIdx.x == 0) carry = 0;
    __syncthreads();
    for (int b0 = 0; b0 < N; b0 += 1024) {
        int i = b0 + threadIdx.x;
        int v = (i < N) ? cnt[i] : 0;
        s[threadIdx.x] = v;
        __syncthreads();
        for (int d = 1; d < 1024; d <<= 1) {
            int t = (threadIdx.x >= d) ? s[threadIdx.x - d] : 0;
            __syncthreads();
            s[threadIdx.x] += t;
            __syncthreads();
        }
        if (i < N) off[i] = carry + s[threadIdx.x] - v;  // exclusive
        __syncthreads();
        if (threadIdx.x == 0) carry += s[1023];
        __syncthreads();
    }
}

__global__ __launch_bounds__(256) void fill_kernel(
    const int* __restrict__ ei0, const int* __restrict__ off,
    int* __restrict__ cur, int* __restrict__ elist, int E)
{
    int e = blockIdx.x * 256 + threadIdx.x;
    if (e < E) {
        int i = ei0[e];
        int p = atomicAdd(&cur[i], 1);
        elist[off[i] + p] = e;
    }
}

// ---------------- weight pre-pack into B-fragment order ----------------
// Frag (nt,ks) of W[K][N]: lane l, elem j holds W[ks*32+(l>>4)*8+j][nt*16+(l&15)]
// stored bf16 at out[frag*512 + l*8 + j]. One block per frag, 64 threads.

__global__ __launch_bounds__(64) void pack_weights_kernel(
    const float* __restrict__ W1, const float* __restrict__ W2,
    const float* __restrict__ W3, const float* __restrict__ W4,
    unsigned short* __restrict__ W1p, unsigned short* __restrict__ W2p,
    unsigned short* __restrict__ W3p, unsigned short* __restrict__ W4p)
{
    int f = blockIdx.x;           // 0..103
    const int lane = threadIdx.x; // 0..63
    const float* W; unsigned short* out; int K, N, KS;
    if (f < 40)      { W = W1; out = W1p; K = 131; N = 128; KS = 5; }
    else if (f < 56) { W = W2; out = W2p; K = 128; N = 64;  KS = 4; f -= 40; }
    else if (f < 88) { W = W3; out = W3p; K = 128; N = 128; KS = 4; f -= 56; }
    else             { W = W4; out = W4p; K = 128; N = 64;  KS = 4; f -= 88; }
    const int nt = f / KS, ks = f % KS;
    const int n  = nt * 16 + (lane & 15);
    const int k0 = ks * 32 + (lane >> 4) * 8;
    unsigned short* dst = out + (size_t)f * 512 + lane * 8;
    #pragma unroll
    for (int j = 0; j < 8; ++j) {
        float v = (k0 + j < K) ? W[(size_t)(k0 + j) * N + n] : 0.f;
        dst[j] = f2bf(v);
    }
}

// ---------------- edge MLP (MFMA) -> bf16 msg buffer ----------------

__global__ __launch_bounds__(256) void edge_mlp_mfma(
    const float* __restrict__ x, const float* __restrict__ pos,
    const int* __restrict__ ei0, const int* __restrict__ ei1,
    const unsigned short* __restrict__ W1p, const float* __restrict__ b1,
    const unsigned short* __restrict__ W2p, const float* __restrict__ b2,
    unsigned short* __restrict__ msg, int E)
{
    // 128 rows x 168 bf16 = 336 B stride (21*16B, odd -> conflict-friendly)
    __shared__ unsigned short s_a[EPB][168];

    const int tid  = threadIdx.x;
    const int wv   = tid >> 6;
    const int lane = tid & 63;
    const int r    = lane >> 4;   // quad
    const int c    = lane & 15;
    const int base = blockIdx.x * EPB;

    // ---- stage [x_i | x_j-x_i | relpos | 0-pad] as bf16, K padded to 160
    #pragma unroll
    for (int it = 0; it < 8; ++it) {
        const int e  = wv * 32 + it * 4 + r;   // 0..127, each once
        const int ei = base + e;
        if (ei < E) {
            const int i = ei0[ei];
            const int j = ei1[ei];
            const float4 xi = *(const float4*)(x + (size_t)i * 64 + 4 * c);
            const float4 xj = *(const float4*)(x + (size_t)j * 64 + 4 * c);
            ushort4 a, d;
            a.x = f2bf(xi.x); a.y = f2bf(xi.y); a.z = f2bf(xi.z); a.w = f2bf(xi.w);
            d.x = f2bf(xj.x - xi.x); d.y = f2bf(xj.y - xi.y);
            d.z = f2bf(xj.z - xi.z); d.w = f2bf(xj.w - xi.w);
            *(ushort4*)&s_a[e][4 * c]      = a;
            *(ushort4*)&s_a[e][64 + 4 * c] = d;
            float pv = (c < 3) ? (pos[(size_t)j * 3 + c] - pos[(size_t)i * 3 + c]) : 0.f;
            s_a[e][128 + c] = f2bf(pv);
            s_a[e][144 + c] = 0;
        } else {
            ushort4 z; z.x = z.y = z.z = z.w = 0;
            *(ushort4*)&s_a[e][4 * c]      = z;
            *(ushort4*)&s_a[e][64 + 4 * c] = z;
            s_a[e][128 + c] = 0;
            s_a[e][144 + c] = 0;
        }
    }
    __syncthreads();

    // ---- load all layer-1 A-frags (then s_a is free for reuse)
    bf16x8 a1[2][5];
    #pragma unroll
    for (int mh = 0; mh < 2; ++mh)
        #pragma unroll
        for (int ks = 0; ks < 5; ++ks)
            a1[mh][ks] = *(const bf16x8*)&s_a[wv * 32 + mh * 16 + c][ks * 32 + r * 8];
    __syncthreads();

    // ---- layer 1: hidden = relu(A @ W1 + b1), N=128, K=160(pad)
    f32x4 acc1[2][8];
    #pragma unroll
    for (int nt = 0; nt < 8; ++nt) {
        const float bv = b1[nt * 16 + c];
        acc1[0][nt] = (f32x4){bv, bv, bv, bv};
        acc1[1][nt] = (f32x4){bv, bv, bv, bv};
    }
    #pragma unroll
    for (int nt = 0; nt < 8; ++nt)
        #pragma unroll
        for (int ks = 0; ks < 5; ++ks) {
            const bf16x8 b = *(const bf16x8*)(W1p + (size_t)(nt * 5 + ks) * 512 + lane * 8);
            acc1[0][nt] = __builtin_amdgcn_mfma_f32_16x16x32_bf16(a1[0][ks], b, acc1[0][nt], 0, 0, 0);
            acc1[1][nt] = __builtin_amdgcn_mfma_f32_16x16x32_bf16(a1[1][ks], b, acc1[1][nt], 0, 0, 0);
        }

    // ---- relu -> bf16 hidden back into s_a (cols 0..127)
    #pragma unroll
    for (int mh = 0; mh < 2; ++mh)
        #pragma unroll
        for (int nt = 0; nt < 8; ++nt)
            #pragma unroll
            for (int reg = 0; reg < 4; ++reg) {
                const int row = wv * 32 + mh * 16 + r * 4 + reg;
                s_a[row][nt * 16 + c] = f2bf(fmaxf(acc1[mh][nt][reg], 0.f));
            }
    __syncthreads();

    // ---- layer 2: msg = hidden @ W2 + b2, N=64, K=128
    bf16x8 a2[2][4];
    #pragma unroll
    for (int mh = 0; mh < 2; ++mh)
        #pragma unroll
        for (int ks = 0; ks < 4; ++ks)
            a2[mh][ks] = *(const bf16x8*)&s_a[wv * 32 + mh * 16 + c][ks * 32 + r * 8];
    __syncthreads();

    f32x4 acc2[2][4];
    #pragma unroll
    for (int nt = 0; nt < 4; ++nt) {
        const float bv = b2[nt * 16 + c];
        acc2[0][nt] = (f32x4){bv, bv, bv, bv};
        acc2[1][nt] = (f32x4){bv, bv, bv, bv};
    }
    #pragma unroll
    for (int nt = 0; nt < 4; ++nt)
        #pragma unroll
        for (int ks = 0; ks < 4; ++ks) {
            const bf16x8 b = *(const bf16x8*)(W2p + (size_t)(nt * 4 + ks) * 512 + lane * 8);
            acc2[0][nt] = __builtin_amdgcn_mfma_f32_16x16x32_bf16(a2[0][ks], b, acc2[0][nt], 0, 0, 0);
            acc2[1][nt] = __builtin_amdgcn_mfma_f32_16x16x32_bf16(a2[1][ks], b, acc2[1][nt], 0, 0, 0);
        }

    // ---- msg bf16 into s_a cols 0..63, then coalesced copy-out
    #pragma unroll
    for (int mh = 0; mh < 2; ++mh)
        #pragma unroll
        for (int nt = 0; nt < 4; ++nt)
            #pragma unroll
            for (int reg = 0; reg < 4; ++reg) {
                const int row = wv * 32 + mh * 16 + r * 4 + reg;
                s_a[row][nt * 16 + c] = f2bf(acc2[mh][nt][reg]);
            }
    __syncthreads();

    {
        const int e = tid >> 1, h = tid & 1;
        const int ei = base + e;
        if (ei < E) {
            const ushort4* src = (const ushort4*)&s_a[e][h * 32];
            ushort4* dst = (ushort4*)(msg + (size_t)ei * 64 + h * 32);
            #pragma unroll
            for (int q = 0; q < 8; ++q) dst[q] = src[q];  // FIX: 8x4=32 shorts (was 4 -> half missing)
        }
    }
}

// ---------------- gather-mean + node MLP (MFMA) ----------------

__global__ __launch_bounds__(256) void node_mlp_mfma(
    const float* __restrict__ x, const unsigned short* __restrict__ msg,
    const int* __restrict__ off, const int* __restrict__ cnt,
    const int* __restrict__ elist,
    const unsigned short* __restrict__ W3p, const float* __restrict__ b3,
    const unsigned short* __restrict__ W4p, const float* __restrict__ b4,
    float* __restrict__ out, int N)
{
    // 64 rows x 136 bf16 = 272 B stride (17*16B, odd); also holds 64 fp32 out
    __shared__ unsigned short s_a[NPB][136];

    const int tid  = threadIdx.x;
    const int wv   = tid >> 6;
    const int lane = tid & 63;
    const int r    = lane >> 4;
    const int c    = lane & 15;
    const int base = blockIdx.x * NPB;

    // ---- stage [x | mean(msg)] as bf16 (lane = feature)
    for (int nl = wv; nl < NPB; nl += 4) {
        const int n = base + nl;
        if (n < N) {
            s_a[nl][lane] = f2bf(x[(size_t)n * 64 + lane]);
            const int o0  = off[n];
            const int deg = cnt[n];
            float a = 0.f;
            int t = 0;
            for (; t + 4 <= deg; t += 4) {
                const int e0 = elist[o0 + t];
                const int e1 = elist[o0 + t + 1];
                const int e2 = elist[o0 + t + 2];
                const int e3 = elist[o0 + t + 3];
                const float m0 = bf2f(msg[(size_t)e0 * 64 + lane]);
                const float m1 = bf2f(msg[(size_t)e1 * 64 + lane]);
                const float m2 = bf2f(msg[(size_t)e2 * 64 + lane]);
                const float m3 = bf2f(msg[(size_t)e3 * 64 + lane]);
                a += (m0 + m1) + (m2 + m3);
            }
            for (; t < deg; ++t)
                a += bf2f(msg[(size_t)elist[o0 + t] * 64 + lane]);
            s_a[nl][64 + lane] = f2bf(a / (float)max(deg, 1));
        } else {
            s_a[nl][lane] = 0;
            s_a[nl][64 + lane] = 0;
        }
    }
    __syncthreads();

    // ---- layer 3: hidden = relu(A @ W3 + b3), M=16/wave, N=128, K=128
    bf16x8 a1[4];
    #pragma unroll
    for (int ks = 0; ks < 4; ++ks)
        a1[ks] = *(const bf16x8*)&s_a[wv * 16 + c][ks * 32 + r * 8];
    __syncthreads();

    f32x4 acc1[8];
    #pragma unroll
    for (int nt = 0; nt < 8; ++nt) {
        const float bv = b3[nt * 16 + c];
        acc1[nt] = (f32x4){bv, bv, bv, bv};
    }
    #pragma unroll
    for (int nt = 0; nt < 8; ++nt)
        #pragma unroll
        for (int ks = 0; ks < 4; ++ks) {
            const bf16x8 b = *(const bf16x8*)(W3p + (size_t)(nt * 4 + ks) * 512 + lane * 8);
            acc1[nt] = __builtin_amdgcn_mfma_f32_16x16x32_bf16(a1[ks], b, acc1[nt], 0, 0, 0);
        }
    #pragma unroll
    for (int nt = 0; nt < 8; ++nt)
        #pragma unroll
        for (int reg = 0; reg < 4; ++reg)
            s_a[wv * 16 + r * 4 + reg][nt * 16 + c] = f2bf(fmaxf(acc1[nt][reg], 0.f));
    __syncthreads();

    // ---- layer 4: out = hidden @ W4 + b4, N=64, K=128
    bf16x8 a2[4];
    #pragma unroll
    for (int ks = 0; ks < 4; ++ks)
        a2[ks] = *(const bf16x8*)&s_a[wv * 16 + c][ks * 32 + r * 8];
    __syncthreads();

    f32x4 acc2[4];
    #pragma unroll
    for (int nt = 0; nt < 4; ++nt) {
        const float bv = b4[nt * 16 + c];
        acc2[nt] = (f32x4){bv, bv, bv, bv};
    }
    #pragma unroll
    for (int nt = 0; nt < 4; ++nt)
        #pragma unroll
        for (int ks = 0; ks < 4; ++ks) {
            const bf16x8 b = *(const bf16x8*)(W4p + (size_t)(nt * 4 + ks) * 512 + lane * 8);
            acc2[nt] = __builtin_amdgcn_mfma_f32_16x16x32_bf16(a2[ks], b, acc2[nt], 0, 0, 0);
        }

    // ---- fp32 epilogue through LDS rows, then coalesced float4 stores
    #pragma unroll
    for (int nt = 0; nt < 4; ++nt)
        #pragma unroll
        for (int reg = 0; reg < 4; ++reg) {
            float* row = (float*)&s_a[wv * 16 + r * 4 + reg][0];
            row[nt * 16 + c] = acc2[nt][reg];
        }
    __syncthreads();

    {
        const int nl = tid >> 2, q = tid & 3;
        const int n = base + nl;
        if (n < N) {
            const float4* src = (const float4*)((const float*)&s_a[nl][0] + q * 16);
            float4* dst = (float4*)(out + (size_t)n * 64 + q * 16);
            #pragma unroll
            for (int u = 0; u < 4; ++u) dst[u] = src[u];
        }
    }
}

// ---------------- fallback (R1 atomic fp32 path, if ws too small) ----------------

#define EB 32
#define NB 32

__global__ __launch_bounds__(256) void mpnn_edge_atomic_kernel(
    const float* __restrict__ x, const float* __restrict__ pos,
    const int* __restrict__ ei0, const int* __restrict__ ei1,
    const float* __restrict__ W1, const float* __restrict__ b1,
    const float* __restrict__ W2, const float* __restrict__ b2,
    float* __restrict__ summed, float* __restrict__ counts, int E)
{
    __shared__ float s_in[EB][132];
    __shared__ int   s_idx[EB];

    const int tid  = threadIdx.x;
    const int base = blockIdx.x * EB;
    const int wv   = tid >> 6;
    const int lane = tid & 63;

    for (int e = wv; e < EB; e += 4) {
        const int ei = base + e;
        if (ei < E) {
            const int i = ei0[ei];
            const int j = ei1[ei];
            const float xi = x[(size_t)i * 64 + lane];
            const float xj = x[(size_t)j * 64 + lane];
            s_in[e][lane]      = xi;
            s_in[e][64 + lane] = xj - xi;
            if (lane < 3)
                s_in[e][128 + lane] = pos[(size_t)j * 3 + lane] - pos[(size_t)i * 3 + lane];
            if (lane == 0) s_idx[e] = i;
        } else {
            s_in[e][lane] = 0.f; s_in[e][64 + lane] = 0.f;
            if (lane < 3) s_in[e][128 + lane] = 0.f;
            if (lane == 0) s_idx[e] = -1;
        }
    }
    __syncthreads();

    float acc1[4][4];
    {
        const int cg = tid & 31;
        const int er = tid >> 5;
        const float4 bb = *(const float4*)(b1 + 4 * cg);
        #pragma unroll
        for (int t = 0; t < 4; ++t) {
            acc1[t][0] = bb.x; acc1[t][1] = bb.y; acc1[t][2] = bb.z; acc1[t][3] = bb.w;
        }
        for (int k = 0; k < 128; k += 4) {
            float wv4[4][4];
            #pragma unroll
            for (int kk = 0; kk < 4; ++kk) {
                const float4 w = *(const float4*)(W1 + (size_t)(k + kk) * 128 + 4 * cg);
                wv4[kk][0] = w.x; wv4[kk][1] = w.y; wv4[kk][2] = w.z; wv4[kk][3] = w.w;
            }
            #pragma unroll
            for (int t = 0; t < 4; ++t) {
                const float4 m = *(const float4*)(&s_in[er + 8 * t][k]);
                const float mm[4] = {m.x, m.y, m.z, m.w};
                #pragma unroll
                for (int kk = 0; kk < 4; ++kk)
                    #pragma unroll
                    for (int cc = 0; cc < 4; ++cc)
                        acc1[t][cc] += mm[kk] * wv4[kk][cc];
            }
        }
        for (int k = 128; k < 131; ++k) {
            float wk[4];
            #pragma unroll
            for (int cc = 0; cc < 4; ++cc) wk[cc] = W1[(size_t)k * 128 + 4 * cg + cc];
            #pragma unroll
            for (int t = 0; t < 4; ++t) {
                const float m = s_in[er + 8 * t][k];
                #pragma unroll
                for (int cc = 0; cc < 4; ++cc) acc1[t][cc] += m * wk[cc];
            }
        }
    }
    __syncthreads();
    {
        const int cg = tid & 31;
        const int er = tid >> 5;
        #pragma unroll
        for (int t = 0; t < 4; ++t)
            #pragma unroll
            for (int cc = 0; cc < 4; ++cc)
                s_in[er + 8 * t][4 * cg + cc] = fmaxf(acc1[t][cc], 0.f);
    }
    __syncthreads();
    {
        const int cg = tid & 15;
        const int er = tid >> 4;
        float acc[2][4];
        const float4 bb = *(const float4*)(b2 + 4 * cg);
        #pragma unroll
        for (int t = 0; t < 2; ++t) {
            acc[t][0] = bb.x; acc[t][1] = bb.y; acc[t][2] = bb.z; acc[t][3] = bb.w;
        }
        for (int k = 0; k < 128; k += 4) {
            float wv4[4][4];
            #pragma unroll
            for (int kk = 0; kk < 4; ++kk) {
                const float4 w = *(const float4*)(W2 + (size_t)(k + kk) * 64 + 4 * cg);
                wv4[kk][0] = w.x; wv4[kk][1] = w.y; wv4[kk][2] = w.z; wv4[kk][3] = w.w;
            }
            #pragma unroll
            for (int t = 0; t < 2; ++t) {
                const float4 m = *(const float4*)(&s_in[er + 16 * t][k]);
                const float mm[4] = {m.x, m.y, m.z, m.w};
                #pragma unroll
                for (int kk = 0; kk < 4; ++kk)
                    #pragma unroll
                    for (int cc = 0; cc < 4; ++cc)
                        acc[t][cc] += mm[kk] * wv4[kk][cc];
            }
        }
        #pragma unroll
        for (int t = 0; t < 2; ++t) {
            const int e = er + 16 * t;
            const int i = s_idx[e];
            if (i >= 0) {
                #pragma unroll
                for (int cc = 0; cc < 4; ++cc)
                    atomicAdd(&summed[(size_t)i * 64 + 4 * cg + cc], acc[t][cc]);
            }
        }
    }
    if (tid < EB) {
        const int i = s_idx[tid];
        if (i >= 0) atomicAdd(&counts[i], 1.0f);
    }
}

__global__ __launch_bounds__(256) void mpnn_node_legacy_kernel(
    const float* __restrict__ x, const float* __restrict__ summed,
    const float* __restrict__ counts,
    const float* __restrict__ W3, const float* __restrict__ b3,
    const float* __restrict__ W4, const float* __restrict__ b4,
    float* __restrict__ out, int N)
{
    __shared__ float s_in[NB][132];

    const int tid  = threadIdx.x;
    const int base = blockIdx.x * NB;
    const int wv   = tid >> 6;
    const int lane = tid & 63;

    for (int nl = wv; nl < NB; nl += 4) {
        const int n = base + nl;
        if (n < N) {
            s_in[nl][lane] = x[(size_t)n * 64 + lane];
            const float inv = 1.0f / fmaxf(counts[n], 1.0f);
            s_in[nl][64 + lane] = summed[(size_t)n * 64 + lane] * inv;
        } else {
            s_in[nl][lane] = 0.f; s_in[nl][64 + lane] = 0.f;
        }
    }
    __syncthreads();

    float acc1[4][4];
    {
        const int cg = tid & 31;
        const int er = tid >> 5;
        const float4 bb = *(const float4*)(b3 + 4 * cg);
        #pragma unroll
        for (int t = 0; t < 4; ++t) {
            acc1[t][0] = bb.x; acc1[t][1] = bb.y; acc1[t][2] = bb.z; acc1[t][3] = bb.w;
        }
        for (int k = 0; k < 128; k += 4) {
            float wv4[4][4];
            #pragma unroll
            for (int kk = 0; kk < 4; ++kk) {
                const float4 w = *(const float4*)(W3 + (size_t)(k + kk) * 128 + 4 * cg);
                wv4[kk][0] = w.x; wv4[kk][1] = w.y; wv4[kk][2] = w.z; wv4[kk][3] = w.w;
            }
            #pragma unroll
            for (int t = 0; t < 4; ++t) {
                const float4 m = *(const float4*)(&s_in[er + 8 * t][k]);
                const float mm[4] = {m.x, m.y, m.z, m.w};
                #pragma unroll
                for (int kk = 0; kk < 4; ++kk)
                    #pragma unroll
                    for (int cc = 0; cc < 4; ++cc)
                        acc1[t][cc] += mm[kk] * wv4[kk][cc];
            }
        }
    }
    __syncthreads();
    {
        const int cg = tid & 31;
        const int er = tid >> 5;
        #pragma unroll
        for (int t = 0; t < 4; ++t)
            #pragma unroll
            for (int cc = 0; cc < 4; ++cc)
                s_in[er + 8 * t][4 * cg + cc] = fmaxf(acc1[t][cc], 0.f);
    }
    __syncthreads();
    {
        const int cg = tid & 15;
        const int er = tid >> 4;
        float acc[2][4];
        const float4 bb = *(const float4*)(b4 + 4 * cg);
        #pragma unroll
        for (int t = 0; t < 2; ++t) {
            acc[t][0] = bb.x; acc[t][1] = bb.y; acc[t][2] = bb.z; acc[t][3] = bb.w;
        }
        for (int k = 0; k < 128; k += 4) {
            float wv4[4][4];
            #pragma unroll
            for (int kk = 0; kk < 4; ++kk) {
                const float4 w = *(const float4*)(W4 + (size_t)(k + kk) * 64 + 4 * cg);
                wv4[kk][0] = w.x; wv4[kk][1] = w.y; wv4[kk][2] = w.z; wv4[kk][3] = w.w;
            }
            #pragma unroll
            for (int t = 0; t < 2; ++t) {
                const float4 m = *(const float4*)(&s_in[er + 16 * t][k]);
                const float mm[4] = {m.x, m.y, m.z, m.w};
                #pragma unroll
                for (int kk = 0; kk < 4; ++kk)
                    #pragma unroll
                    for (int cc = 0; cc < 4; ++cc)
                        acc[t][cc] += mm[kk] * wv4[kk][cc];
            }
        }
        #pragma unroll
        for (int t = 0; t < 2; ++t) {
            const int n = base + er + 16 * t;
            if (n < N) {
                float4 o;
                o.x = acc[t][0]; o.y = acc[t][1]; o.z = acc[t][2]; o.w = acc[t][3];
                *(float4*)(out + (size_t)n * 64 + 4 * cg) = o;
            }
        }
    }
}

// ---------------- launch ----------------

extern "C" void kernel_launch(void* const* d_in, const int* in_sizes, int n_in,
                              void* d_out, int out_size, void* d_ws, size_t ws_size,
                              hipStream_t stream) {
    const float* x    = (const float*)d_in[0];
    const float* pos  = (const float*)d_in[1];
    const int*   eidx = (const int*)d_in[2];
    const float* W1   = (const float*)d_in[3];
    const float* b1   = (const float*)d_in[4];
    const float* W2   = (const float*)d_in[5];
    const float* b2   = (const float*)d_in[6];
    const float* W3   = (const float*)d_in[7];
    const float* b3   = (const float*)d_in[8];
    const float* W4   = (const float*)d_in[9];
    const float* b4   = (const float*)d_in[10];

    const int N = in_sizes[0] / 64;
    const int E = in_sizes[2] / 2;
    const int* ei0 = eidx;       // edge_index[0] = aggregation node i
    const int* ei1 = eidx + E;   // edge_index[1] = neighbor j

    // ws: msg bf16 [E,64] | W1p 40K | W2p 16K | W3p 32K | W4p 16K
    //     | cnt N | cur N | off N+1 | elist E
    const size_t msg_bytes = (size_t)E * 64 * 2;
    const size_t pack_bytes = (40 + 16 + 32 + 16) * 1024;
    const size_t need = msg_bytes + pack_bytes +
                        (size_t)N * 4 * 2 + (size_t)(N + 1) * 4 + (size_t)E * 4;

    if (ws_size >= need) {
        char* p = (char*)d_ws;
        unsigned short* msg = (unsigned short*)p;  p += msg_bytes;
        unsigned short* W1p = (unsigned short*)p;  p += 40 * 1024;
        unsigned short* W2p = (unsigned short*)p;  p += 16 * 1024;
        unsigned short* W3p = (unsigned short*)p;  p += 32 * 1024;
        unsigned short* W4p = (unsigned short*)p;  p += 16 * 1024;
        int* cnt   = (int*)p;  p += (size_t)N * 4;
        int* cur   = (int*)p;  p += (size_t)N * 4;
        int* off   = (int*)p;  p += (size_t)(N + 1) * 4;
        int* elist = (int*)p;

        hipMemsetAsync(cnt, 0, (size_t)N * 4 * 2, stream);  // cnt + cur

        pack_weights_kernel<<<104, 64, 0, stream>>>(W1, W2, W3, W4, W1p, W2p, W3p, W4p);

        const int eb256 = (E + 255) / 256;
        count_kernel<<<eb256, 256, 0, stream>>>(ei0, cnt, E);
        scan_kernel<<<1, 1024, 0, stream>>>(cnt, off, N);
        fill_kernel<<<eb256, 256, 0, stream>>>(ei0, off, cur, elist, E);

        edge_mlp_mfma<<<(E + EPB - 1) / EPB, 256, 0, stream>>>(
            x, pos, ei0, ei1, W1p, b1, W2p, b2, msg, E);

        node_mlp_mfma<<<(N + NPB - 1) / NPB, 256, 0, stream>>>(
            x, msg, off, cnt, elist, W3p, b3, W4p, b4, (float*)d_out, N);
    } else {
        // fallback: R1 atomic fp32 path
        float* summed = (float*)d_ws;
        float* counts = summed + (size_t)N * 64;
        hipMemsetAsync(d_ws, 0, ((size_t)N * 64 + N) * sizeof(float), stream);

        mpnn_edge_atomic_kernel<<<(E + EB - 1) / EB, 256, 0, stream>>>(
            x, pos, ei0, ei1, W1, b1, W2, b2, summed, counts, E);
        mpnn_node_legacy_kernel<<<(N + NB - 1) / NB, 256, 0, stream>>>(
            x, summed, counts, W3, b3, W4, b4, (float*)d_out, N);
    }
}

// Round 6
// 432.850 us; speedup vs baseline: 2.5166x; 1.2992x over previous
//
#include <hip/hip_runtime.h>

// MPNN: edge MLP (131->128->64) + scatter-mean + node MLP (128->128->64)
// N=50000, E=800000, fp32 in/out.
// R6: CSR-ORDERED edge processing. Edges are processed in elist order so
//  - x_i gathers are run-localized (same i for ~deg consecutive edges),
//  - msg[p] is written sequentially (coalesced, and the node kernel reads
//    its messages CONTIGUOUSLY [off[n],off[n+1]) -> streaming not random),
//  - fill_kernel pre-permutes (i,j) into an int2 list (no dependent
//    random ei0/ei1 load inside the edge kernel).
// Plus: x pre-cast to bf16 (6.4 MB, near-L2-resident, halves gather bytes)
// and a 3-phase scan (the R5 single-block scan was ~tens of µs serialized).
// MFMA geometry unchanged from R5 (16x16x32 bf16, packed B-frags).

#define EPB 128  // edges per block (4 waves x M=32)
#define NPB 64   // nodes per block (4 waves x M=16)

typedef __attribute__((ext_vector_type(8))) short bf16x8;
typedef __attribute__((ext_vector_type(4))) float f32x4;

static __device__ __forceinline__ unsigned short f2bf(float f) {
    union { float f; unsigned u; } v; v.f = f;
    unsigned u = v.u + 0x7FFFu + ((v.u >> 16) & 1u);  // RNE
    return (unsigned short)(u >> 16);
}
static __device__ __forceinline__ float bf2f(unsigned short h) {
    union { unsigned u; float f; } v; v.u = ((unsigned)h) << 16;
    return v.f;
}

// ---------------- x -> bf16 cast ----------------

__global__ __launch_bounds__(256) void xcast_kernel(
    const float* __restrict__ x, unsigned short* __restrict__ xb, int n)
{
    int i = (blockIdx.x * 256 + threadIdx.x) * 4;
    if (i < n) {
        const float4 v = *(const float4*)(x + i);
        ushort4 o;
        o.x = f2bf(v.x); o.y = f2bf(v.y); o.z = f2bf(v.z); o.w = f2bf(v.w);
        *(ushort4*)(xb + i) = o;
    }
}

// ---------------- CSR build ----------------

__global__ __launch_bounds__(256) void count_kernel(
    const int* __restrict__ ei0, int* __restrict__ cnt, int E)
{
    int e = blockIdx.x * 256 + threadIdx.x;
    if (e < E) atomicAdd(&cnt[ei0[e]], 1);
}

// 3-phase exclusive scan of cnt[N] -> off[N] (+ off[N] = total)
__global__ __launch_bounds__(1024) void scanA_kernel(
    const int* __restrict__ cnt, int* __restrict__ bsum, int N)
{
    __shared__ int ws[16];
    const int i = blockIdx.x * 1024 + threadIdx.x;
    int v = (i < N) ? cnt[i] : 0;
    #pragma unroll
    for (int d = 32; d >= 1; d >>= 1) v += __shfl_down(v, d, 64);
    if ((threadIdx.x & 63) == 0) ws[threadIdx.x >> 6] = v;
    __syncthreads();
    if (threadIdx.x == 0) {
        int s = 0;
        #pragma unroll
        for (int k = 0; k < 16; ++k) s += ws[k];
        bsum[blockIdx.x] = s;
    }
}

__global__ __launch_bounds__(64) void scanB_kernel(
    const int* __restrict__ bsum, int* __restrict__ boff,
    int* __restrict__ off, int N, int nb)
{
    const int l = threadIdx.x;
    if (nb <= 64) {
        const int v = (l < nb) ? bsum[l] : 0;
        int incl = v;
        #pragma unroll
        for (int d = 1; d < 64; d <<= 1) {
            int t = __shfl_up(incl, d, 64);
            if (l >= d) incl += t;
        }
        if (l < nb) boff[l] = incl - v;
        if (l == 63) off[N] = incl;  // grand total = E
    } else if (l == 0) {
        int s = 0;
        for (int k = 0; k < nb; ++k) { boff[k] = s; s += bsum[k]; }
        off[N] = s;
    }
}

__global__ __launch_bounds__(1024) void scanC_kernel(
    const int* __restrict__ cnt, const int* __restrict__ boff,
    int* __restrict__ off, int N)
{
    __shared__ int wsum[16];
    const int i = blockIdx.x * 1024 + threadIdx.x;
    const int lane = threadIdx.x & 63, w = threadIdx.x >> 6;
    const int v = (i < N) ? cnt[i] : 0;
    int incl = v;
    #pragma unroll
    for (int d = 1; d < 64; d <<= 1) {
        int t = __shfl_up(incl, d, 64);
        if (lane >= d) incl += t;
    }
    if (lane == 63) wsum[w] = incl;
    __syncthreads();
    int pre = 0;
    for (int k = 0; k < w; ++k) pre += wsum[k];
    if (i < N) off[i] = boff[blockIdx.x] + pre + incl - v;
}

// fill: CSR slot p gets the pre-permuted (i, j) pair (int2) — the edge
// kernel then needs no random ei0/ei1 indirection.
__global__ __launch_bounds__(256) void fill_kernel(
    const int* __restrict__ ei0, const int* __restrict__ ei1,
    const int* __restrict__ off, int* __restrict__ cur,
    int2* __restrict__ eij, int E)
{
    int e = blockIdx.x * 256 + threadIdx.x;
    if (e < E) {
        const int i = ei0[e];
        const int p = atomicAdd(&cur[i], 1);
        int2 v; v.x = i; v.y = ei1[e];
        eij[off[i] + p] = v;
    }
}

// ---------------- weight pre-pack into B-fragment order ----------------
// Frag (nt,ks) of W[K][N]: lane l, elem j holds W[ks*32+(l>>4)*8+j][nt*16+(l&15)]
// stored bf16 at out[frag*512 + l*8 + j].

__global__ __launch_bounds__(64) void pack_weights_kernel(
    const float* __restrict__ W1, const float* __restrict__ W2,
    const float* __restrict__ W3, const float* __restrict__ W4,
    unsigned short* __restrict__ W1p, unsigned short* __restrict__ W2p,
    unsigned short* __restrict__ W3p, unsigned short* __restrict__ W4p)
{
    int f = blockIdx.x;           // 0..103
    const int lane = threadIdx.x; // 0..63
    const float* W; unsigned short* out; int K, N, KS;
    if (f < 40)      { W = W1; out = W1p; K = 131; N = 128; KS = 5; }
    else if (f < 56) { W = W2; out = W2p; K = 128; N = 64;  KS = 4; f -= 40; }
    else if (f < 88) { W = W3; out = W3p; K = 128; N = 128; KS = 4; f -= 56; }
    else             { W = W4; out = W4p; K = 128; N = 64;  KS = 4; f -= 88; }
    const int nt = f / KS, ks = f % KS;
    const int n  = nt * 16 + (lane & 15);
    const int k0 = ks * 32 + (lane >> 4) * 8;
    unsigned short* dst = out + (size_t)f * 512 + lane * 8;
    #pragma unroll
    for (int j = 0; j < 8; ++j) {
        float v = (k0 + j < K) ? W[(size_t)(k0 + j) * N + n] : 0.f;
        dst[j] = f2bf(v);
    }
}

// ---------------- edge MLP (MFMA), CSR order -> sequential msg ----------------

__global__ __launch_bounds__(256) void edge_mlp_mfma(
    const unsigned short* __restrict__ xb, const float* __restrict__ pos,
    const int2* __restrict__ eij,
    const unsigned short* __restrict__ W1p, const float* __restrict__ b1,
    const unsigned short* __restrict__ W2p, const float* __restrict__ b2,
    unsigned short* __restrict__ msg, int E)
{
    // 128 rows x 168 bf16 = 336 B stride (21*16B, odd -> conflict-friendly)
    __shared__ unsigned short s_a[EPB][168];
    __shared__ int2 s_ij[EPB];

    const int tid  = threadIdx.x;
    const int wv   = tid >> 6;
    const int lane = tid & 63;
    const int r    = lane >> 4;   // quad
    const int c    = lane & 15;
    const int base = blockIdx.x * EPB;

    // preload the (i,j) tile (coalesced int2)
    if (tid < EPB) {
        const int p = base + tid;
        int2 v; v.x = -1; v.y = -1;
        if (p < E) v = eij[p];
        s_ij[tid] = v;
    }
    __syncthreads();

    // ---- stage [x_i | x_j-x_i | relpos | 0-pad] as bf16, K padded to 160
    #pragma unroll
    for (int it = 0; it < 8; ++it) {
        const int e = wv * 32 + it * 4 + r;   // 0..127, each once
        const int2 ij = s_ij[e];
        if (ij.x >= 0) {
            const ushort4 xi = *(const ushort4*)(xb + (size_t)ij.x * 64 + 4 * c);
            const ushort4 xj = *(const ushort4*)(xb + (size_t)ij.y * 64 + 4 * c);
            *(ushort4*)&s_a[e][4 * c] = xi;
            ushort4 d;
            d.x = f2bf(bf2f(xj.x) - bf2f(xi.x));
            d.y = f2bf(bf2f(xj.y) - bf2f(xi.y));
            d.z = f2bf(bf2f(xj.z) - bf2f(xi.z));
            d.w = f2bf(bf2f(xj.w) - bf2f(xi.w));
            *(ushort4*)&s_a[e][64 + 4 * c] = d;
            float pv = (c < 3) ? (pos[(size_t)ij.y * 3 + c] - pos[(size_t)ij.x * 3 + c]) : 0.f;
            s_a[e][128 + c] = f2bf(pv);
            s_a[e][144 + c] = 0;
        } else {
            ushort4 z; z.x = z.y = z.z = z.w = 0;
            *(ushort4*)&s_a[e][4 * c]      = z;
            *(ushort4*)&s_a[e][64 + 4 * c] = z;
            s_a[e][128 + c] = 0;
            s_a[e][144 + c] = 0;
        }
    }
    __syncthreads();

    // ---- load all layer-1 A-frags (then s_a is free for reuse)
    bf16x8 a1[2][5];
    #pragma unroll
    for (int mh = 0; mh < 2; ++mh)
        #pragma unroll
        for (int ks = 0; ks < 5; ++ks)
            a1[mh][ks] = *(const bf16x8*)&s_a[wv * 32 + mh * 16 + c][ks * 32 + r * 8];
    __syncthreads();

    // ---- layer 1: hidden = relu(A @ W1 + b1), N=128, K=160(pad)
    f32x4 acc1[2][8];
    #pragma unroll
    for (int nt = 0; nt < 8; ++nt) {
        const float bv = b1[nt * 16 + c];
        acc1[0][nt] = (f32x4){bv, bv, bv, bv};
        acc1[1][nt] = (f32x4){bv, bv, bv, bv};
    }
    #pragma unroll
    for (int nt = 0; nt < 8; ++nt)
        #pragma unroll
        for (int ks = 0; ks < 5; ++ks) {
            const bf16x8 b = *(const bf16x8*)(W1p + (size_t)(nt * 5 + ks) * 512 + lane * 8);
            acc1[0][nt] = __builtin_amdgcn_mfma_f32_16x16x32_bf16(a1[0][ks], b, acc1[0][nt], 0, 0, 0);
            acc1[1][nt] = __builtin_amdgcn_mfma_f32_16x16x32_bf16(a1[1][ks], b, acc1[1][nt], 0, 0, 0);
        }

    // ---- relu -> bf16 hidden back into s_a (cols 0..127)
    #pragma unroll
    for (int mh = 0; mh < 2; ++mh)
        #pragma unroll
        for (int nt = 0; nt < 8; ++nt)
            #pragma unroll
            for (int reg = 0; reg < 4; ++reg) {
                const int row = wv * 32 + mh * 16 + r * 4 + reg;
                s_a[row][nt * 16 + c] = f2bf(fmaxf(acc1[mh][nt][reg], 0.f));
            }
    __syncthreads();

    // ---- layer 2: msg = hidden @ W2 + b2, N=64, K=128
    bf16x8 a2[2][4];
    #pragma unroll
    for (int mh = 0; mh < 2; ++mh)
        #pragma unroll
        for (int ks = 0; ks < 4; ++ks)
            a2[mh][ks] = *(const bf16x8*)&s_a[wv * 32 + mh * 16 + c][ks * 32 + r * 8];
    __syncthreads();

    f32x4 acc2[2][4];
    #pragma unroll
    for (int nt = 0; nt < 4; ++nt) {
        const float bv = b2[nt * 16 + c];
        acc2[0][nt] = (f32x4){bv, bv, bv, bv};
        acc2[1][nt] = (f32x4){bv, bv, bv, bv};
    }
    #pragma unroll
    for (int nt = 0; nt < 4; ++nt)
        #pragma unroll
        for (int ks = 0; ks < 4; ++ks) {
            const bf16x8 b = *(const bf16x8*)(W2p + (size_t)(nt * 4 + ks) * 512 + lane * 8);
            acc2[0][nt] = __builtin_amdgcn_mfma_f32_16x16x32_bf16(a2[0][ks], b, acc2[0][nt], 0, 0, 0);
            acc2[1][nt] = __builtin_amdgcn_mfma_f32_16x16x32_bf16(a2[1][ks], b, acc2[1][nt], 0, 0, 0);
        }

    // ---- msg bf16 into s_a cols 0..63, then fully-sequential copy-out
    #pragma unroll
    for (int mh = 0; mh < 2; ++mh)
        #pragma unroll
        for (int nt = 0; nt < 4; ++nt)
            #pragma unroll
            for (int reg = 0; reg < 4; ++reg) {
                const int row = wv * 32 + mh * 16 + r * 4 + reg;
                s_a[row][nt * 16 + c] = f2bf(acc2[mh][nt][reg]);
            }
    __syncthreads();

    {
        const int e = tid >> 1, h = tid & 1;
        const int p = base + e;           // CSR slot: contiguous across block
        if (p < E) {
            const ushort4* src = (const ushort4*)&s_a[e][h * 32];
            ushort4* dst = (ushort4*)(msg + (size_t)p * 64 + h * 32);
            #pragma unroll
            for (int q = 0; q < 8; ++q) dst[q] = src[q];
        }
    }
}

// ---------------- gather-mean (contiguous!) + node MLP (MFMA) ----------------

__global__ __launch_bounds__(256) void node_mlp_mfma(
    const unsigned short* __restrict__ xb, const unsigned short* __restrict__ msg,
    const int* __restrict__ off,
    const unsigned short* __restrict__ W3p, const float* __restrict__ b3,
    const unsigned short* __restrict__ W4p, const float* __restrict__ b4,
    float* __restrict__ out, int N)
{
    // 64 rows x 136 bf16 = 272 B stride (17*16B, odd); also holds 64 fp32 out
    __shared__ unsigned short s_a[NPB][136];

    const int tid  = threadIdx.x;
    const int wv   = tid >> 6;
    const int lane = tid & 63;
    const int r    = lane >> 4;
    const int c    = lane & 15;
    const int base = blockIdx.x * NPB;

    // ---- stage [x | mean(msg)] as bf16; msg rows are CONTIGUOUS per node
    for (int nl = wv; nl < NPB; nl += 4) {
        const int n = base + nl;
        if (n < N) {
            s_a[nl][lane] = xb[(size_t)n * 64 + lane];
            const int o0 = off[n];
            const int o1 = off[n + 1];
            const int deg = o1 - o0;
            float a = 0.f;
            int p = o0;
            for (; p + 4 <= o1; p += 4) {
                const float m0 = bf2f(msg[(size_t)(p + 0) * 64 + lane]);
                const float m1 = bf2f(msg[(size_t)(p + 1) * 64 + lane]);
                const float m2 = bf2f(msg[(size_t)(p + 2) * 64 + lane]);
                const float m3 = bf2f(msg[(size_t)(p + 3) * 64 + lane]);
                a += (m0 + m1) + (m2 + m3);
            }
            for (; p < o1; ++p)
                a += bf2f(msg[(size_t)p * 64 + lane]);
            s_a[nl][64 + lane] = f2bf(a / (float)max(deg, 1));
        } else {
            s_a[nl][lane] = 0;
            s_a[nl][64 + lane] = 0;
        }
    }
    __syncthreads();

    // ---- layer 3: hidden = relu(A @ W3 + b3), M=16/wave, N=128, K=128
    bf16x8 a1[4];
    #pragma unroll
    for (int ks = 0; ks < 4; ++ks)
        a1[ks] = *(const bf16x8*)&s_a[wv * 16 + c][ks * 32 + r * 8];
    __syncthreads();

    f32x4 acc1[8];
    #pragma unroll
    for (int nt = 0; nt < 8; ++nt) {
        const float bv = b3[nt * 16 + c];
        acc1[nt] = (f32x4){bv, bv, bv, bv};
    }
    #pragma unroll
    for (int nt = 0; nt < 8; ++nt)
        #pragma unroll
        for (int ks = 0; ks < 4; ++ks) {
            const bf16x8 b = *(const bf16x8*)(W3p + (size_t)(nt * 4 + ks) * 512 + lane * 8);
            acc1[nt] = __builtin_amdgcn_mfma_f32_16x16x32_bf16(a1[ks], b, acc1[nt], 0, 0, 0);
        }
    #pragma unroll
    for (int nt = 0; nt < 8; ++nt)
        #pragma unroll
        for (int reg = 0; reg < 4; ++reg)
            s_a[wv * 16 + r * 4 + reg][nt * 16 + c] = f2bf(fmaxf(acc1[nt][reg], 0.f));
    __syncthreads();

    // ---- layer 4: out = hidden @ W4 + b4, N=64, K=128
    bf16x8 a2[4];
    #pragma unroll
    for (int ks = 0; ks < 4; ++ks)
        a2[ks] = *(const bf16x8*)&s_a[wv * 16 + c][ks * 32 + r * 8];
    __syncthreads();

    f32x4 acc2[4];
    #pragma unroll
    for (int nt = 0; nt < 4; ++nt) {
        const float bv = b4[nt * 16 + c];
        acc2[nt] = (f32x4){bv, bv, bv, bv};
    }
    #pragma unroll
    for (int nt = 0; nt < 4; ++nt)
        #pragma unroll
        for (int ks = 0; ks < 4; ++ks) {
            const bf16x8 b = *(const bf16x8*)(W4p + (size_t)(nt * 4 + ks) * 512 + lane * 8);
            acc2[nt] = __builtin_amdgcn_mfma_f32_16x16x32_bf16(a2[ks], b, acc2[nt], 0, 0, 0);
        }

    // ---- fp32 epilogue through LDS rows, then coalesced float4 stores
    #pragma unroll
    for (int nt = 0; nt < 4; ++nt)
        #pragma unroll
        for (int reg = 0; reg < 4; ++reg) {
            float* row = (float*)&s_a[wv * 16 + r * 4 + reg][0];
            row[nt * 16 + c] = acc2[nt][reg];
        }
    __syncthreads();

    {
        const int nl = tid >> 2, q = tid & 3;
        const int n = base + nl;
        if (n < N) {
            const float4* src = (const float4*)((const float*)&s_a[nl][0] + q * 16);
            float4* dst = (float4*)(out + (size_t)n * 64 + q * 16);
            #pragma unroll
            for (int u = 0; u < 4; ++u) dst[u] = src[u];
        }
    }
}

// ---------------- fallback (atomic fp32 path, if ws too small) ----------------

#define EB 32
#define NB 32

__global__ __launch_bounds__(256) void mpnn_edge_atomic_kernel(
    const float* __restrict__ x, const float* __restrict__ pos,
    const int* __restrict__ ei0, const int* __restrict__ ei1,
    const float* __restrict__ W1, const float* __restrict__ b1,
    const float* __restrict__ W2, const float* __restrict__ b2,
    float* __restrict__ summed, float* __restrict__ counts, int E)
{
    __shared__ float s_in[EB][132];
    __shared__ int   s_idx[EB];

    const int tid  = threadIdx.x;
    const int base = blockIdx.x * EB;
    const int wv   = tid >> 6;
    const int lane = tid & 63;

    for (int e = wv; e < EB; e += 4) {
        const int ei = base + e;
        if (ei < E) {
            const int i = ei0[ei];
            const int j = ei1[ei];
            const float xi = x[(size_t)i * 64 + lane];
            const float xj = x[(size_t)j * 64 + lane];
            s_in[e][lane]      = xi;
            s_in[e][64 + lane] = xj - xi;
            if (lane < 3)
                s_in[e][128 + lane] = pos[(size_t)j * 3 + lane] - pos[(size_t)i * 3 + lane];
            if (lane == 0) s_idx[e] = i;
        } else {
            s_in[e][lane] = 0.f; s_in[e][64 + lane] = 0.f;
            if (lane < 3) s_in[e][128 + lane] = 0.f;
            if (lane == 0) s_idx[e] = -1;
        }
    }
    __syncthreads();

    float acc1[4][4];
    {
        const int cg = tid & 31;
        const int er = tid >> 5;
        const float4 bb = *(const float4*)(b1 + 4 * cg);
        #pragma unroll
        for (int t = 0; t < 4; ++t) {
            acc1[t][0] = bb.x; acc1[t][1] = bb.y; acc1[t][2] = bb.z; acc1[t][3] = bb.w;
        }
        for (int k = 0; k < 128; k += 4) {
            float wv4[4][4];
            #pragma unroll
            for (int kk = 0; kk < 4; ++kk) {
                const float4 w = *(const float4*)(W1 + (size_t)(k + kk) * 128 + 4 * cg);
                wv4[kk][0] = w.x; wv4[kk][1] = w.y; wv4[kk][2] = w.z; wv4[kk][3] = w.w;
            }
            #pragma unroll
            for (int t = 0; t < 4; ++t) {
                const float4 m = *(const float4*)(&s_in[er + 8 * t][k]);
                const float mm[4] = {m.x, m.y, m.z, m.w};
                #pragma unroll
                for (int kk = 0; kk < 4; ++kk)
                    #pragma unroll
                    for (int cc = 0; cc < 4; ++cc)
                        acc1[t][cc] += mm[kk] * wv4[kk][cc];
            }
        }
        for (int k = 128; k < 131; ++k) {
            float wk[4];
            #pragma unroll
            for (int cc = 0; cc < 4; ++cc) wk[cc] = W1[(size_t)k * 128 + 4 * cg + cc];
            #pragma unroll
            for (int t = 0; t < 4; ++t) {
                const float m = s_in[er + 8 * t][k];
                #pragma unroll
                for (int cc = 0; cc < 4; ++cc) acc1[t][cc] += m * wk[cc];
            }
        }
    }
    __syncthreads();
    {
        const int cg = tid & 31;
        const int er = tid >> 5;
        #pragma unroll
        for (int t = 0; t < 4; ++t)
            #pragma unroll
            for (int cc = 0; cc < 4; ++cc)
                s_in[er + 8 * t][4 * cg + cc] = fmaxf(acc1[t][cc], 0.f);
    }
    __syncthreads();
    {
        const int cg = tid & 15;
        const int er = tid >> 4;
        float acc[2][4];
        const float4 bb = *(const float4*)(b2 + 4 * cg);
        #pragma unroll
        for (int t = 0; t < 2; ++t) {
            acc[t][0] = bb.x; acc[t][1] = bb.y; acc[t][2] = bb.z; acc[t][3] = bb.w;
        }
        for (int k = 0; k < 128; k += 4) {
            float wv4[4][4];
            #pragma unroll
            for (int kk = 0; kk < 4; ++kk) {
                const float4 w = *(const float4*)(W2 + (size_t)(k + kk) * 64 + 4 * cg);
                wv4[kk][0] = w.x; wv4[kk][1] = w.y; wv4[kk][2] = w.z; wv4[kk][3] = w.w;
            }
            #pragma unroll
            for (int t = 0; t < 2; ++t) {
                const float4 m = *(const float4*)(&s_in[er + 16 * t][k]);
                const float mm[4] = {m.x, m.y, m.z, m.w};
                #pragma unroll
                for (int kk = 0; kk < 4; ++kk)
                    #pragma unroll
                    for (int cc = 0; cc < 4; ++cc)
                        acc[t][cc] += mm[kk] * wv4[kk][cc];
            }
        }
        #pragma unroll
        for (int t = 0; t < 2; ++t) {
            const int e = er + 16 * t;
            const int i = s_idx[e];
            if (i >= 0) {
                #pragma unroll
                for (int cc = 0; cc < 4; ++cc)
                    atomicAdd(&summed[(size_t)i * 64 + 4 * cg + cc], acc[t][cc]);
            }
        }
    }
    if (tid < EB) {
        const int i = s_idx[tid];
        if (i >= 0) atomicAdd(&counts[i], 1.0f);
    }
}

__global__ __launch_bounds__(256) void mpnn_node_legacy_kernel(
    const float* __restrict__ x, const float* __restrict__ summed,
    const float* __restrict__ counts,
    const float* __restrict__ W3, const float* __restrict__ b3,
    const float* __restrict__ W4, const float* __restrict__ b4,
    float* __restrict__ out, int N)
{
    __shared__ float s_in[NB][132];

    const int tid  = threadIdx.x;
    const int base = blockIdx.x * NB;
    const int wv   = tid >> 6;
    const int lane = tid & 63;

    for (int nl = wv; nl < NB; nl += 4) {
        const int n = base + nl;
        if (n < N) {
            s_in[nl][lane] = x[(size_t)n * 64 + lane];
            const float inv = 1.0f / fmaxf(counts[n], 1.0f);
            s_in[nl][64 + lane] = summed[(size_t)n * 64 + lane] * inv;
        } else {
            s_in[nl][lane] = 0.f; s_in[nl][64 + lane] = 0.f;
        }
    }
    __syncthreads();

    float acc1[4][4];
    {
        const int cg = tid & 31;
        const int er = tid >> 5;
        const float4 bb = *(const float4*)(b3 + 4 * cg);
        #pragma unroll
        for (int t = 0; t < 4; ++t) {
            acc1[t][0] = bb.x; acc1[t][1] = bb.y; acc1[t][2] = bb.z; acc1[t][3] = bb.w;
        }
        for (int k = 0; k < 128; k += 4) {
            float wv4[4][4];
            #pragma unroll
            for (int kk = 0; kk < 4; ++kk) {
                const float4 w = *(const float4*)(W3 + (size_t)(k + kk) * 128 + 4 * cg);
                wv4[kk][0] = w.x; wv4[kk][1] = w.y; wv4[kk][2] = w.z; wv4[kk][3] = w.w;
            }
            #pragma unroll
            for (int t = 0; t < 4; ++t) {
                const float4 m = *(const float4*)(&s_in[er + 8 * t][k]);
                const float mm[4] = {m.x, m.y, m.z, m.w};
                #pragma unroll
                for (int kk = 0; kk < 4; ++kk)
                    #pragma unroll
                    for (int cc = 0; cc < 4; ++cc)
                        acc1[t][cc] += mm[kk] * wv4[kk][cc];
            }
        }
    }
    __syncthreads();
    {
        const int cg = tid & 31;
        const int er = tid >> 5;
        #pragma unroll
        for (int t = 0; t < 4; ++t)
            #pragma unroll
            for (int cc = 0; cc < 4; ++cc)
                s_in[er + 8 * t][4 * cg + cc] = fmaxf(acc1[t][cc], 0.f);
    }
    __syncthreads();
    {
        const int cg = tid & 15;
        const int er = tid >> 4;
        float acc[2][4];
        const float4 bb = *(const float4*)(b4 + 4 * cg);
        #pragma unroll
        for (int t = 0; t < 2; ++t) {
            acc[t][0] = bb.x; acc[t][1] = bb.y; acc[t][2] = bb.z; acc[t][3] = bb.w;
        }
        for (int k = 0; k < 128; k += 4) {
            float wv4[4][4];
            #pragma unroll
            for (int kk = 0; kk < 4; ++kk) {
                const float4 w = *(const float4*)(W4 + (size_t)(k + kk) * 64 + 4 * cg);
                wv4[kk][0] = w.x; wv4[kk][1] = w.y; wv4[kk][2] = w.z; wv4[kk][3] = w.w;
            }
            #pragma unroll
            for (int t = 0; t < 2; ++t) {
                const float4 m = *(const float4*)(&s_in[er + 16 * t][k]);
                const float mm[4] = {m.x, m.y, m.z, m.w};
                #pragma unroll
                for (int kk = 0; kk < 4; ++kk)
                    #pragma unroll
                    for (int cc = 0; cc < 4; ++cc)
                        acc[t][cc] += mm[kk] * wv4[kk][cc];
            }
        }
        #pragma unroll
        for (int t = 0; t < 2; ++t) {
            const int n = base + er + 16 * t;
            if (n < N) {
                float4 o;
                o.x = acc[t][0]; o.y = acc[t][1]; o.z = acc[t][2]; o.w = acc[t][3];
                *(float4*)(out + (size_t)n * 64 + 4 * cg) = o;
            }
        }
    }
}

// ---------------- launch ----------------

extern "C" void kernel_launch(void* const* d_in, const int* in_sizes, int n_in,
                              void* d_out, int out_size, void* d_ws, size_t ws_size,
                              hipStream_t stream) {
    const float* x    = (const float*)d_in[0];
    const float* pos  = (const float*)d_in[1];
    const int*   eidx = (const int*)d_in[2];
    const float* W1   = (const float*)d_in[3];
    const float* b1   = (const float*)d_in[4];
    const float* W2   = (const float*)d_in[5];
    const float* b2   = (const float*)d_in[6];
    const float* W3   = (const float*)d_in[7];
    const float* b3   = (const float*)d_in[8];
    const float* W4   = (const float*)d_in[9];
    const float* b4   = (const float*)d_in[10];

    const int N = in_sizes[0] / 64;
    const int E = in_sizes[2] / 2;
    const int* ei0 = eidx;       // edge_index[0] = aggregation node i
    const int* ei1 = eidx + E;   // edge_index[1] = neighbor j
    const int nb = (N + 1023) / 1024;

    // ws: msg bf16 [E,64] | xb bf16 [N,64] | W1p..W4p | cnt N | cur N
    //     | off N+1 | bsum 64 | boff 64 | eij int2[E]
    const size_t msg_bytes  = (size_t)E * 64 * 2;
    const size_t xb_bytes   = (size_t)N * 64 * 2;
    const size_t pack_bytes = (40 + 16 + 32 + 16) * 1024;
    const size_t need = msg_bytes + xb_bytes + pack_bytes +
                        (size_t)N * 4 * 2 + (size_t)(N + 1) * 4 +
                        2 * 64 * 4 + (size_t)E * 8;

    if (ws_size >= need) {
        char* p = (char*)d_ws;
        unsigned short* msg = (unsigned short*)p;  p += msg_bytes;
        unsigned short* xb  = (unsigned short*)p;  p += xb_bytes;
        unsigned short* W1p = (unsigned short*)p;  p += 40 * 1024;
        unsigned short* W2p = (unsigned short*)p;  p += 16 * 1024;
        unsigned short* W3p = (unsigned short*)p;  p += 32 * 1024;
        unsigned short* W4p = (unsigned short*)p;  p += 16 * 1024;
        int* cnt  = (int*)p;  p += (size_t)N * 4;
        int* cur  = (int*)p;  p += (size_t)N * 4;
        int* off  = (int*)p;  p += (size_t)(N + 1) * 4;
        int* bsum = (int*)p;  p += 64 * 4;
        int* boff = (int*)p;  p += 64 * 4;
        int2* eij = (int2*)p;

        hipMemsetAsync(cnt, 0, (size_t)N * 4 * 2, stream);  // cnt + cur

        xcast_kernel<<<(N * 64 / 4 + 255) / 256, 256, 0, stream>>>(x, xb, N * 64);
        pack_weights_kernel<<<104, 64, 0, stream>>>(W1, W2, W3, W4, W1p, W2p, W3p, W4p);

        const int eb256 = (E + 255) / 256;
        count_kernel<<<eb256, 256, 0, stream>>>(ei0, cnt, E);
        scanA_kernel<<<nb, 1024, 0, stream>>>(cnt, bsum, N);
        scanB_kernel<<<1, 64, 0, stream>>>(bsum, boff, off, N, nb);
        scanC_kernel<<<nb, 1024, 0, stream>>>(cnt, boff, off, N);
        fill_kernel<<<eb256, 256, 0, stream>>>(ei0, ei1, off, cur, eij, E);

        edge_mlp_mfma<<<(E + EPB - 1) / EPB, 256, 0, stream>>>(
            xb, pos, eij, W1p, b1, W2p, b2, msg, E);

        node_mlp_mfma<<<(N + NPB - 1) / NPB, 256, 0, stream>>>(
            xb, msg, off, W3p, b3, W4p, b4, (float*)d_out, N);
    } else {
        // fallback: atomic fp32 path
        float* summed = (float*)d_ws;
        float* counts = summed + (size_t)N * 64;
        hipMemsetAsync(d_ws, 0, ((size_t)N * 64 + N) * sizeof(float), stream);

        mpnn_edge_atomic_kernel<<<(E + EB - 1) / EB, 256, 0, stream>>>(
            x, pos, ei0, ei1, W1, b1, W2, b2, summed, counts, E);
        mpnn_node_legacy_kernel<<<(N + NB - 1) / NB, 256, 0, stream>>>(
            x, summed, counts, W3, b3, W4, b4, (float*)d_out, N);
    }
}

// Round 7
// 322.869 us; speedup vs baseline: 3.3739x; 1.3406x over previous
//
#include <hip/hip_runtime.h>

// MPNN: edge MLP (131->128->64) + scatter-mean + node MLP (128->128->64)
// N=50000, E=800000, fp32 in/out.
// R7: ALGEBRAIC FACTORIZATION of edge layer-1 through per-node projections:
//   hidden = relu(P[i] + Q[j]),  P = x@(W1a-W1b) - pos@W1c + b1,
//                                Q = x@W1b       + pos@W1c
// (exact regrouping of relu(xi@W1a+(xj-xi)@W1b+(pj-pi)@W1c+b1)).
// P,Q precomputed by one tiny MFMA GEMM (N x 96 x 256, ~2.4 GFLOP) stored
// bf16 interleaved PQ[n][256]. Edge kernel: gather P[i],Q[j] chunks DIRECTLY
// into layer-2 A-frag registers (zero staging LDS, zero transpose), add+relu,
// 32 MFMA, one 16KB LDS roundtrip for coalesced msg store. LDS 44->19.5KB.
// CSR order from R6 kept (sequential msg, contiguous node gather).

#define EPB 128  // edges per block (4 waves x M=32)
#define NPB 64   // nodes per block (4 waves x M=16)

typedef __attribute__((ext_vector_type(8))) short bf16x8;
typedef __attribute__((ext_vector_type(4))) float f32x4;

static __device__ __forceinline__ unsigned short f2bf(float f) {
    union { float f; unsigned u; } v; v.f = f;
    unsigned u = v.u + 0x7FFFu + ((v.u >> 16) & 1u);  // RNE
    return (unsigned short)(u >> 16);
}
static __device__ __forceinline__ float bf2f(unsigned short h) {
    union { unsigned u; float f; } v; v.u = ((unsigned)h) << 16;
    return v.f;
}

// ---------------- CSR build ----------------

__global__ __launch_bounds__(256) void count_kernel(
    const int* __restrict__ ei0, int* __restrict__ cnt, int E)
{
    int e = blockIdx.x * 256 + threadIdx.x;
    if (e < E) atomicAdd(&cnt[ei0[e]], 1);
}

__global__ __launch_bounds__(1024) void scanA_kernel(
    const int* __restrict__ cnt, int* __restrict__ bsum, int N)
{
    __shared__ int ws[16];
    const int i = blockIdx.x * 1024 + threadIdx.x;
    int v = (i < N) ? cnt[i] : 0;
    #pragma unroll
    for (int d = 32; d >= 1; d >>= 1) v += __shfl_down(v, d, 64);
    if ((threadIdx.x & 63) == 0) ws[threadIdx.x >> 6] = v;
    __syncthreads();
    if (threadIdx.x == 0) {
        int s = 0;
        #pragma unroll
        for (int k = 0; k < 16; ++k) s += ws[k];
        bsum[blockIdx.x] = s;
    }
}

// scanC computes its own block offset from bsum (merged old scanB) and
// writes off[N] = E.
__global__ __launch_bounds__(1024) void scanC_kernel(
    const int* __restrict__ cnt, const int* __restrict__ bsum,
    int* __restrict__ off, int N, int Etot)
{
    __shared__ int wsum[16];
    __shared__ int boffs;
    const int i = blockIdx.x * 1024 + threadIdx.x;
    const int lane = threadIdx.x & 63, w = threadIdx.x >> 6;
    if (threadIdx.x < 64) {
        int acc = 0;
        for (int k = threadIdx.x; k < blockIdx.x; k += 64) acc += bsum[k];
        #pragma unroll
        for (int d = 32; d >= 1; d >>= 1) acc += __shfl_down(acc, d, 64);
        if (threadIdx.x == 0) boffs = acc;
    }
    const int v = (i < N) ? cnt[i] : 0;
    int incl = v;
    #pragma unroll
    for (int d = 1; d < 64; d <<= 1) {
        int t = __shfl_up(incl, d, 64);
        if (lane >= d) incl += t;
    }
    if (lane == 63) wsum[w] = incl;
    __syncthreads();
    int pre = 0;
    for (int k = 0; k < w; ++k) pre += wsum[k];
    if (i < N) off[i] = boffs + pre + incl - v;
    if (blockIdx.x == 0 && threadIdx.x == 0) off[N] = Etot;
}

__global__ __launch_bounds__(256) void fill_kernel(
    const int* __restrict__ ei0, const int* __restrict__ ei1,
    const int* __restrict__ off, int* __restrict__ cur,
    int2* __restrict__ eij, int E)
{
    int e = blockIdx.x * 256 + threadIdx.x;
    if (e < E) {
        const int i = ei0[e];
        const int p = atomicAdd(&cur[i], 1);
        int2 v; v.x = i; v.y = ei1[e];
        eij[off[i] + p] = v;
    }
}

// ---------------- weight pre-pack into B-fragment order ----------------
// f<48: Wc[96][256] combined layer-1 projection (KS=3, 16 nt):
//   col n<128 (P): k<64 -> W1[k][n]-W1[64+k][n]; 64<=k<67 -> -W1[128+k-64][n]
//   col n>=128 (Q): k<64 -> W1[64+k][n-128];     64<=k<67 ->  W1[128+k-64][n-128]
// f<64: W2p; f<96: W3p; f<112: W4p (as before).
// Frag layout: lane l elem j = W[ks*32+(l>>4)*8+j][nt*16+(l&15)].

__global__ __launch_bounds__(64) void pack_weights_kernel(
    const float* __restrict__ W1, const float* __restrict__ W2,
    const float* __restrict__ W3, const float* __restrict__ W4,
    unsigned short* __restrict__ Wcp, unsigned short* __restrict__ W2p,
    unsigned short* __restrict__ W3p, unsigned short* __restrict__ W4p)
{
    int f = blockIdx.x;           // 0..111
    const int lane = threadIdx.x; // 0..63
    if (f < 48) {
        const int nt = f / 3, ks = f % 3;
        const int n  = nt * 16 + (lane & 15);
        const int k0 = ks * 32 + (lane >> 4) * 8;
        unsigned short* dst = Wcp + (size_t)f * 512 + lane * 8;
        #pragma unroll
        for (int j = 0; j < 8; ++j) {
            const int k = k0 + j;
            float v = 0.f;
            if (n < 128) {          // P-part
                if (k < 64)       v = W1[(size_t)k * 128 + n] - W1[(size_t)(64 + k) * 128 + n];
                else if (k < 67)  v = -W1[(size_t)(128 + k - 64) * 128 + n];
            } else {                // Q-part
                const int nq = n - 128;
                if (k < 64)       v = W1[(size_t)(64 + k) * 128 + nq];
                else if (k < 67)  v = W1[(size_t)(128 + k - 64) * 128 + nq];
            }
            dst[j] = f2bf(v);
        }
        return;
    }
    const float* W; unsigned short* out; int K, N, KS;
    if (f < 64)      { W = W2; out = W2p; K = 128; N = 64;  KS = 4; f -= 48; }
    else if (f < 96) { W = W3; out = W3p; K = 128; N = 128; KS = 4; f -= 64; }
    else             { W = W4; out = W4p; K = 128; N = 64;  KS = 4; f -= 96; }
    const int nt = f / KS, ks = f % KS;
    const int n  = nt * 16 + (lane & 15);
    const int k0 = ks * 32 + (lane >> 4) * 8;
    unsigned short* dst = out + (size_t)f * 512 + lane * 8;
    #pragma unroll
    for (int j = 0; j < 8; ++j) {
        float v = (k0 + j < K) ? W[(size_t)(k0 + j) * N + n] : 0.f;
        dst[j] = f2bf(v);
    }
}

// ---------------- per-node projection GEMM: PQ = [x|pos] @ Wc (+b1 on P) ----

__global__ __launch_bounds__(256) void pq_kernel(
    const float* __restrict__ x, const float* __restrict__ pos,
    const unsigned short* __restrict__ Wcp, const float* __restrict__ b1,
    unsigned short* __restrict__ PQ, int N)
{
    __shared__ unsigned short s[NPB][104];  // 96 cols + 8 pad (13*16B, odd)

    const int tid  = threadIdx.x;
    const int wv   = tid >> 6;
    const int lane = tid & 63;
    const int r    = lane >> 4;
    const int c    = lane & 15;
    const int base = blockIdx.x * NPB;

    for (int nl = wv; nl < NPB; nl += 4) {
        const int n = base + nl;
        s[nl][lane] = (n < N) ? f2bf(x[(size_t)n * 64 + lane]) : 0;
        if (lane < 32)
            s[nl][64 + lane] = (n < N && lane < 3) ? f2bf(pos[(size_t)n * 3 + lane]) : 0;
    }
    __syncthreads();

    bf16x8 a[3];
    #pragma unroll
    for (int ks = 0; ks < 3; ++ks)
        a[ks] = *(const bf16x8*)&s[wv * 16 + c][ks * 32 + r * 8];

    f32x4 acc[16];
    #pragma unroll
    for (int nt = 0; nt < 16; ++nt) {
        const float bv = (nt < 8) ? b1[nt * 16 + c] : 0.f;  // bias folded into P
        acc[nt] = (f32x4){bv, bv, bv, bv};
    }
    #pragma unroll
    for (int nt = 0; nt < 16; ++nt)
        #pragma unroll
        for (int ks = 0; ks < 3; ++ks) {
            const bf16x8 b = *(const bf16x8*)(Wcp + (size_t)(nt * 3 + ks) * 512 + lane * 8);
            acc[nt] = __builtin_amdgcn_mfma_f32_16x16x32_bf16(a[ks], b, acc[nt], 0, 0, 0);
        }

    #pragma unroll
    for (int nt = 0; nt < 16; ++nt)
        #pragma unroll
        for (int reg = 0; reg < 4; ++reg) {
            const int n = base + wv * 16 + r * 4 + reg;
            if (n < N) PQ[(size_t)n * 256 + nt * 16 + c] = f2bf(acc[nt][reg]);
        }
}

// ---------------- edge kernel: hidden = relu(P[i]+Q[j]) -> layer-2 MFMA ----

__global__ __launch_bounds__(256) void edge_mlp_mfma(
    const unsigned short* __restrict__ PQ, const int2* __restrict__ eij,
    const unsigned short* __restrict__ W2p, const float* __restrict__ b2,
    unsigned short* __restrict__ msg, int E)
{
    __shared__ unsigned short s_m[EPB][72];  // 64 cols + 8 pad (9*16B, odd)
    __shared__ int2 s_ij[EPB];

    const int tid  = threadIdx.x;
    const int wv   = tid >> 6;
    const int lane = tid & 63;
    const int r    = lane >> 4;
    const int c    = lane & 15;
    const int base = blockIdx.x * EPB;

    if (tid < EPB) {
        const int p = base + tid;
        int2 v; v.x = 0; v.y = 0;           // pad edges read node 0 (valid mem)
        if (p < E) v = eij[p];
        s_ij[tid] = v;
    }
    __syncthreads();

    // ---- build layer-2 A-frags in registers: a[mh][ks][j] = relu(P[i][k]+Q[j][k])
    bf16x8 a2[2][4];
    #pragma unroll
    for (int mh = 0; mh < 2; ++mh) {
        const int2 ij = s_ij[wv * 32 + mh * 16 + c];
        const unsigned short* Pi = PQ + (size_t)ij.x * 256;
        const unsigned short* Qj = PQ + (size_t)ij.y * 256 + 128;
        #pragma unroll
        for (int ks = 0; ks < 4; ++ks) {
            const bf16x8 pp = *(const bf16x8*)(Pi + ks * 32 + r * 8);
            const bf16x8 qq = *(const bf16x8*)(Qj + ks * 32 + r * 8);
            bf16x8 h;
            #pragma unroll
            for (int t = 0; t < 8; ++t) {
                const float v = bf2f((unsigned short)pp[t]) + bf2f((unsigned short)qq[t]);
                h[t] = (short)f2bf(fmaxf(v, 0.f));
            }
            a2[mh][ks] = h;
        }
    }

    // ---- layer 2: msg = hidden @ W2 + b2, N=64, K=128
    f32x4 acc2[2][4];
    #pragma unroll
    for (int nt = 0; nt < 4; ++nt) {
        const float bv = b2[nt * 16 + c];
        acc2[0][nt] = (f32x4){bv, bv, bv, bv};
        acc2[1][nt] = (f32x4){bv, bv, bv, bv};
    }
    #pragma unroll
    for (int nt = 0; nt < 4; ++nt)
        #pragma unroll
        for (int ks = 0; ks < 4; ++ks) {
            const bf16x8 b = *(const bf16x8*)(W2p + (size_t)(nt * 4 + ks) * 512 + lane * 8);
            acc2[0][nt] = __builtin_amdgcn_mfma_f32_16x16x32_bf16(a2[0][ks], b, acc2[0][nt], 0, 0, 0);
            acc2[1][nt] = __builtin_amdgcn_mfma_f32_16x16x32_bf16(a2[1][ks], b, acc2[1][nt], 0, 0, 0);
        }

    // ---- msg bf16 via LDS, then fully-sequential coalesced copy-out
    #pragma unroll
    for (int mh = 0; mh < 2; ++mh)
        #pragma unroll
        for (int nt = 0; nt < 4; ++nt)
            #pragma unroll
            for (int reg = 0; reg < 4; ++reg) {
                const int row = wv * 32 + mh * 16 + r * 4 + reg;
                s_m[row][nt * 16 + c] = f2bf(acc2[mh][nt][reg]);
            }
    __syncthreads();

    {
        const int e = tid >> 1, h = tid & 1;
        const int p = base + e;   // CSR slot: contiguous across block
        if (p < E) {
            const ushort4* src = (const ushort4*)&s_m[e][h * 32];
            ushort4* dst = (ushort4*)(msg + (size_t)p * 64 + h * 32);
            #pragma unroll
            for (int q = 0; q < 8; ++q) dst[q] = src[q];
        }
    }
}

// ---------------- gather-mean (contiguous) + node MLP (MFMA) ----------------

__global__ __launch_bounds__(256) void node_mlp_mfma(
    const float* __restrict__ x, const unsigned short* __restrict__ msg,
    const int* __restrict__ off,
    const unsigned short* __restrict__ W3p, const float* __restrict__ b3,
    const unsigned short* __restrict__ W4p, const float* __restrict__ b4,
    float* __restrict__ out, int N)
{
    __shared__ unsigned short s_a[NPB][136];  // 128 + 8 pad (17*16B, odd)

    const int tid  = threadIdx.x;
    const int wv   = tid >> 6;
    const int lane = tid & 63;
    const int r    = lane >> 4;
    const int c    = lane & 15;
    const int base = blockIdx.x * NPB;

    for (int nl = wv; nl < NPB; nl += 4) {
        const int n = base + nl;
        if (n < N) {
            s_a[nl][lane] = f2bf(x[(size_t)n * 64 + lane]);
            const int o0 = off[n];
            const int o1 = off[n + 1];
            const int deg = o1 - o0;
            float a = 0.f;
            int p = o0;
            for (; p + 4 <= o1; p += 4) {
                const float m0 = bf2f(msg[(size_t)(p + 0) * 64 + lane]);
                const float m1 = bf2f(msg[(size_t)(p + 1) * 64 + lane]);
                const float m2 = bf2f(msg[(size_t)(p + 2) * 64 + lane]);
                const float m3 = bf2f(msg[(size_t)(p + 3) * 64 + lane]);
                a += (m0 + m1) + (m2 + m3);
            }
            for (; p < o1; ++p)
                a += bf2f(msg[(size_t)p * 64 + lane]);
            s_a[nl][64 + lane] = f2bf(a / (float)max(deg, 1));
        } else {
            s_a[nl][lane] = 0;
            s_a[nl][64 + lane] = 0;
        }
    }
    __syncthreads();

    bf16x8 a1[4];
    #pragma unroll
    for (int ks = 0; ks < 4; ++ks)
        a1[ks] = *(const bf16x8*)&s_a[wv * 16 + c][ks * 32 + r * 8];
    __syncthreads();

    f32x4 acc1[8];
    #pragma unroll
    for (int nt = 0; nt < 8; ++nt) {
        const float bv = b3[nt * 16 + c];
        acc1[nt] = (f32x4){bv, bv, bv, bv};
    }
    #pragma unroll
    for (int nt = 0; nt < 8; ++nt)
        #pragma unroll
        for (int ks = 0; ks < 4; ++ks) {
            const bf16x8 b = *(const bf16x8*)(W3p + (size_t)(nt * 4 + ks) * 512 + lane * 8);
            acc1[nt] = __builtin_amdgcn_mfma_f32_16x16x32_bf16(a1[ks], b, acc1[nt], 0, 0, 0);
        }
    #pragma unroll
    for (int nt = 0; nt < 8; ++nt)
        #pragma unroll
        for (int reg = 0; reg < 4; ++reg)
            s_a[wv * 16 + r * 4 + reg][nt * 16 + c] = f2bf(fmaxf(acc1[nt][reg], 0.f));
    __syncthreads();

    bf16x8 a2[4];
    #pragma unroll
    for (int ks = 0; ks < 4; ++ks)
        a2[ks] = *(const bf16x8*)&s_a[wv * 16 + c][ks * 32 + r * 8];
    __syncthreads();

    f32x4 acc2[4];
    #pragma unroll
    for (int nt = 0; nt < 4; ++nt) {
        const float bv = b4[nt * 16 + c];
        acc2[nt] = (f32x4){bv, bv, bv, bv};
    }
    #pragma unroll
    for (int nt = 0; nt < 4; ++nt)
        #pragma unroll
        for (int ks = 0; ks < 4; ++ks) {
            const bf16x8 b = *(const bf16x8*)(W4p + (size_t)(nt * 4 + ks) * 512 + lane * 8);
            acc2[nt] = __builtin_amdgcn_mfma_f32_16x16x32_bf16(a2[ks], b, acc2[nt], 0, 0, 0);
        }

    #pragma unroll
    for (int nt = 0; nt < 4; ++nt)
        #pragma unroll
        for (int reg = 0; reg < 4; ++reg) {
            float* row = (float*)&s_a[wv * 16 + r * 4 + reg][0];
            row[nt * 16 + c] = acc2[nt][reg];
        }
    __syncthreads();

    {
        const int nl = tid >> 2, q = tid & 3;
        const int n = base + nl;
        if (n < N) {
            const float4* src = (const float4*)((const float*)&s_a[nl][0] + q * 16);
            float4* dst = (float4*)(out + (size_t)n * 64 + q * 16);
            #pragma unroll
            for (int u = 0; u < 4; ++u) dst[u] = src[u];
        }
    }
}

// ---------------- fallback (atomic fp32 path, if ws too small) ----------------

#define EB 32
#define NB 32

__global__ __launch_bounds__(256) void mpnn_edge_atomic_kernel(
    const float* __restrict__ x, const float* __restrict__ pos,
    const int* __restrict__ ei0, const int* __restrict__ ei1,
    const float* __restrict__ W1, const float* __restrict__ b1,
    const float* __restrict__ W2, const float* __restrict__ b2,
    float* __restrict__ summed, float* __restrict__ counts, int E)
{
    __shared__ float s_in[EB][132];
    __shared__ int   s_idx[EB];

    const int tid  = threadIdx.x;
    const int base = blockIdx.x * EB;
    const int wv   = tid >> 6;
    const int lane = tid & 63;

    for (int e = wv; e < EB; e += 4) {
        const int ei = base + e;
        if (ei < E) {
            const int i = ei0[ei];
            const int j = ei1[ei];
            const float xi = x[(size_t)i * 64 + lane];
            const float xj = x[(size_t)j * 64 + lane];
            s_in[e][lane]      = xi;
            s_in[e][64 + lane] = xj - xi;
            if (lane < 3)
                s_in[e][128 + lane] = pos[(size_t)j * 3 + lane] - pos[(size_t)i * 3 + lane];
            if (lane == 0) s_idx[e] = i;
        } else {
            s_in[e][lane] = 0.f; s_in[e][64 + lane] = 0.f;
            if (lane < 3) s_in[e][128 + lane] = 0.f;
            if (lane == 0) s_idx[e] = -1;
        }
    }
    __syncthreads();

    float acc1[4][4];
    {
        const int cg = tid & 31;
        const int er = tid >> 5;
        const float4 bb = *(const float4*)(b1 + 4 * cg);
        #pragma unroll
        for (int t = 0; t < 4; ++t) {
            acc1[t][0] = bb.x; acc1[t][1] = bb.y; acc1[t][2] = bb.z; acc1[t][3] = bb.w;
        }
        for (int k = 0; k < 128; k += 4) {
            float wv4[4][4];
            #pragma unroll
            for (int kk = 0; kk < 4; ++kk) {
                const float4 w = *(const float4*)(W1 + (size_t)(k + kk) * 128 + 4 * cg);
                wv4[kk][0] = w.x; wv4[kk][1] = w.y; wv4[kk][2] = w.z; wv4[kk][3] = w.w;
            }
            #pragma unroll
            for (int t = 0; t < 4; ++t) {
                const float4 m = *(const float4*)(&s_in[er + 8 * t][k]);
                const float mm[4] = {m.x, m.y, m.z, m.w};
                #pragma unroll
                for (int kk = 0; kk < 4; ++kk)
                    #pragma unroll
                    for (int cc = 0; cc < 4; ++cc)
                        acc1[t][cc] += mm[kk] * wv4[kk][cc];
            }
        }
        for (int k = 128; k < 131; ++k) {
            float wk[4];
            #pragma unroll
            for (int cc = 0; cc < 4; ++cc) wk[cc] = W1[(size_t)k * 128 + 4 * cg + cc];
            #pragma unroll
            for (int t = 0; t < 4; ++t) {
                const float m = s_in[er + 8 * t][k];
                #pragma unroll
                for (int cc = 0; cc < 4; ++cc) acc1[t][cc] += m * wk[cc];
            }
        }
    }
    __syncthreads();
    {
        const int cg = tid & 31;
        const int er = tid >> 5;
        #pragma unroll
        for (int t = 0; t < 4; ++t)
            #pragma unroll
            for (int cc = 0; cc < 4; ++cc)
                s_in[er + 8 * t][4 * cg + cc] = fmaxf(acc1[t][cc], 0.f);
    }
    __syncthreads();
    {
        const int cg = tid & 15;
        const int er = tid >> 4;
        float acc[2][4];
        const float4 bb = *(const float4*)(b2 + 4 * cg);
        #pragma unroll
        for (int t = 0; t < 2; ++t) {
            acc[t][0] = bb.x; acc[t][1] = bb.y; acc[t][2] = bb.z; acc[t][3] = bb.w;
        }
        for (int k = 0; k < 128; k += 4) {
            float wv4[4][4];
            #pragma unroll
            for (int kk = 0; kk < 4; ++kk) {
                const float4 w = *(const float4*)(W2 + (size_t)(k + kk) * 64 + 4 * cg);
                wv4[kk][0] = w.x; wv4[kk][1] = w.y; wv4[kk][2] = w.z; wv4[kk][3] = w.w;
            }
            #pragma unroll
            for (int t = 0; t < 2; ++t) {
                const float4 m = *(const float4*)(&s_in[er + 16 * t][k]);
                const float mm[4] = {m.x, m.y, m.z, m.w};
                #pragma unroll
                for (int kk = 0; kk < 4; ++kk)
                    #pragma unroll
                    for (int cc = 0; cc < 4; ++cc)
                        acc[t][cc] += mm[kk] * wv4[kk][cc];
            }
        }
        #pragma unroll
        for (int t = 0; t < 2; ++t) {
            const int e = er + 16 * t;
            const int i = s_idx[e];
            if (i >= 0) {
                #pragma unroll
                for (int cc = 0; cc < 4; ++cc)
                    atomicAdd(&summed[(size_t)i * 64 + 4 * cg + cc], acc[t][cc]);
            }
        }
    }
    if (tid < EB) {
        const int i = s_idx[tid];
        if (i >= 0) atomicAdd(&counts[i], 1.0f);
    }
}

__global__ __launch_bounds__(256) void mpnn_node_legacy_kernel(
    const float* __restrict__ x, const float* __restrict__ summed,
    const float* __restrict__ counts,
    const float* __restrict__ W3, const float* __restrict__ b3,
    const float* __restrict__ W4, const float* __restrict__ b4,
    float* __restrict__ out, int N)
{
    __shared__ float s_in[NB][132];

    const int tid  = threadIdx.x;
    const int base = blockIdx.x * NB;
    const int wv   = tid >> 6;
    const int lane = tid & 63;

    for (int nl = wv; nl < NB; nl += 4) {
        const int n = base + nl;
        if (n < N) {
            s_in[nl][lane] = x[(size_t)n * 64 + lane];
            const float inv = 1.0f / fmaxf(counts[n], 1.0f);
            s_in[nl][64 + lane] = summed[(size_t)n * 64 + lane] * inv;
        } else {
            s_in[nl][lane] = 0.f; s_in[nl][64 + lane] = 0.f;
        }
    }
    __syncthreads();

    float acc1[4][4];
    {
        const int cg = tid & 31;
        const int er = tid >> 5;
        const float4 bb = *(const float4*)(b3 + 4 * cg);
        #pragma unroll
        for (int t = 0; t < 4; ++t) {
            acc1[t][0] = bb.x; acc1[t][1] = bb.y; acc1[t][2] = bb.z; acc1[t][3] = bb.w;
        }
        for (int k = 0; k < 128; k += 4) {
            float wv4[4][4];
            #pragma unroll
            for (int kk = 0; kk < 4; ++kk) {
                const float4 w = *(const float4*)(W3 + (size_t)(k + kk) * 128 + 4 * cg);
                wv4[kk][0] = w.x; wv4[kk][1] = w.y; wv4[kk][2] = w.z; wv4[kk][3] = w.w;
            }
            #pragma unroll
            for (int t = 0; t < 4; ++t) {
                const float4 m = *(const float4*)(&s_in[er + 8 * t][k]);
                const float mm[4] = {m.x, m.y, m.z, m.w};
                #pragma unroll
                for (int kk = 0; kk < 4; ++kk)
                    #pragma unroll
                    for (int cc = 0; cc < 4; ++cc)
                        acc1[t][cc] += mm[kk] * wv4[kk][cc];
            }
        }
    }
    __syncthreads();
    {
        const int cg = tid & 31;
        const int er = tid >> 5;
        #pragma unroll
        for (int t = 0; t < 4; ++t)
            #pragma unroll
            for (int cc = 0; cc < 4; ++cc)
                s_in[er + 8 * t][4 * cg + cc] = fmaxf(acc1[t][cc], 0.f);
    }
    __syncthreads();
    {
        const int cg = tid & 15;
        const int er = tid >> 4;
        float acc[2][4];
        const float4 bb = *(const float4*)(b4 + 4 * cg);
        #pragma unroll
        for (int t = 0; t < 2; ++t) {
            acc[t][0] = bb.x; acc[t][1] = bb.y; acc[t][2] = bb.z; acc[t][3] = bb.w;
        }
        for (int k = 0; k < 128; k += 4) {
            float wv4[4][4];
            #pragma unroll
            for (int kk = 0; kk < 4; ++kk) {
                const float4 w = *(const float4*)(W4 + (size_t)(k + kk) * 64 + 4 * cg);
                wv4[kk][0] = w.x; wv4[kk][1] = w.y; wv4[kk][2] = w.z; wv4[kk][3] = w.w;
            }
            #pragma unroll
            for (int t = 0; t < 2; ++t) {
                const float4 m = *(const float4*)(&s_in[er + 16 * t][k]);
                const float mm[4] = {m.x, m.y, m.z, m.w};
                #pragma unroll
                for (int kk = 0; kk < 4; ++kk)
                    #pragma unroll
                    for (int cc = 0; cc < 4; ++cc)
                        acc[t][cc] += mm[kk] * wv4[kk][cc];
            }
        }
        #pragma unroll
        for (int t = 0; t < 2; ++t) {
            const int n = base + er + 16 * t;
            if (n < N) {
                float4 o;
                o.x = acc[t][0]; o.y = acc[t][1]; o.z = acc[t][2]; o.w = acc[t][3];
                *(float4*)(out + (size_t)n * 64 + 4 * cg) = o;
            }
        }
    }
}

// ---------------- launch ----------------

static inline size_t rup(size_t v) { return (v + 255) & ~(size_t)255; }

extern "C" void kernel_launch(void* const* d_in, const int* in_sizes, int n_in,
                              void* d_out, int out_size, void* d_ws, size_t ws_size,
                              hipStream_t stream) {
    const float* x    = (const float*)d_in[0];
    const float* pos  = (const float*)d_in[1];
    const int*   eidx = (const int*)d_in[2];
    const float* W1   = (const float*)d_in[3];
    const float* b1   = (const float*)d_in[4];
    const float* W2   = (const float*)d_in[5];
    const float* b2   = (const float*)d_in[6];
    const float* W3   = (const float*)d_in[7];
    const float* b3   = (const float*)d_in[8];
    const float* W4   = (const float*)d_in[9];
    const float* b4   = (const float*)d_in[10];

    const int N = in_sizes[0] / 64;
    const int E = in_sizes[2] / 2;
    const int* ei0 = eidx;       // edge_index[0] = aggregation node i
    const int* ei1 = eidx + E;   // edge_index[1] = neighbor j
    const int nb = (N + 1023) / 1024;

    const size_t msg_b = rup((size_t)E * 64 * 2);
    const size_t pq_b  = rup((size_t)N * 256 * 2);
    const size_t wcp_b = rup(48 * 512 * 2);
    const size_t w2p_b = rup(16 * 512 * 2);
    const size_t w3p_b = rup(32 * 512 * 2);
    const size_t w4p_b = rup(16 * 512 * 2);
    const size_t cnt_b = rup((size_t)N * 4);
    const size_t off_b = rup((size_t)(N + 1) * 4);
    const size_t bsum_b = rup(256 * 4);
    const size_t eij_b = rup((size_t)E * 8);
    const size_t need = msg_b + pq_b + wcp_b + w2p_b + w3p_b + w4p_b +
                        2 * cnt_b + off_b + bsum_b + eij_b;

    if (ws_size >= need) {
        char* p = (char*)d_ws;
        unsigned short* msg = (unsigned short*)p;  p += msg_b;
        unsigned short* PQ  = (unsigned short*)p;  p += pq_b;
        unsigned short* Wcp = (unsigned short*)p;  p += wcp_b;
        unsigned short* W2p = (unsigned short*)p;  p += w2p_b;
        unsigned short* W3p = (unsigned short*)p;  p += w3p_b;
        unsigned short* W4p = (unsigned short*)p;  p += w4p_b;
        int* cnt  = (int*)p;  p += cnt_b;
        int* cur  = (int*)p;  p += cnt_b;
        int* off  = (int*)p;  p += off_b;
        int* bsum = (int*)p;  p += bsum_b;
        int2* eij = (int2*)p;

        hipMemsetAsync(cnt, 0, 2 * cnt_b, stream);  // cnt + cur (adjacent)

        pack_weights_kernel<<<112, 64, 0, stream>>>(W1, W2, W3, W4, Wcp, W2p, W3p, W4p);
        pq_kernel<<<(N + NPB - 1) / NPB, 256, 0, stream>>>(x, pos, Wcp, b1, PQ, N);

        const int eb256 = (E + 255) / 256;
        count_kernel<<<eb256, 256, 0, stream>>>(ei0, cnt, E);
        scanA_kernel<<<nb, 1024, 0, stream>>>(cnt, bsum, N);
        scanC_kernel<<<nb, 1024, 0, stream>>>(cnt, bsum, off, N, E);
        fill_kernel<<<eb256, 256, 0, stream>>>(ei0, ei1, off, cur, eij, E);

        edge_mlp_mfma<<<(E + EPB - 1) / EPB, 256, 0, stream>>>(
            PQ, eij, W2p, b2, msg, E);

        node_mlp_mfma<<<(N + NPB - 1) / NPB, 256, 0, stream>>>(
            x, msg, off, W3p, b3, W4p, b4, (float*)d_out, N);
    } else {
        // fallback: atomic fp32 path
        float* summed = (float*)d_ws;
        float* counts = summed + (size_t)N * 64;
        hipMemsetAsync(d_ws, 0, ((size_t)N * 64 + N) * sizeof(float), stream);

        mpnn_edge_atomic_kernel<<<(E + EB - 1) / EB, 256, 0, stream>>>(
            x, pos, ei0, ei1, W1, b1, W2, b2, summed, counts, E);
        mpnn_node_legacy_kernel<<<(N + NB - 1) / NB, 256, 0, stream>>>(
            x, summed, counts, W3, b3, W4, b4, (float*)d_out, N);
    }
}

// Round 8
// 291.999 us; speedup vs baseline: 3.7305x; 1.1057x over previous
//
#include <hip/hip_runtime.h>

// MPNN: edge MLP (131->128->64) + scatter-mean + node MLP (128->128->64)
// N=50000, E=800000, fp32 in/out.
// R8: FUSED AGGREGATION. Edge kernel (hidden=relu(P[i]+Q[j]) -> layer-2 MFMA)
// now does an in-block SEGMENTED REDUCTION over the CSR-ordered slots
// (runs of equal i are contiguous) and atomicAdds per-run fp32 sums into
// aggr[N][64]. The 100 MB msg write + 102 MB node re-read are eliminated;
// node kernel is pure streaming. P/Q stored as separate dense arrays
// (12.8 MB each) for better L2 behavior on the random-j Q gather.
// Factorization (exact): hidden = relu(P[i]+Q[j]),
//   P = x@(W1a-W1b) - pos@W1c + b1,  Q = x@W1b + pos@W1c.

#define EPB 128  // edges per block (4 waves x M=32)
#define NPB 64   // nodes per block (4 waves x M=16)

typedef __attribute__((ext_vector_type(8))) short bf16x8;
typedef __attribute__((ext_vector_type(4))) float f32x4;

static __device__ __forceinline__ unsigned short f2bf(float f) {
    union { float f; unsigned u; } v; v.f = f;
    unsigned u = v.u + 0x7FFFu + ((v.u >> 16) & 1u);  // RNE
    return (unsigned short)(u >> 16);
}
static __device__ __forceinline__ float bf2f(unsigned short h) {
    union { unsigned u; float f; } v; v.u = ((unsigned)h) << 16;
    return v.f;
}

// ---------------- CSR build ----------------

__global__ __launch_bounds__(256) void count_kernel(
    const int* __restrict__ ei0, int* __restrict__ cnt, int E)
{
    int e = blockIdx.x * 256 + threadIdx.x;
    if (e < E) atomicAdd(&cnt[ei0[e]], 1);
}

__global__ __launch_bounds__(1024) void scanA_kernel(
    const int* __restrict__ cnt, int* __restrict__ bsum, int N)
{
    __shared__ int ws[16];
    const int i = blockIdx.x * 1024 + threadIdx.x;
    int v = (i < N) ? cnt[i] : 0;
    #pragma unroll
    for (int d = 32; d >= 1; d >>= 1) v += __shfl_down(v, d, 64);
    if ((threadIdx.x & 63) == 0) ws[threadIdx.x >> 6] = v;
    __syncthreads();
    if (threadIdx.x == 0) {
        int s = 0;
        #pragma unroll
        for (int k = 0; k < 16; ++k) s += ws[k];
        bsum[blockIdx.x] = s;
    }
}

__global__ __launch_bounds__(1024) void scanC_kernel(
    const int* __restrict__ cnt, const int* __restrict__ bsum,
    int* __restrict__ off, int N, int Etot)
{
    __shared__ int wsum[16];
    __shared__ int boffs;
    const int i = blockIdx.x * 1024 + threadIdx.x;
    const int lane = threadIdx.x & 63, w = threadIdx.x >> 6;
    if (threadIdx.x < 64) {
        int acc = 0;
        for (int k = threadIdx.x; k < blockIdx.x; k += 64) acc += bsum[k];
        #pragma unroll
        for (int d = 32; d >= 1; d >>= 1) acc += __shfl_down(acc, d, 64);
        if (threadIdx.x == 0) boffs = acc;
    }
    const int v = (i < N) ? cnt[i] : 0;
    int incl = v;
    #pragma unroll
    for (int d = 1; d < 64; d <<= 1) {
        int t = __shfl_up(incl, d, 64);
        if (lane >= d) incl += t;
    }
    if (lane == 63) wsum[w] = incl;
    __syncthreads();
    int pre = 0;
    for (int k = 0; k < w; ++k) pre += wsum[k];
    if (i < N) off[i] = boffs + pre + incl - v;
    if (blockIdx.x == 0 && threadIdx.x == 0) off[N] = Etot;
}

__global__ __launch_bounds__(256) void fill_kernel(
    const int* __restrict__ ei0, const int* __restrict__ ei1,
    const int* __restrict__ off, int* __restrict__ cur,
    int2* __restrict__ eij, int E)
{
    int e = blockIdx.x * 256 + threadIdx.x;
    if (e < E) {
        const int i = ei0[e];
        const int p = atomicAdd(&cur[i], 1);
        int2 v; v.x = i; v.y = ei1[e];
        eij[off[i] + p] = v;
    }
}

// ---------------- weight pre-pack into B-fragment order ----------------
// f<48: Wc[96][256]: cols 0..127 = P-proj, 128..255 = Q-proj (see pq_kernel).
// Frag layout: lane l elem j = W[ks*32+(l>>4)*8+j][nt*16+(l&15)].

__global__ __launch_bounds__(64) void pack_weights_kernel(
    const float* __restrict__ W1, const float* __restrict__ W2,
    const float* __restrict__ W3, const float* __restrict__ W4,
    unsigned short* __restrict__ Wcp, unsigned short* __restrict__ W2p,
    unsigned short* __restrict__ W3p, unsigned short* __restrict__ W4p)
{
    int f = blockIdx.x;           // 0..111
    const int lane = threadIdx.x; // 0..63
    if (f < 48) {
        const int nt = f / 3, ks = f % 3;
        const int n  = nt * 16 + (lane & 15);
        const int k0 = ks * 32 + (lane >> 4) * 8;
        unsigned short* dst = Wcp + (size_t)f * 512 + lane * 8;
        #pragma unroll
        for (int j = 0; j < 8; ++j) {
            const int k = k0 + j;
            float v = 0.f;
            if (n < 128) {          // P-part
                if (k < 64)       v = W1[(size_t)k * 128 + n] - W1[(size_t)(64 + k) * 128 + n];
                else if (k < 67)  v = -W1[(size_t)(128 + k - 64) * 128 + n];
            } else {                // Q-part
                const int nq = n - 128;
                if (k < 64)       v = W1[(size_t)(64 + k) * 128 + nq];
                else if (k < 67)  v = W1[(size_t)(128 + k - 64) * 128 + nq];
            }
            dst[j] = f2bf(v);
        }
        return;
    }
    const float* W; unsigned short* out; int K, N, KS;
    if (f < 64)      { W = W2; out = W2p; K = 128; N = 64;  KS = 4; f -= 48; }
    else if (f < 96) { W = W3; out = W3p; K = 128; N = 128; KS = 4; f -= 64; }
    else             { W = W4; out = W4p; K = 128; N = 64;  KS = 4; f -= 96; }
    const int nt = f / KS, ks = f % KS;
    const int n  = nt * 16 + (lane & 15);
    const int k0 = ks * 32 + (lane >> 4) * 8;
    unsigned short* dst = out + (size_t)f * 512 + lane * 8;
    #pragma unroll
    for (int j = 0; j < 8; ++j) {
        float v = (k0 + j < K) ? W[(size_t)(k0 + j) * N + n] : 0.f;
        dst[j] = f2bf(v);
    }
}

// ---------------- per-node projections: P,Q = [x|pos] @ Wc (+b1 on P) ------

__global__ __launch_bounds__(256) void pq_kernel(
    const float* __restrict__ x, const float* __restrict__ pos,
    const unsigned short* __restrict__ Wcp, const float* __restrict__ b1,
    unsigned short* __restrict__ P, unsigned short* __restrict__ Q, int N)
{
    __shared__ unsigned short s[NPB][104];  // 96 cols + 8 pad

    const int tid  = threadIdx.x;
    const int wv   = tid >> 6;
    const int lane = tid & 63;
    const int r    = lane >> 4;
    const int c    = lane & 15;
    const int base = blockIdx.x * NPB;

    for (int nl = wv; nl < NPB; nl += 4) {
        const int n = base + nl;
        s[nl][lane] = (n < N) ? f2bf(x[(size_t)n * 64 + lane]) : 0;
        if (lane < 32)
            s[nl][64 + lane] = (n < N && lane < 3) ? f2bf(pos[(size_t)n * 3 + lane]) : 0;
    }
    __syncthreads();

    bf16x8 a[3];
    #pragma unroll
    for (int ks = 0; ks < 3; ++ks)
        a[ks] = *(const bf16x8*)&s[wv * 16 + c][ks * 32 + r * 8];

    f32x4 acc[16];
    #pragma unroll
    for (int nt = 0; nt < 16; ++nt) {
        const float bv = (nt < 8) ? b1[nt * 16 + c] : 0.f;  // bias folded into P
        acc[nt] = (f32x4){bv, bv, bv, bv};
    }
    #pragma unroll
    for (int nt = 0; nt < 16; ++nt)
        #pragma unroll
        for (int ks = 0; ks < 3; ++ks) {
            const bf16x8 b = *(const bf16x8*)(Wcp + (size_t)(nt * 3 + ks) * 512 + lane * 8);
            acc[nt] = __builtin_amdgcn_mfma_f32_16x16x32_bf16(a[ks], b, acc[nt], 0, 0, 0);
        }

    #pragma unroll
    for (int nt = 0; nt < 16; ++nt)
        #pragma unroll
        for (int reg = 0; reg < 4; ++reg) {
            const int n = base + wv * 16 + r * 4 + reg;
            if (n < N) {
                if (nt < 8) P[(size_t)n * 128 + nt * 16 + c]       = f2bf(acc[nt][reg]);
                else        Q[(size_t)n * 128 + (nt - 8) * 16 + c] = f2bf(acc[nt][reg]);
            }
        }
}

// ------- edge kernel: relu(P[i]+Q[j]) -> layer-2 MFMA -> fused seg-reduce ----

__global__ __launch_bounds__(256) void edge_aggr_mfma(
    const unsigned short* __restrict__ P, const unsigned short* __restrict__ Q,
    const int2* __restrict__ eij,
    const unsigned short* __restrict__ W2p, const float* __restrict__ b2,
    float* __restrict__ aggr, int E)
{
    __shared__ unsigned short s_m[EPB][72];  // msgs, 64 cols + 8 pad
    __shared__ int2 s_ij[EPB];
    __shared__ int  s_start[EPB + 4];        // run starts + terminator
    __shared__ int  s_wsumA[2];
    __shared__ int  s_nruns;

    const int tid  = threadIdx.x;
    const int wv   = tid >> 6;
    const int lane = tid & 63;
    const int r    = lane >> 4;
    const int c    = lane & 15;
    const int base = blockIdx.x * EPB;
    const int ne   = min(EPB, E - base);     // valid slots in this block (>=1)

    if (tid < EPB) {
        const int p = base + tid;
        int2 v; v.x = -1; v.y = -1;
        if (p < E) v = eij[p];
        s_ij[tid] = v;
    }
    __syncthreads();

    // ---- layer-2 A-frags in registers: relu(P[i][k] + Q[j][k])
    bf16x8 a2[2][4];
    #pragma unroll
    for (int mh = 0; mh < 2; ++mh) {
        const int2 ij = s_ij[wv * 32 + mh * 16 + c];
        if (ij.x >= 0) {
            const unsigned short* Pi = P + (size_t)ij.x * 128;
            const unsigned short* Qj = Q + (size_t)ij.y * 128;
            #pragma unroll
            for (int ks = 0; ks < 4; ++ks) {
                const bf16x8 pp = *(const bf16x8*)(Pi + ks * 32 + r * 8);
                const bf16x8 qq = *(const bf16x8*)(Qj + ks * 32 + r * 8);
                bf16x8 h;
                #pragma unroll
                for (int t = 0; t < 8; ++t) {
                    const float v = bf2f((unsigned short)pp[t]) + bf2f((unsigned short)qq[t]);
                    h[t] = (short)f2bf(fmaxf(v, 0.f));
                }
                a2[mh][ks] = h;
            }
        } else {
            #pragma unroll
            for (int ks = 0; ks < 4; ++ks) a2[mh][ks] = (bf16x8){0,0,0,0,0,0,0,0};
        }
    }

    // ---- layer 2: msg = hidden @ W2 + b2, N=64, K=128
    f32x4 acc2[2][4];
    #pragma unroll
    for (int nt = 0; nt < 4; ++nt) {
        const float bv = b2[nt * 16 + c];
        acc2[0][nt] = (f32x4){bv, bv, bv, bv};
        acc2[1][nt] = (f32x4){bv, bv, bv, bv};
    }
    #pragma unroll
    for (int nt = 0; nt < 4; ++nt)
        #pragma unroll
        for (int ks = 0; ks < 4; ++ks) {
            const bf16x8 b = *(const bf16x8*)(W2p + (size_t)(nt * 4 + ks) * 512 + lane * 8);
            acc2[0][nt] = __builtin_amdgcn_mfma_f32_16x16x32_bf16(a2[0][ks], b, acc2[0][nt], 0, 0, 0);
            acc2[1][nt] = __builtin_amdgcn_mfma_f32_16x16x32_bf16(a2[1][ks], b, acc2[1][nt], 0, 0, 0);
        }

    // ---- msgs to LDS (bf16)
    #pragma unroll
    for (int mh = 0; mh < 2; ++mh)
        #pragma unroll
        for (int nt = 0; nt < 4; ++nt)
            #pragma unroll
            for (int reg = 0; reg < 4; ++reg) {
                const int row = wv * 32 + mh * 16 + r * 4 + reg;
                s_m[row][nt * 16 + c] = f2bf(acc2[mh][nt][reg]);
            }

    // ---- run detection over slots [0, ne): flag = start-of-run
    int flag = 0, incl = 0;
    if (tid < EPB) {
        flag = (tid < ne) && (tid == 0 || s_ij[tid].x != s_ij[tid - 1].x);
        incl = flag;
    }
    #pragma unroll
    for (int d = 1; d < 64; d <<= 1) {       // per-wave inclusive prefix
        int t = __shfl_up(incl, d, 64);
        if (lane >= d) incl += t;
    }
    if (tid < EPB && lane == 63) s_wsumA[tid >> 6] = incl;
    __syncthreads();                         // also covers s_m writes above
    if (tid < EPB) {
        const int rid = incl + ((tid >= 64) ? s_wsumA[0] : 0);  // inclusive
        if (flag) s_start[rid - 1] = tid;
    }
    if (tid == 0) {
        const int nr = s_wsumA[0] + s_wsumA[1];
        s_nruns = nr;
        s_start[nr] = ne;                    // terminator
    }
    __syncthreads();

    // ---- segmented reduce: one wave per run (round-robin), lanes = 64 cols
    for (int rn = wv; rn < s_nruns; rn += 4) {
        const int e0 = s_start[rn], e1 = s_start[rn + 1];
        const int i  = s_ij[e0].x;
        float acc = 0.f;
        for (int e = e0; e < e1; ++e)
            acc += bf2f(s_m[e][lane]);
        atomicAdd(&aggr[(size_t)i * 64 + lane], acc);
    }
}

// ---------------- node MLP (streaming aggr) ----------------

__global__ __launch_bounds__(256) void node_mlp_mfma(
    const float* __restrict__ x, const float* __restrict__ aggr,
    const int* __restrict__ off,
    const unsigned short* __restrict__ W3p, const float* __restrict__ b3,
    const unsigned short* __restrict__ W4p, const float* __restrict__ b4,
    float* __restrict__ out, int N)
{
    __shared__ unsigned short s_a[NPB][136];  // 128 + 8 pad

    const int tid  = threadIdx.x;
    const int wv   = tid >> 6;
    const int lane = tid & 63;
    const int r    = lane >> 4;
    const int c    = lane & 15;
    const int base = blockIdx.x * NPB;

    for (int nl = wv; nl < NPB; nl += 4) {
        const int n = base + nl;
        if (n < N) {
            s_a[nl][lane] = f2bf(x[(size_t)n * 64 + lane]);
            const int deg = off[n + 1] - off[n];
            const float a = aggr[(size_t)n * 64 + lane] / (float)max(deg, 1);
            s_a[nl][64 + lane] = f2bf(a);
        } else {
            s_a[nl][lane] = 0;
            s_a[nl][64 + lane] = 0;
        }
    }
    __syncthreads();

    bf16x8 a1[4];
    #pragma unroll
    for (int ks = 0; ks < 4; ++ks)
        a1[ks] = *(const bf16x8*)&s_a[wv * 16 + c][ks * 32 + r * 8];
    __syncthreads();

    f32x4 acc1[8];
    #pragma unroll
    for (int nt = 0; nt < 8; ++nt) {
        const float bv = b3[nt * 16 + c];
        acc1[nt] = (f32x4){bv, bv, bv, bv};
    }
    #pragma unroll
    for (int nt = 0; nt < 8; ++nt)
        #pragma unroll
        for (int ks = 0; ks < 4; ++ks) {
            const bf16x8 b = *(const bf16x8*)(W3p + (size_t)(nt * 4 + ks) * 512 + lane * 8);
            acc1[nt] = __builtin_amdgcn_mfma_f32_16x16x32_bf16(a1[ks], b, acc1[nt], 0, 0, 0);
        }
    #pragma unroll
    for (int nt = 0; nt < 8; ++nt)
        #pragma unroll
        for (int reg = 0; reg < 4; ++reg)
            s_a[wv * 16 + r * 4 + reg][nt * 16 + c] = f2bf(fmaxf(acc1[nt][reg], 0.f));
    __syncthreads();

    bf16x8 a2[4];
    #pragma unroll
    for (int ks = 0; ks < 4; ++ks)
        a2[ks] = *(const bf16x8*)&s_a[wv * 16 + c][ks * 32 + r * 8];
    __syncthreads();

    f32x4 acc2[4];
    #pragma unroll
    for (int nt = 0; nt < 4; ++nt) {
        const float bv = b4[nt * 16 + c];
        acc2[nt] = (f32x4){bv, bv, bv, bv};
    }
    #pragma unroll
    for (int nt = 0; nt < 4; ++nt)
        #pragma unroll
        for (int ks = 0; ks < 4; ++ks) {
            const bf16x8 b = *(const bf16x8*)(W4p + (size_t)(nt * 4 + ks) * 512 + lane * 8);
            acc2[nt] = __builtin_amdgcn_mfma_f32_16x16x32_bf16(a2[ks], b, acc2[nt], 0, 0, 0);
        }

    #pragma unroll
    for (int nt = 0; nt < 4; ++nt)
        #pragma unroll
        for (int reg = 0; reg < 4; ++reg) {
            float* row = (float*)&s_a[wv * 16 + r * 4 + reg][0];
            row[nt * 16 + c] = acc2[nt][reg];
        }
    __syncthreads();

    {
        const int nl = tid >> 2, q = tid & 3;
        const int n = base + nl;
        if (n < N) {
            const float4* src = (const float4*)((const float*)&s_a[nl][0] + q * 16);
            float4* dst = (float4*)(out + (size_t)n * 64 + q * 16);
            #pragma unroll
            for (int u = 0; u < 4; ++u) dst[u] = src[u];
        }
    }
}

// ---------------- fallback (atomic fp32 path, if ws too small) ----------------

#define EB 32
#define NB 32

__global__ __launch_bounds__(256) void mpnn_edge_atomic_kernel(
    const float* __restrict__ x, const float* __restrict__ pos,
    const int* __restrict__ ei0, const int* __restrict__ ei1,
    const float* __restrict__ W1, const float* __restrict__ b1,
    const float* __restrict__ W2, const float* __restrict__ b2,
    float* __restrict__ summed, float* __restrict__ counts, int E)
{
    __shared__ float s_in[EB][132];
    __shared__ int   s_idx[EB];

    const int tid  = threadIdx.x;
    const int base = blockIdx.x * EB;
    const int wv   = tid >> 6;
    const int lane = tid & 63;

    for (int e = wv; e < EB; e += 4) {
        const int ei = base + e;
        if (ei < E) {
            const int i = ei0[ei];
            const int j = ei1[ei];
            const float xi = x[(size_t)i * 64 + lane];
            const float xj = x[(size_t)j * 64 + lane];
            s_in[e][lane]      = xi;
            s_in[e][64 + lane] = xj - xi;
            if (lane < 3)
                s_in[e][128 + lane] = pos[(size_t)j * 3 + lane] - pos[(size_t)i * 3 + lane];
            if (lane == 0) s_idx[e] = i;
        } else {
            s_in[e][lane] = 0.f; s_in[e][64 + lane] = 0.f;
            if (lane < 3) s_in[e][128 + lane] = 0.f;
            if (lane == 0) s_idx[e] = -1;
        }
    }
    __syncthreads();

    float acc1[4][4];
    {
        const int cg = tid & 31;
        const int er = tid >> 5;
        const float4 bb = *(const float4*)(b1 + 4 * cg);
        #pragma unroll
        for (int t = 0; t < 4; ++t) {
            acc1[t][0] = bb.x; acc1[t][1] = bb.y; acc1[t][2] = bb.z; acc1[t][3] = bb.w;
        }
        for (int k = 0; k < 128; k += 4) {
            float wv4[4][4];
            #pragma unroll
            for (int kk = 0; kk < 4; ++kk) {
                const float4 w = *(const float4*)(W1 + (size_t)(k + kk) * 128 + 4 * cg);
                wv4[kk][0] = w.x; wv4[kk][1] = w.y; wv4[kk][2] = w.z; wv4[kk][3] = w.w;
            }
            #pragma unroll
            for (int t = 0; t < 4; ++t) {
                const float4 m = *(const float4*)(&s_in[er + 8 * t][k]);
                const float mm[4] = {m.x, m.y, m.z, m.w};
                #pragma unroll
                for (int kk = 0; kk < 4; ++kk)
                    #pragma unroll
                    for (int cc = 0; cc < 4; ++cc)
                        acc1[t][cc] += mm[kk] * wv4[kk][cc];
            }
        }
        for (int k = 128; k < 131; ++k) {
            float wk[4];
            #pragma unroll
            for (int cc = 0; cc < 4; ++cc) wk[cc] = W1[(size_t)k * 128 + 4 * cg + cc];
            #pragma unroll
            for (int t = 0; t < 4; ++t) {
                const float m = s_in[er + 8 * t][k];
                #pragma unroll
                for (int cc = 0; cc < 4; ++cc) acc1[t][cc] += m * wk[cc];
            }
        }
    }
    __syncthreads();
    {
        const int cg = tid & 31;
        const int er = tid >> 5;
        #pragma unroll
        for (int t = 0; t < 4; ++t)
            #pragma unroll
            for (int cc = 0; cc < 4; ++cc)
                s_in[er + 8 * t][4 * cg + cc] = fmaxf(acc1[t][cc], 0.f);
    }
    __syncthreads();
    {
        const int cg = tid & 15;
        const int er = tid >> 4;
        float acc[2][4];
        const float4 bb = *(const float4*)(b2 + 4 * cg);
        #pragma unroll
        for (int t = 0; t < 2; ++t) {
            acc[t][0] = bb.x; acc[t][1] = bb.y; acc[t][2] = bb.z; acc[t][3] = bb.w;
        }
        for (int k = 0; k < 128; k += 4) {
            float wv4[4][4];
            #pragma unroll
            for (int kk = 0; kk < 4; ++kk) {
                const float4 w = *(const float4*)(W2 + (size_t)(k + kk) * 64 + 4 * cg);
                wv4[kk][0] = w.x; wv4[kk][1] = w.y; wv4[kk][2] = w.z; wv4[kk][3] = w.w;
            }
            #pragma unroll
            for (int t = 0; t < 2; ++t) {
                const float4 m = *(const float4*)(&s_in[er + 16 * t][k]);
                const float mm[4] = {m.x, m.y, m.z, m.w};
                #pragma unroll
                for (int kk = 0; kk < 4; ++kk)
                    #pragma unroll
                    for (int cc = 0; cc < 4; ++cc)
                        acc[t][cc] += mm[kk] * wv4[kk][cc];
            }
        }
        #pragma unroll
        for (int t = 0; t < 2; ++t) {
            const int e = er + 16 * t;
            const int i = s_idx[e];
            if (i >= 0) {
                #pragma unroll
                for (int cc = 0; cc < 4; ++cc)
                    atomicAdd(&summed[(size_t)i * 64 + 4 * cg + cc], acc[t][cc]);
            }
        }
    }
    if (tid < EB) {
        const int i = s_idx[tid];
        if (i >= 0) atomicAdd(&counts[i], 1.0f);
    }
}

__global__ __launch_bounds__(256) void mpnn_node_legacy_kernel(
    const float* __restrict__ x, const float* __restrict__ summed,
    const float* __restrict__ counts,
    const float* __restrict__ W3, const float* __restrict__ b3,
    const float* __restrict__ W4, const float* __restrict__ b4,
    float* __restrict__ out, int N)
{
    __shared__ float s_in[NB][132];

    const int tid  = threadIdx.x;
    const int base = blockIdx.x * NB;
    const int wv   = tid >> 6;
    const int lane = tid & 63;

    for (int nl = wv; nl < NB; nl += 4) {
        const int n = base + nl;
        if (n < N) {
            s_in[nl][lane] = x[(size_t)n * 64 + lane];
            const float inv = 1.0f / fmaxf(counts[n], 1.0f);
            s_in[nl][64 + lane] = summed[(size_t)n * 64 + lane] * inv;
        } else {
            s_in[nl][lane] = 0.f; s_in[nl][64 + lane] = 0.f;
        }
    }
    __syncthreads();

    float acc1[4][4];
    {
        const int cg = tid & 31;
        const int er = tid >> 5;
        const float4 bb = *(const float4*)(b3 + 4 * cg);
        #pragma unroll
        for (int t = 0; t < 4; ++t) {
            acc1[t][0] = bb.x; acc1[t][1] = bb.y; acc1[t][2] = bb.z; acc1[t][3] = bb.w;
        }
        for (int k = 0; k < 128; k += 4) {
            float wv4[4][4];
            #pragma unroll
            for (int kk = 0; kk < 4; ++kk) {
                const float4 w = *(const float4*)(W3 + (size_t)(k + kk) * 128 + 4 * cg);
                wv4[kk][0] = w.x; wv4[kk][1] = w.y; wv4[kk][2] = w.z; wv4[kk][3] = w.w;
            }
            #pragma unroll
            for (int t = 0; t < 4; ++t) {
                const float4 m = *(const float4*)(&s_in[er + 8 * t][k]);
                const float mm[4] = {m.x, m.y, m.z, m.w};
                #pragma unroll
                for (int kk = 0; kk < 4; ++kk)
                    #pragma unroll
                    for (int cc = 0; cc < 4; ++cc)
                        acc1[t][cc] += mm[kk] * wv4[kk][cc];
            }
        }
    }
    __syncthreads();
    {
        const int cg = tid & 31;
        const int er = tid >> 5;
        #pragma unroll
        for (int t = 0; t < 4; ++t)
            #pragma unroll
            for (int cc = 0; cc < 4; ++cc)
                s_in[er + 8 * t][4 * cg + cc] = fmaxf(acc1[t][cc], 0.f);
    }
    __syncthreads();
    {
        const int cg = tid & 15;
        const int er = tid >> 4;
        float acc[2][4];
        const float4 bb = *(const float4*)(b4 + 4 * cg);
        #pragma unroll
        for (int t = 0; t < 2; ++t) {
            acc[t][0] = bb.x; acc[t][1] = bb.y; acc[t][2] = bb.z; acc[t][3] = bb.w;
        }
        for (int k = 0; k < 128; k += 4) {
            float wv4[4][4];
            #pragma unroll
            for (int kk = 0; kk < 4; ++kk) {
                const float4 w = *(const float4*)(W4 + (size_t)(k + kk) * 64 + 4 * cg);
                wv4[kk][0] = w.x; wv4[kk][1] = w.y; wv4[kk][2] = w.z; wv4[kk][3] = w.w;
            }
            #pragma unroll
            for (int t = 0; t < 2; ++t) {
                const float4 m = *(const float4*)(&s_in[er + 16 * t][k]);
                const float mm[4] = {m.x, m.y, m.z, m.w};
                #pragma unroll
                for (int kk = 0; kk < 4; ++kk)
                    #pragma unroll
                    for (int cc = 0; cc < 4; ++cc)
                        acc[t][cc] += mm[kk] * wv4[kk][cc];
            }
        }
        #pragma unroll
        for (int t = 0; t < 2; ++t) {
            const int n = base + er + 16 * t;
            if (n < N) {
                float4 o;
                o.x = acc[t][0]; o.y = acc[t][1]; o.z = acc[t][2]; o.w = acc[t][3];
                *(float4*)(out + (size_t)n * 64 + 4 * cg) = o;
            }
        }
    }
}

// ---------------- launch ----------------

static inline size_t rup(size_t v) { return (v + 255) & ~(size_t)255; }

extern "C" void kernel_launch(void* const* d_in, const int* in_sizes, int n_in,
                              void* d_out, int out_size, void* d_ws, size_t ws_size,
                              hipStream_t stream) {
    const float* x    = (const float*)d_in[0];
    const float* pos  = (const float*)d_in[1];
    const int*   eidx = (const int*)d_in[2];
    const float* W1   = (const float*)d_in[3];
    const float* b1   = (const float*)d_in[4];
    const float* W2   = (const float*)d_in[5];
    const float* b2   = (const float*)d_in[6];
    const float* W3   = (const float*)d_in[7];
    const float* b3   = (const float*)d_in[8];
    const float* W4   = (const float*)d_in[9];
    const float* b4   = (const float*)d_in[10];

    const int N = in_sizes[0] / 64;
    const int E = in_sizes[2] / 2;
    const int* ei0 = eidx;       // edge_index[0] = aggregation node i
    const int* ei1 = eidx + E;   // edge_index[1] = neighbor j
    const int nb = (N + 1023) / 1024;

    const size_t p_b    = rup((size_t)N * 128 * 2);
    const size_t q_b    = rup((size_t)N * 128 * 2);
    const size_t wcp_b  = rup(48 * 512 * 2);
    const size_t w2p_b  = rup(16 * 512 * 2);
    const size_t w3p_b  = rup(32 * 512 * 2);
    const size_t w4p_b  = rup(16 * 512 * 2);
    const size_t aggr_b = rup((size_t)N * 64 * 4);
    const size_t cnt_b  = rup((size_t)N * 4);
    const size_t off_b  = rup((size_t)(N + 1) * 4);
    const size_t bsum_b = rup(256 * 4);
    const size_t eij_b  = rup((size_t)E * 8);
    const size_t need = p_b + q_b + wcp_b + w2p_b + w3p_b + w4p_b +
                        aggr_b + 2 * cnt_b + off_b + bsum_b + eij_b;

    if (ws_size >= need) {
        char* p = (char*)d_ws;
        unsigned short* P   = (unsigned short*)p;  p += p_b;
        unsigned short* Q   = (unsigned short*)p;  p += q_b;
        unsigned short* Wcp = (unsigned short*)p;  p += wcp_b;
        unsigned short* W2p = (unsigned short*)p;  p += w2p_b;
        unsigned short* W3p = (unsigned short*)p;  p += w3p_b;
        unsigned short* W4p = (unsigned short*)p;  p += w4p_b;
        float* aggr = (float*)p;  p += aggr_b;
        int* cnt  = (int*)p;  p += cnt_b;
        int* cur  = (int*)p;  p += cnt_b;
        int* off  = (int*)p;  p += off_b;
        int* bsum = (int*)p;  p += bsum_b;
        int2* eij = (int2*)p;

        // zero aggr + cnt + cur in one shot (adjacent)
        hipMemsetAsync(aggr, 0, aggr_b + 2 * cnt_b, stream);

        pack_weights_kernel<<<112, 64, 0, stream>>>(W1, W2, W3, W4, Wcp, W2p, W3p, W4p);
        pq_kernel<<<(N + NPB - 1) / NPB, 256, 0, stream>>>(x, pos, Wcp, b1, P, Q, N);

        const int eb256 = (E + 255) / 256;
        count_kernel<<<eb256, 256, 0, stream>>>(ei0, cnt, E);
        scanA_kernel<<<nb, 1024, 0, stream>>>(cnt, bsum, N);
        scanC_kernel<<<nb, 1024, 0, stream>>>(cnt, bsum, off, N, E);
        fill_kernel<<<eb256, 256, 0, stream>>>(ei0, ei1, off, cur, eij, E);

        edge_aggr_mfma<<<(E + EPB - 1) / EPB, 256, 0, stream>>>(
            P, Q, eij, W2p, b2, aggr, E);

        node_mlp_mfma<<<(N + NPB - 1) / NPB, 256, 0, stream>>>(
            x, aggr, off, W3p, b3, W4p, b4, (float*)d_out, N);
    } else {
        // fallback: atomic fp32 path
        float* summed = (float*)d_ws;
        float* counts = summed + (size_t)N * 64;
        hipMemsetAsync(d_ws, 0, ((size_t)N * 64 + N) * sizeof(float), stream);

        mpnn_edge_atomic_kernel<<<(E + EB - 1) / EB, 256, 0, stream>>>(
            x, pos, ei0, ei1, W1, b1, W2, b2, summed, counts, E);
        mpnn_node_legacy_kernel<<<(N + NB - 1) / NB, 256, 0, stream>>>(
            x, summed, counts, W3, b3, W4, b4, (float*)d_out, N);
    }
}

// Round 10
// 262.175 us; speedup vs baseline: 4.1549x; 1.1138x over previous
//
#include <hip/hip_runtime.h>

// MPNN: edge MLP (131->128->64) + scatter-mean + node MLP (128->128->64)
// N=50000, E=800000, fp32 in/out.
// R10: R9 with the pq epilogue bug fixed: a P/Q row is 128 ushorts = 32
// ushort4, so each of the 4 threads/row copies EIGHT ushort4 (R9 copied 4,
// leaving cols 64..127 unwritten -> hidden half-zeroed -> absmax 1.66).
// R9 changes kept: atomic-free fill via rank[], coalesced pq stores,
// packed-dword relu(P+Q) frag build.
// Factorization (exact): hidden = relu(P[i]+Q[j]),
//   P = x@(W1a-W1b) - pos@W1c + b1,  Q = x@W1b + pos@W1c.

#define EPB 128  // edges per block (4 waves x M=32)
#define NPB 64   // nodes per block (4 waves x M=16)

typedef __attribute__((ext_vector_type(8))) short bf16x8;
typedef __attribute__((ext_vector_type(4))) float f32x4;

static __device__ __forceinline__ unsigned short f2bf(float f) {
    union { float f; unsigned u; } v; v.f = f;
    unsigned u = v.u + 0x7FFFu + ((v.u >> 16) & 1u);  // RNE
    return (unsigned short)(u >> 16);
}
static __device__ __forceinline__ float bf2f(unsigned short h) {
    union { unsigned u; float f; } v; v.u = ((unsigned)h) << 16;
    return v.f;
}
// packed: two bf16 in u32 -> relu(p+q) -> two bf16 (truncating round)
static __device__ __forceinline__ unsigned relu_add_pk(unsigned pu, unsigned qu) {
    union { unsigned u; float f; } plo, phi, qlo, qhi, lo, hi;
    plo.u = pu << 16;           phi.u = pu & 0xffff0000u;
    qlo.u = qu << 16;           qhi.u = qu & 0xffff0000u;
    lo.f = fmaxf(plo.f + qlo.f, 0.f);
    hi.f = fmaxf(phi.f + qhi.f, 0.f);
    return (hi.u & 0xffff0000u) | (lo.u >> 16);
}

// ---------------- CSR build ----------------

__global__ __launch_bounds__(256) void count_kernel(
    const int* __restrict__ ei0, int* __restrict__ cnt,
    int* __restrict__ rank, int E)
{
    int e = blockIdx.x * 256 + threadIdx.x;
    if (e < E) rank[e] = atomicAdd(&cnt[ei0[e]], 1);
}

__global__ __launch_bounds__(1024) void scanA_kernel(
    const int* __restrict__ cnt, int* __restrict__ bsum, int N)
{
    __shared__ int ws[16];
    const int i = blockIdx.x * 1024 + threadIdx.x;
    int v = (i < N) ? cnt[i] : 0;
    #pragma unroll
    for (int d = 32; d >= 1; d >>= 1) v += __shfl_down(v, d, 64);
    if ((threadIdx.x & 63) == 0) ws[threadIdx.x >> 6] = v;
    __syncthreads();
    if (threadIdx.x == 0) {
        int s = 0;
        #pragma unroll
        for (int k = 0; k < 16; ++k) s += ws[k];
        bsum[blockIdx.x] = s;
    }
}

__global__ __launch_bounds__(1024) void scanC_kernel(
    const int* __restrict__ cnt, const int* __restrict__ bsum,
    int* __restrict__ off, int N, int Etot)
{
    __shared__ int wsum[16];
    __shared__ int boffs;
    const int i = blockIdx.x * 1024 + threadIdx.x;
    const int lane = threadIdx.x & 63, w = threadIdx.x >> 6;
    if (threadIdx.x < 64) {
        int acc = 0;
        for (int k = threadIdx.x; k < blockIdx.x; k += 64) acc += bsum[k];
        #pragma unroll
        for (int d = 32; d >= 1; d >>= 1) acc += __shfl_down(acc, d, 64);
        if (threadIdx.x == 0) boffs = acc;
    }
    const int v = (i < N) ? cnt[i] : 0;
    int incl = v;
    #pragma unroll
    for (int d = 1; d < 64; d <<= 1) {
        int t = __shfl_up(incl, d, 64);
        if (lane >= d) incl += t;
    }
    if (lane == 63) wsum[w] = incl;
    __syncthreads();
    int pre = 0;
    for (int k = 0; k < w; ++k) pre += wsum[k];
    if (i < N) off[i] = boffs + pre + incl - v;
    if (blockIdx.x == 0 && threadIdx.x == 0) off[N] = Etot;
}

// atomic-free: slot = off[i] + rank[e]  (rank from count_kernel)
__global__ __launch_bounds__(256) void fill_kernel(
    const int* __restrict__ ei0, const int* __restrict__ ei1,
    const int* __restrict__ off, const int* __restrict__ rank,
    int2* __restrict__ eij, int E)
{
    int e = blockIdx.x * 256 + threadIdx.x;
    if (e < E) {
        const int i = ei0[e];
        int2 v; v.x = i; v.y = ei1[e];
        eij[off[i] + rank[e]] = v;
    }
}

// ---------------- weight pre-pack into B-fragment order ----------------
// f<48: Wc[96][256]: cols 0..127 = P-proj, 128..255 = Q-proj.
// Frag layout: lane l elem j = W[ks*32+(l>>4)*8+j][nt*16+(l&15)].

__global__ __launch_bounds__(64) void pack_weights_kernel(
    const float* __restrict__ W1, const float* __restrict__ W2,
    const float* __restrict__ W3, const float* __restrict__ W4,
    unsigned short* __restrict__ Wcp, unsigned short* __restrict__ W2p,
    unsigned short* __restrict__ W3p, unsigned short* __restrict__ W4p)
{
    int f = blockIdx.x;           // 0..111
    const int lane = threadIdx.x; // 0..63
    if (f < 48) {
        const int nt = f / 3, ks = f % 3;
        const int n  = nt * 16 + (lane & 15);
        const int k0 = ks * 32 + (lane >> 4) * 8;
        unsigned short* dst = Wcp + (size_t)f * 512 + lane * 8;
        #pragma unroll
        for (int j = 0; j < 8; ++j) {
            const int k = k0 + j;
            float v = 0.f;
            if (n < 128) {          // P-part
                if (k < 64)       v = W1[(size_t)k * 128 + n] - W1[(size_t)(64 + k) * 128 + n];
                else if (k < 67)  v = -W1[(size_t)(128 + k - 64) * 128 + n];
            } else {                // Q-part
                const int nq = n - 128;
                if (k < 64)       v = W1[(size_t)(64 + k) * 128 + nq];
                else if (k < 67)  v = W1[(size_t)(128 + k - 64) * 128 + nq];
            }
            dst[j] = f2bf(v);
        }
        return;
    }
    const float* W; unsigned short* out; int K, N, KS;
    if (f < 64)      { W = W2; out = W2p; K = 128; N = 64;  KS = 4; f -= 48; }
    else if (f < 96) { W = W3; out = W3p; K = 128; N = 128; KS = 4; f -= 64; }
    else             { W = W4; out = W4p; K = 128; N = 64;  KS = 4; f -= 96; }
    const int nt = f / KS, ks = f % KS;
    const int n  = nt * 16 + (lane & 15);
    const int k0 = ks * 32 + (lane >> 4) * 8;
    unsigned short* dst = out + (size_t)f * 512 + lane * 8;
    #pragma unroll
    for (int j = 0; j < 8; ++j) {
        float v = (k0 + j < K) ? W[(size_t)(k0 + j) * N + n] : 0.f;
        dst[j] = f2bf(v);
    }
}

// ---------------- per-node projections: P,Q = [x|pos] @ Wc (+b1 on P) ------

__global__ __launch_bounds__(256) void pq_kernel(
    const float* __restrict__ x, const float* __restrict__ pos,
    const unsigned short* __restrict__ Wcp, const float* __restrict__ b1,
    unsigned short* __restrict__ P, unsigned short* __restrict__ Q, int N)
{
    __shared__ unsigned short s[NPB][136];  // input (96 cols), reused for P/Q staging (128)

    const int tid  = threadIdx.x;
    const int wv   = tid >> 6;
    const int lane = tid & 63;
    const int r    = lane >> 4;
    const int c    = lane & 15;
    const int base = blockIdx.x * NPB;

    for (int nl = wv; nl < NPB; nl += 4) {
        const int n = base + nl;
        s[nl][lane] = (n < N) ? f2bf(x[(size_t)n * 64 + lane]) : 0;
        if (lane < 32)
            s[nl][64 + lane] = (n < N && lane < 3) ? f2bf(pos[(size_t)n * 3 + lane]) : 0;
    }
    __syncthreads();

    bf16x8 a[3];
    #pragma unroll
    for (int ks = 0; ks < 3; ++ks)
        a[ks] = *(const bf16x8*)&s[wv * 16 + c][ks * 32 + r * 8];
    __syncthreads();   // all frag reads done before staging overwrites s

    f32x4 acc[16];
    #pragma unroll
    for (int nt = 0; nt < 16; ++nt) {
        const float bv = (nt < 8) ? b1[nt * 16 + c] : 0.f;  // bias folded into P
        acc[nt] = (f32x4){bv, bv, bv, bv};
    }
    #pragma unroll
    for (int nt = 0; nt < 16; ++nt)
        #pragma unroll
        for (int ks = 0; ks < 3; ++ks) {
            const bf16x8 b = *(const bf16x8*)(Wcp + (size_t)(nt * 3 + ks) * 512 + lane * 8);
            acc[nt] = __builtin_amdgcn_mfma_f32_16x16x32_bf16(a[ks], b, acc[nt], 0, 0, 0);
        }

    // ---- stage P rows in LDS, coalesced ushort4 store (32 ushort4/row!)
    #pragma unroll
    for (int nt = 0; nt < 8; ++nt)
        #pragma unroll
        for (int reg = 0; reg < 4; ++reg)
            s[wv * 16 + r * 4 + reg][nt * 16 + c] = f2bf(acc[nt][reg]);
    __syncthreads();
    {
        const int nl = tid >> 2, q = tid & 3;
        const int n = base + nl;
        if (n < N) {
            const ushort4* src = (const ushort4*)&s[nl][0];
            ushort4* dst = (ushort4*)(P + (size_t)n * 128);
            #pragma unroll
            for (int u = 0; u < 8; ++u) dst[q * 8 + u] = src[q * 8 + u];  // FIX: 8 per thread
        }
    }
    __syncthreads();

    // ---- stage Q rows, same path
    #pragma unroll
    for (int nt = 8; nt < 16; ++nt)
        #pragma unroll
        for (int reg = 0; reg < 4; ++reg)
            s[wv * 16 + r * 4 + reg][(nt - 8) * 16 + c] = f2bf(acc[nt][reg]);
    __syncthreads();
    {
        const int nl = tid >> 2, q = tid & 3;
        const int n = base + nl;
        if (n < N) {
            const ushort4* src = (const ushort4*)&s[nl][0];
            ushort4* dst = (ushort4*)(Q + (size_t)n * 128);
            #pragma unroll
            for (int u = 0; u < 8; ++u) dst[q * 8 + u] = src[q * 8 + u];  // FIX: 8 per thread
        }
    }
}

// ------- edge kernel: relu(P[i]+Q[j]) -> layer-2 MFMA -> fused seg-reduce ----

__global__ __launch_bounds__(256) void edge_aggr_mfma(
    const unsigned short* __restrict__ P, const unsigned short* __restrict__ Q,
    const int2* __restrict__ eij,
    const unsigned short* __restrict__ W2p, const float* __restrict__ b2,
    float* __restrict__ aggr, int E)
{
    __shared__ unsigned short s_m[EPB][72];  // msgs, 64 cols + 8 pad
    __shared__ int2 s_ij[EPB];
    __shared__ int  s_start[EPB + 4];        // run starts + terminator
    __shared__ int  s_wsumA[2];
    __shared__ int  s_nruns;

    const int tid  = threadIdx.x;
    const int wv   = tid >> 6;
    const int lane = tid & 63;
    const int r    = lane >> 4;
    const int c    = lane & 15;
    const int base = blockIdx.x * EPB;
    const int ne   = min(EPB, E - base);     // valid slots in this block (>=1)

    if (tid < EPB) {
        const int p = base + tid;
        int2 v; v.x = -1; v.y = -1;
        if (p < E) v = eij[p];
        s_ij[tid] = v;
    }
    __syncthreads();

    // ---- layer-2 A-frags: relu(P[i]+Q[j]) via packed-dword unpack/add/trunc
    bf16x8 a2[2][4];
    #pragma unroll
    for (int mh = 0; mh < 2; ++mh) {
        const int2 ij = s_ij[wv * 32 + mh * 16 + c];
        if (ij.x >= 0) {
            const unsigned* Pi = (const unsigned*)(P + (size_t)ij.x * 128);
            const unsigned* Qj = (const unsigned*)(Q + (size_t)ij.y * 128);
            #pragma unroll
            for (int ks = 0; ks < 4; ++ks) {
                const uint4 pu = *(const uint4*)(Pi + ks * 16 + r * 4);
                const uint4 qu = *(const uint4*)(Qj + ks * 16 + r * 4);
                uint4 h;
                h.x = relu_add_pk(pu.x, qu.x);
                h.y = relu_add_pk(pu.y, qu.y);
                h.z = relu_add_pk(pu.z, qu.z);
                h.w = relu_add_pk(pu.w, qu.w);
                a2[mh][ks] = *(const bf16x8*)&h;
            }
        } else {
            #pragma unroll
            for (int ks = 0; ks < 4; ++ks) a2[mh][ks] = (bf16x8){0,0,0,0,0,0,0,0};
        }
    }

    // ---- layer 2: msg = hidden @ W2 + b2, N=64, K=128
    f32x4 acc2[2][4];
    #pragma unroll
    for (int nt = 0; nt < 4; ++nt) {
        const float bv = b2[nt * 16 + c];
        acc2[0][nt] = (f32x4){bv, bv, bv, bv};
        acc2[1][nt] = (f32x4){bv, bv, bv, bv};
    }
    #pragma unroll
    for (int nt = 0; nt < 4; ++nt)
        #pragma unroll
        for (int ks = 0; ks < 4; ++ks) {
            const bf16x8 b = *(const bf16x8*)(W2p + (size_t)(nt * 4 + ks) * 512 + lane * 8);
            acc2[0][nt] = __builtin_amdgcn_mfma_f32_16x16x32_bf16(a2[0][ks], b, acc2[0][nt], 0, 0, 0);
            acc2[1][nt] = __builtin_amdgcn_mfma_f32_16x16x32_bf16(a2[1][ks], b, acc2[1][nt], 0, 0, 0);
        }

    // ---- msgs to LDS (bf16, RNE)
    #pragma unroll
    for (int mh = 0; mh < 2; ++mh)
        #pragma unroll
        for (int nt = 0; nt < 4; ++nt)
            #pragma unroll
            for (int reg = 0; reg < 4; ++reg) {
                const int row = wv * 32 + mh * 16 + r * 4 + reg;
                s_m[row][nt * 16 + c] = f2bf(acc2[mh][nt][reg]);
            }

    // ---- run detection over slots [0, ne)
    int flag = 0, incl = 0;
    if (tid < EPB) {
        flag = (tid < ne) && (tid == 0 || s_ij[tid].x != s_ij[tid - 1].x);
        incl = flag;
    }
    #pragma unroll
    for (int d = 1; d < 64; d <<= 1) {
        int t = __shfl_up(incl, d, 64);
        if (lane >= d) incl += t;
    }
    if (tid < EPB && lane == 63) s_wsumA[tid >> 6] = incl;
    __syncthreads();                         // also covers s_m writes above
    if (tid < EPB) {
        const int rid = incl + ((tid >= 64) ? s_wsumA[0] : 0);
        if (flag) s_start[rid - 1] = tid;
    }
    if (tid == 0) {
        const int nr = s_wsumA[0] + s_wsumA[1];
        s_nruns = nr;
        s_start[nr] = ne;
    }
    __syncthreads();

    // ---- segmented reduce: one wave per run, lanes = 64 cols
    for (int rn = wv; rn < s_nruns; rn += 4) {
        const int e0 = s_start[rn], e1 = s_start[rn + 1];
        const int i  = s_ij[e0].x;
        float acc = 0.f;
        for (int e = e0; e < e1; ++e)
            acc += bf2f(s_m[e][lane]);
        atomicAdd(&aggr[(size_t)i * 64 + lane], acc);
    }
}

// ---------------- node MLP (streaming aggr) ----------------

__global__ __launch_bounds__(256) void node_mlp_mfma(
    const float* __restrict__ x, const float* __restrict__ aggr,
    const int* __restrict__ off,
    const unsigned short* __restrict__ W3p, const float* __restrict__ b3,
    const unsigned short* __restrict__ W4p, const float* __restrict__ b4,
    float* __restrict__ out, int N)
{
    __shared__ unsigned short s_a[NPB][136];  // 128 + 8 pad

    const int tid  = threadIdx.x;
    const int wv   = tid >> 6;
    const int lane = tid & 63;
    const int r    = lane >> 4;
    const int c    = lane & 15;
    const int base = blockIdx.x * NPB;

    for (int nl = wv; nl < NPB; nl += 4) {
        const int n = base + nl;
        if (n < N) {
            s_a[nl][lane] = f2bf(x[(size_t)n * 64 + lane]);
            const int deg = off[n + 1] - off[n];
            const float a = aggr[(size_t)n * 64 + lane] / (float)max(deg, 1);
            s_a[nl][64 + lane] = f2bf(a);
        } else {
            s_a[nl][lane] = 0;
            s_a[nl][64 + lane] = 0;
        }
    }
    __syncthreads();

    bf16x8 a1[4];
    #pragma unroll
    for (int ks = 0; ks < 4; ++ks)
        a1[ks] = *(const bf16x8*)&s_a[wv * 16 + c][ks * 32 + r * 8];
    __syncthreads();

    f32x4 acc1[8];
    #pragma unroll
    for (int nt = 0; nt < 8; ++nt) {
        const float bv = b3[nt * 16 + c];
        acc1[nt] = (f32x4){bv, bv, bv, bv};
    }
    #pragma unroll
    for (int nt = 0; nt < 8; ++nt)
        #pragma unroll
        for (int ks = 0; ks < 4; ++ks) {
            const bf16x8 b = *(const bf16x8*)(W3p + (size_t)(nt * 4 + ks) * 512 + lane * 8);
            acc1[nt] = __builtin_amdgcn_mfma_f32_16x16x32_bf16(a1[ks], b, acc1[nt], 0, 0, 0);
        }
    #pragma unroll
    for (int nt = 0; nt < 8; ++nt)
        #pragma unroll
        for (int reg = 0; reg < 4; ++reg)
            s_a[wv * 16 + r * 4 + reg][nt * 16 + c] = f2bf(fmaxf(acc1[nt][reg], 0.f));
    __syncthreads();

    bf16x8 a2[4];
    #pragma unroll
    for (int ks = 0; ks < 4; ++ks)
        a2[ks] = *(const bf16x8*)&s_a[wv * 16 + c][ks * 32 + r * 8];
    __syncthreads();

    f32x4 acc2[4];
    #pragma unroll
    for (int nt = 0; nt < 4; ++nt) {
        const float bv = b4[nt * 16 + c];
        acc2[nt] = (f32x4){bv, bv, bv, bv};
    }
    #pragma unroll
    for (int nt = 0; nt < 4; ++nt)
        #pragma unroll
        for (int ks = 0; ks < 4; ++ks) {
            const bf16x8 b = *(const bf16x8*)(W4p + (size_t)(nt * 4 + ks) * 512 + lane * 8);
            acc2[nt] = __builtin_amdgcn_mfma_f32_16x16x32_bf16(a2[ks], b, acc2[nt], 0, 0, 0);
        }

    #pragma unroll
    for (int nt = 0; nt < 4; ++nt)
        #pragma unroll
        for (int reg = 0; reg < 4; ++reg) {
            float* row = (float*)&s_a[wv * 16 + r * 4 + reg][0];
            row[nt * 16 + c] = acc2[nt][reg];
        }
    __syncthreads();

    {
        const int nl = tid >> 2, q = tid & 3;
        const int n = base + nl;
        if (n < N) {
            const float4* src = (const float4*)((const float*)&s_a[nl][0] + q * 16);
            float4* dst = (float4*)(out + (size_t)n * 64 + q * 16);
            #pragma unroll
            for (int u = 0; u < 4; ++u) dst[u] = src[u];
        }
    }
}

// ---------------- fallback (atomic fp32 path, if ws too small) ----------------

#define EB 32
#define NB 32

__global__ __launch_bounds__(256) void mpnn_edge_atomic_kernel(
    const float* __restrict__ x, const float* __restrict__ pos,
    const int* __restrict__ ei0, const int* __restrict__ ei1,
    const float* __restrict__ W1, const float* __restrict__ b1,
    const float* __restrict__ W2, const float* __restrict__ b2,
    float* __restrict__ summed, float* __restrict__ counts, int E)
{
    __shared__ float s_in[EB][132];
    __shared__ int   s_idx[EB];

    const int tid  = threadIdx.x;
    const int base = blockIdx.x * EB;
    const int wv   = tid >> 6;
    const int lane = tid & 63;

    for (int e = wv; e < EB; e += 4) {
        const int ei = base + e;
        if (ei < E) {
            const int i = ei0[ei];
            const int j = ei1[ei];
            const float xi = x[(size_t)i * 64 + lane];
            const float xj = x[(size_t)j * 64 + lane];
            s_in[e][lane]      = xi;
            s_in[e][64 + lane] = xj - xi;
            if (lane < 3)
                s_in[e][128 + lane] = pos[(size_t)j * 3 + lane] - pos[(size_t)i * 3 + lane];
            if (lane == 0) s_idx[e] = i;
        } else {
            s_in[e][lane] = 0.f; s_in[e][64 + lane] = 0.f;
            if (lane < 3) s_in[e][128 + lane] = 0.f;
            if (lane == 0) s_idx[e] = -1;
        }
    }
    __syncthreads();

    float acc1[4][4];
    {
        const int cg = tid & 31;
        const int er = tid >> 5;
        const float4 bb = *(const float4*)(b1 + 4 * cg);
        #pragma unroll
        for (int t = 0; t < 4; ++t) {
            acc1[t][0] = bb.x; acc1[t][1] = bb.y; acc1[t][2] = bb.z; acc1[t][3] = bb.w;
        }
        for (int k = 0; k < 128; k += 4) {
            float wv4[4][4];
            #pragma unroll
            for (int kk = 0; kk < 4; ++kk) {
                const float4 w = *(const float4*)(W1 + (size_t)(k + kk) * 128 + 4 * cg);
                wv4[kk][0] = w.x; wv4[kk][1] = w.y; wv4[kk][2] = w.z; wv4[kk][3] = w.w;
            }
            #pragma unroll
            for (int t = 0; t < 4; ++t) {
                const float4 m = *(const float4*)(&s_in[er + 8 * t][k]);
                const float mm[4] = {m.x, m.y, m.z, m.w};
                #pragma unroll
                for (int kk = 0; kk < 4; ++kk)
                    #pragma unroll
                    for (int cc = 0; cc < 4; ++cc)
                        acc1[t][cc] += mm[kk] * wv4[kk][cc];
            }
        }
        for (int k = 128; k < 131; ++k) {
            float wk[4];
            #pragma unroll
            for (int cc = 0; cc < 4; ++cc) wk[cc] = W1[(size_t)k * 128 + 4 * cg + cc];
            #pragma unroll
            for (int t = 0; t < 4; ++t) {
                const float m = s_in[er + 8 * t][k];
                #pragma unroll
                for (int cc = 0; cc < 4; ++cc) acc1[t][cc] += m * wk[cc];
            }
        }
    }
    __syncthreads();
    {
        const int cg = tid & 31;
        const int er = tid >> 5;
        #pragma unroll
        for (int t = 0; t < 4; ++t)
            #pragma unroll
            for (int cc = 0; cc < 4; ++cc)
                s_in[er + 8 * t][4 * cg + cc] = fmaxf(acc1[t][cc], 0.f);
    }
    __syncthreads();
    {
        const int cg = tid & 15;
        const int er = tid >> 4;
        float acc[2][4];
        const float4 bb = *(const float4*)(b2 + 4 * cg);
        #pragma unroll
        for (int t = 0; t < 2; ++t) {
            acc[t][0] = bb.x; acc[t][1] = bb.y; acc[t][2] = bb.z; acc[t][3] = bb.w;
        }
        for (int k = 0; k < 128; k += 4) {
            float wv4[4][4];
            #pragma unroll
            for (int kk = 0; kk < 4; ++kk) {
                const float4 w = *(const float4*)(W2 + (size_t)(k + kk) * 64 + 4 * cg);
                wv4[kk][0] = w.x; wv4[kk][1] = w.y; wv4[kk][2] = w.z; wv4[kk][3] = w.w;
            }
            #pragma unroll
            for (int t = 0; t < 2; ++t) {
                const float4 m = *(const float4*)(&s_in[er + 16 * t][k]);
                const float mm[4] = {m.x, m.y, m.z, m.w};
                #pragma unroll
                for (int kk = 0; kk < 4; ++kk)
                    #pragma unroll
                    for (int cc = 0; cc < 4; ++cc)
                        acc[t][cc] += mm[kk] * wv4[kk][cc];
            }
        }
        #pragma unroll
        for (int t = 0; t < 2; ++t) {
            const int e = er + 16 * t;
            const int i = s_idx[e];
            if (i >= 0) {
                #pragma unroll
                for (int cc = 0; cc < 4; ++cc)
                    atomicAdd(&summed[(size_t)i * 64 + 4 * cg + cc], acc[t][cc]);
            }
        }
    }
    if (tid < EB) {
        const int i = s_idx[tid];
        if (i >= 0) atomicAdd(&counts[i], 1.0f);
    }
}

__global__ __launch_bounds__(256) void mpnn_node_legacy_kernel(
    const float* __restrict__ x, const float* __restrict__ summed,
    const float* __restrict__ counts,
    const float* __restrict__ W3, const float* __restrict__ b3,
    const float* __restrict__ W4, const float* __restrict__ b4,
    float* __restrict__ out, int N)
{
    __shared__ float s_in[NB][132];

    const int tid  = threadIdx.x;
    const int base = blockIdx.x * NB;
    const int wv   = tid >> 6;
    const int lane = tid & 63;

    for (int nl = wv; nl < NB; nl += 4) {
        const int n = base + nl;
        if (n < N) {
            s_in[nl][lane] = x[(size_t)n * 64 + lane];
            const float inv = 1.0f / fmaxf(counts[n], 1.0f);
            s_in[nl][64 + lane] = summed[(size_t)n * 64 + lane] * inv;
        } else {
            s_in[nl][lane] = 0.f; s_in[nl][64 + lane] = 0.f;
        }
    }
    __syncthreads();

    float acc1[4][4];
    {
        const int cg = tid & 31;
        const int er = tid >> 5;
        const float4 bb = *(const float4*)(b3 + 4 * cg);
        #pragma unroll
        for (int t = 0; t < 4; ++t) {
            acc1[t][0] = bb.x; acc1[t][1] = bb.y; acc1[t][2] = bb.z; acc1[t][3] = bb.w;
        }
        for (int k = 0; k < 128; k += 4) {
            float wv4[4][4];
            #pragma unroll
            for (int kk = 0; kk < 4; ++kk) {
                const float4 w = *(const float4*)(W3 + (size_t)(k + kk) * 128 + 4 * cg);
                wv4[kk][0] = w.x; wv4[kk][1] = w.y; wv4[kk][2] = w.z; wv4[kk][3] = w.w;
            }
            #pragma unroll
            for (int t = 0; t < 4; ++t) {
                const float4 m = *(const float4*)(&s_in[er + 8 * t][k]);
                const float mm[4] = {m.x, m.y, m.z, m.w};
                #pragma unroll
                for (int kk = 0; kk < 4; ++kk)
                    #pragma unroll
                    for (int cc = 0; cc < 4; ++cc)
                        acc1[t][cc] += mm[kk] * wv4[kk][cc];
            }
        }
    }
    __syncthreads();
    {
        const int cg = tid & 31;
        const int er = tid >> 5;
        #pragma unroll
        for (int t = 0; t < 4; ++t)
            #pragma unroll
            for (int cc = 0; cc < 4; ++cc)
                s_in[er + 8 * t][4 * cg + cc] = fmaxf(acc1[t][cc], 0.f);
    }
    __syncthreads();
    {
        const int cg = tid & 15;
        const int er = tid >> 4;
        float acc[2][4];
        const float4 bb = *(const float4*)(b4 + 4 * cg);
        #pragma unroll
        for (int t = 0; t < 2; ++t) {
            acc[t][0] = bb.x; acc[t][1] = bb.y; acc[t][2] = bb.z; acc[t][3] = bb.w;
        }
        for (int k = 0; k < 128; k += 4) {
            float wv4[4][4];
            #pragma unroll
            for (int kk = 0; kk < 4; ++kk) {
                const float4 w = *(const float4*)(W4 + (size_t)(k + kk) * 64 + 4 * cg);
                wv4[kk][0] = w.x; wv4[kk][1] = w.y; wv4[kk][2] = w.z; wv4[kk][3] = w.w;
            }
            #pragma unroll
            for (int t = 0; t < 2; ++t) {
                const float4 m = *(const float4*)(&s_in[er + 16 * t][k]);
                const float mm[4] = {m.x, m.y, m.z, m.w};
                #pragma unroll
                for (int kk = 0; kk < 4; ++kk)
                    #pragma unroll
                    for (int cc = 0; cc < 4; ++cc)
                        acc[t][cc] += mm[kk] * wv4[kk][cc];
            }
        }
        #pragma unroll
        for (int t = 0; t < 2; ++t) {
            const int n = base + er + 16 * t;
            if (n < N) {
                float4 o;
                o.x = acc[t][0]; o.y = acc[t][1]; o.z = acc[t][2]; o.w = acc[t][3];
                *(float4*)(out + (size_t)n * 64 + 4 * cg) = o;
            }
        }
    }
}

// ---------------- launch ----------------

static inline size_t rup(size_t v) { return (v + 255) & ~(size_t)255; }

extern "C" void kernel_launch(void* const* d_in, const int* in_sizes, int n_in,
                              void* d_out, int out_size, void* d_ws, size_t ws_size,
                              hipStream_t stream) {
    const float* x    = (const float*)d_in[0];
    const float* pos  = (const float*)d_in[1];
    const int*   eidx = (const int*)d_in[2];
    const float* W1   = (const float*)d_in[3];
    const float* b1   = (const float*)d_in[4];
    const float* W2   = (const float*)d_in[5];
    const float* b2   = (const float*)d_in[6];
    const float* W3   = (const float*)d_in[7];
    const float* b3   = (const float*)d_in[8];
    const float* W4   = (const float*)d_in[9];
    const float* b4   = (const float*)d_in[10];

    const int N = in_sizes[0] / 64;
    const int E = in_sizes[2] / 2;
    const int* ei0 = eidx;       // edge_index[0] = aggregation node i
    const int* ei1 = eidx + E;   // edge_index[1] = neighbor j
    const int nb = (N + 1023) / 1024;

    const size_t p_b    = rup((size_t)N * 128 * 2);
    const size_t q_b    = rup((size_t)N * 128 * 2);
    const size_t wcp_b  = rup(48 * 512 * 2);
    const size_t w2p_b  = rup(16 * 512 * 2);
    const size_t w3p_b  = rup(32 * 512 * 2);
    const size_t w4p_b  = rup(16 * 512 * 2);
    const size_t aggr_b = rup((size_t)N * 64 * 4);
    const size_t cnt_b  = rup((size_t)N * 4);
    const size_t off_b  = rup((size_t)(N + 1) * 4);
    const size_t bsum_b = rup(256 * 4);
    const size_t rank_b = rup((size_t)E * 4);
    const size_t eij_b  = rup((size_t)E * 8);
    const size_t need = p_b + q_b + wcp_b + w2p_b + w3p_b + w4p_b +
                        aggr_b + cnt_b + off_b + bsum_b + rank_b + eij_b;

    if (ws_size >= need) {
        char* p = (char*)d_ws;
        unsigned short* P   = (unsigned short*)p;  p += p_b;
        unsigned short* Q   = (unsigned short*)p;  p += q_b;
        unsigned short* Wcp = (unsigned short*)p;  p += wcp_b;
        unsigned short* W2p = (unsigned short*)p;  p += w2p_b;
        unsigned short* W3p = (unsigned short*)p;  p += w3p_b;
        unsigned short* W4p = (unsigned short*)p;  p += w4p_b;
        float* aggr = (float*)p;  p += aggr_b;
        int* cnt  = (int*)p;  p += cnt_b;
        int* off  = (int*)p;  p += off_b;
        int* bsum = (int*)p;  p += bsum_b;
        int* rank = (int*)p;  p += rank_b;
        int2* eij = (int2*)p;

        // zero aggr + cnt in one shot (adjacent)
        hipMemsetAsync(aggr, 0, aggr_b + cnt_b, stream);

        pack_weights_kernel<<<112, 64, 0, stream>>>(W1, W2, W3, W4, Wcp, W2p, W3p, W4p);
        pq_kernel<<<(N + NPB - 1) / NPB, 256, 0, stream>>>(x, pos, Wcp, b1, P, Q, N);

        const int eb256 = (E + 255) / 256;
        count_kernel<<<eb256, 256, 0, stream>>>(ei0, cnt, rank, E);
        scanA_kernel<<<nb, 1024, 0, stream>>>(cnt, bsum, N);
        scanC_kernel<<<nb, 1024, 0, stream>>>(cnt, bsum, off, N, E);
        fill_kernel<<<eb256, 256, 0, stream>>>(ei0, ei1, off, rank, eij, E);

        edge_aggr_mfma<<<(E + EPB - 1) / EPB, 256, 0, stream>>>(
            P, Q, eij, W2p, b2, aggr, E);

        node_mlp_mfma<<<(N + NPB - 1) / NPB, 256, 0, stream>>>(
            x, aggr, off, W3p, b3, W4p, b4, (float*)d_out, N);
    } else {
        // fallback: atomic fp32 path
        float* summed = (float*)d_ws;
        float* counts = summed + (size_t)N * 64;
        hipMemsetAsync(d_ws, 0, ((size_t)N * 64 + N) * sizeof(float), stream);

        mpnn_edge_atomic_kernel<<<(E + EB - 1) / EB, 256, 0, stream>>>(
            x, pos, ei0, ei1, W1, b1, W2, b2, summed, counts, E);
        mpnn_node_legacy_kernel<<<(N + NB - 1) / NB, 256, 0, stream>>>(
            x, summed, counts, W3, b3, W4, b4, (float*)d_out, N);
    }
}

// Round 11
// 256.405 us; speedup vs baseline: 4.2484x; 1.0225x over previous
//
#include <hip/hip_runtime.h>

// MPNN: edge MLP (131->128->64) + scatter-mean + node MLP (128->128->64)
// N=50000, E=800000, fp32 in/out.
// R11: dispatch-chain collapse (9 -> 6 kernels) + XCD-contiguous edge blocks.
//  K1 prep     = pack-weights (28 blocks) U count+rank (3125 blocks) + bsum sentinels
//  K2 pq_scan  = per-node P/Q projection (782 blocks) U decoupled-lookback
//                exclusive scan of cnt -> off (196 blocks; all co-resident)
//  K3 fill     = atomic-free CSR permute via rank[]
//  K4 edge     = relu(P[i]+Q[j]) -> layer-2 MFMA -> fused seg-reduce -> aggr
//                (blockIdx swizzled so each XCD gets a contiguous slot range)
//  K5 node     = streaming node MLP
// Factorization (exact): hidden = relu(P[i]+Q[j]),
//   P = x@(W1a-W1b) - pos@W1c + b1,  Q = x@W1b + pos@W1c.

#define EPB 128  // edges per block (4 waves x M=32)
#define NPB 64   // nodes per block (4 waves x M=16)

typedef __attribute__((ext_vector_type(8))) short bf16x8;
typedef __attribute__((ext_vector_type(4))) float f32x4;

static __device__ __forceinline__ unsigned short f2bf(float f) {
    union { float f; unsigned u; } v; v.f = f;
    unsigned u = v.u + 0x7FFFu + ((v.u >> 16) & 1u);  // RNE
    return (unsigned short)(u >> 16);
}
static __device__ __forceinline__ float bf2f(unsigned short h) {
    union { unsigned u; float f; } v; v.u = ((unsigned)h) << 16;
    return v.f;
}
// packed: two bf16 in u32 -> relu(p+q) -> two bf16 (truncating round)
static __device__ __forceinline__ unsigned relu_add_pk(unsigned pu, unsigned qu) {
    union { unsigned u; float f; } plo, phi, qlo, qhi, lo, hi;
    plo.u = pu << 16;           phi.u = pu & 0xffff0000u;
    qlo.u = qu << 16;           qhi.u = qu & 0xffff0000u;
    lo.f = fmaxf(plo.f + qlo.f, 0.f);
    hi.f = fmaxf(phi.f + qhi.f, 0.f);
    return (hi.u & 0xffff0000u) | (lo.u >> 16);
}

// ---------------- K1: pack weights U count(+rank) U bsum sentinels ----------
// blocks 0..27: pack (4 frags/block, one per wave); blocks 28..: count.

__global__ __launch_bounds__(256) void prep_kernel(
    const float* __restrict__ W1, const float* __restrict__ W2,
    const float* __restrict__ W3, const float* __restrict__ W4,
    unsigned short* __restrict__ Wcp, unsigned short* __restrict__ W2p,
    unsigned short* __restrict__ W3p, unsigned short* __restrict__ W4p,
    const int* __restrict__ ei0, int* __restrict__ cnt,
    int* __restrict__ rank, int* __restrict__ bsum, int E)
{
    const int tid = threadIdx.x;
    if (blockIdx.x < 28) {
        if (blockIdx.x == 0) bsum[tid] = -1;   // lookback sentinels (256 slots)
        int f = blockIdx.x * 4 + (tid >> 6);   // 0..111
        const int lane = tid & 63;
        if (f < 48) {
            const int nt = f / 3, ks = f % 3;
            const int n  = nt * 16 + (lane & 15);
            const int k0 = ks * 32 + (lane >> 4) * 8;
            unsigned short* dst = Wcp + (size_t)f * 512 + lane * 8;
            #pragma unroll
            for (int j = 0; j < 8; ++j) {
                const int k = k0 + j;
                float v = 0.f;
                if (n < 128) {          // P-part
                    if (k < 64)       v = W1[(size_t)k * 128 + n] - W1[(size_t)(64 + k) * 128 + n];
                    else if (k < 67)  v = -W1[(size_t)(128 + k - 64) * 128 + n];
                } else {                // Q-part
                    const int nq = n - 128;
                    if (k < 64)       v = W1[(size_t)(64 + k) * 128 + nq];
                    else if (k < 67)  v = W1[(size_t)(128 + k - 64) * 128 + nq];
                }
                dst[j] = f2bf(v);
            }
            return;
        }
        const float* W; unsigned short* out; int K, N, KS;
        if (f < 64)      { W = W2; out = W2p; K = 128; N = 64;  KS = 4; f -= 48; }
        else if (f < 96) { W = W3; out = W3p; K = 128; N = 128; KS = 4; f -= 64; }
        else             { W = W4; out = W4p; K = 128; N = 64;  KS = 4; f -= 96; }
        const int nt = f / KS, ks = f % KS;
        const int n  = nt * 16 + (lane & 15);
        const int k0 = ks * 32 + (lane >> 4) * 8;
        unsigned short* dst = out + (size_t)f * 512 + lane * 8;
        #pragma unroll
        for (int j = 0; j < 8; ++j) {
            float v = (k0 + j < K) ? W[(size_t)(k0 + j) * N + n] : 0.f;
            dst[j] = f2bf(v);
        }
    } else {
        const int e = (blockIdx.x - 28) * 256 + tid;
        if (e < E) rank[e] = atomicAdd(&cnt[ei0[e]], 1);
    }
}

// ---------------- K2: pq projection U decoupled-lookback scan ----------------
// blocks [0, pqBlocks): P,Q = [x|pos] @ Wc (+b1 on P)
// blocks [pqBlocks, +scanBlocks): exclusive scan cnt -> off via lookback on bsum.

__global__ __launch_bounds__(256) void pq_scan_kernel(
    const float* __restrict__ x, const float* __restrict__ pos,
    const unsigned short* __restrict__ Wcp, const float* __restrict__ b1,
    unsigned short* __restrict__ P, unsigned short* __restrict__ Q,
    const int* __restrict__ cnt, int* __restrict__ bsum,
    int* __restrict__ off, int N, int Etot)
{
    __shared__ unsigned short s[NPB][136];
    __shared__ int wsum[4];
    __shared__ int s_boff;

    const int tid  = threadIdx.x;
    const int pqBlocks = (N + NPB - 1) / NPB;

    if ((int)blockIdx.x >= pqBlocks) {
        // ---- lookback scan: 256 cnt values per block
        const int s_id = blockIdx.x - pqBlocks;
        const int scanBlocks = (N + 255) >> 8;
        const int i = s_id * 256 + tid;
        const int lane = tid & 63, w = tid >> 6;
        const int v = (i < N) ? cnt[i] : 0;
        int incl = v;
        #pragma unroll
        for (int d = 1; d < 64; d <<= 1) {
            int t = __shfl_up(incl, d, 64);
            if (lane >= d) incl += t;
        }
        if (lane == 63) wsum[w] = incl;
        if (tid == 0) s_boff = 0;
        __syncthreads();
        int pre = 0;
        for (int k = 0; k < w; ++k) pre += wsum[k];
        const int btot = wsum[0] + wsum[1] + wsum[2] + wsum[3];
        if (tid == 0) atomicExch(&bsum[s_id], btot);    // publish (device scope)
        if (tid < s_id) {                               // one predecessor/thread
            int val;
            do { val = atomicAdd(&bsum[tid], 0); } while (val == -1);
            atomicAdd(&s_boff, val);                    // LDS atomic
        }
        __syncthreads();
        if (i < N) off[i] = s_boff + pre + incl - v;
        if (s_id == scanBlocks - 1 && tid == 0) off[N] = Etot;
        return;
    }

    // ---- pq part
    const int wv   = tid >> 6;
    const int lane = tid & 63;
    const int r    = lane >> 4;
    const int c    = lane & 15;
    const int base = blockIdx.x * NPB;

    for (int nl = wv; nl < NPB; nl += 4) {
        const int n = base + nl;
        s[nl][lane] = (n < N) ? f2bf(x[(size_t)n * 64 + lane]) : 0;
        if (lane < 32)
            s[nl][64 + lane] = (n < N && lane < 3) ? f2bf(pos[(size_t)n * 3 + lane]) : 0;
    }
    __syncthreads();

    bf16x8 a[3];
    #pragma unroll
    for (int ks = 0; ks < 3; ++ks)
        a[ks] = *(const bf16x8*)&s[wv * 16 + c][ks * 32 + r * 8];
    __syncthreads();   // all frag reads done before staging overwrites s

    f32x4 acc[16];
    #pragma unroll
    for (int nt = 0; nt < 16; ++nt) {
        const float bv = (nt < 8) ? b1[nt * 16 + c] : 0.f;  // bias folded into P
        acc[nt] = (f32x4){bv, bv, bv, bv};
    }
    #pragma unroll
    for (int nt = 0; nt < 16; ++nt)
        #pragma unroll
        for (int ks = 0; ks < 3; ++ks) {
            const bf16x8 b = *(const bf16x8*)(Wcp + (size_t)(nt * 3 + ks) * 512 + lane * 8);
            acc[nt] = __builtin_amdgcn_mfma_f32_16x16x32_bf16(a[ks], b, acc[nt], 0, 0, 0);
        }

    // ---- stage P rows in LDS, coalesced ushort4 store (32 ushort4/row)
    #pragma unroll
    for (int nt = 0; nt < 8; ++nt)
        #pragma unroll
        for (int reg = 0; reg < 4; ++reg)
            s[wv * 16 + r * 4 + reg][nt * 16 + c] = f2bf(acc[nt][reg]);
    __syncthreads();
    {
        const int nl = tid >> 2, q = tid & 3;
        const int n = base + nl;
        if (n < N) {
            const ushort4* src = (const ushort4*)&s[nl][0];
            ushort4* dst = (ushort4*)(P + (size_t)n * 128);
            #pragma unroll
            for (int u = 0; u < 8; ++u) dst[q * 8 + u] = src[q * 8 + u];
        }
    }
    __syncthreads();

    // ---- stage Q rows, same path
    #pragma unroll
    for (int nt = 8; nt < 16; ++nt)
        #pragma unroll
        for (int reg = 0; reg < 4; ++reg)
            s[wv * 16 + r * 4 + reg][(nt - 8) * 16 + c] = f2bf(acc[nt][reg]);
    __syncthreads();
    {
        const int nl = tid >> 2, q = tid & 3;
        const int n = base + nl;
        if (n < N) {
            const ushort4* src = (const ushort4*)&s[nl][0];
            ushort4* dst = (ushort4*)(Q + (size_t)n * 128);
            #pragma unroll
            for (int u = 0; u < 8; ++u) dst[q * 8 + u] = src[q * 8 + u];
        }
    }
}

// ---------------- K3: atomic-free CSR permute ----------------

__global__ __launch_bounds__(256) void fill_kernel(
    const int* __restrict__ ei0, const int* __restrict__ ei1,
    const int* __restrict__ off, const int* __restrict__ rank,
    int2* __restrict__ eij, int E)
{
    int e = blockIdx.x * 256 + threadIdx.x;
    if (e < E) {
        const int i = ei0[e];
        int2 v; v.x = i; v.y = ei1[e];
        eij[off[i] + rank[e]] = v;
    }
}

// ------- K4: relu(P[i]+Q[j]) -> layer-2 MFMA -> fused seg-reduce ----

__global__ __launch_bounds__(256) void edge_aggr_mfma(
    const unsigned short* __restrict__ P, const unsigned short* __restrict__ Q,
    const int2* __restrict__ eij,
    const unsigned short* __restrict__ W2p, const float* __restrict__ b2,
    float* __restrict__ aggr, int E)
{
    __shared__ unsigned short s_m[EPB][72];  // msgs, 64 cols + 8 pad
    __shared__ int2 s_ij[EPB];
    __shared__ int  s_start[EPB + 4];        // run starts + terminator
    __shared__ int  s_wsumA[2];
    __shared__ int  s_nruns;

    const int tid  = threadIdx.x;
    const int wv   = tid >> 6;
    const int lane = tid & 63;
    const int r    = lane >> 4;
    const int c    = lane & 15;

    // XCD-contiguous swizzle: grid padded to x8; XCD k (round-robin heuristic)
    // gets contiguous slot range -> P gathers localized to ~1.6MB/XCD.
    const int per  = gridDim.x >> 3;
    const int swz  = (blockIdx.x & 7) * per + (blockIdx.x >> 3);
    const int base = swz * EPB;
    if (base >= E) return;
    const int ne   = min(EPB, E - base);     // valid slots in this block (>=1)

    if (tid < EPB) {
        const int p = base + tid;
        int2 v; v.x = -1; v.y = -1;
        if (p < E) v = eij[p];
        s_ij[tid] = v;
    }
    __syncthreads();

    // ---- layer-2 A-frags: relu(P[i]+Q[j]) via packed-dword unpack/add/trunc
    bf16x8 a2[2][4];
    #pragma unroll
    for (int mh = 0; mh < 2; ++mh) {
        const int2 ij = s_ij[wv * 32 + mh * 16 + c];
        if (ij.x >= 0) {
            const unsigned* Pi = (const unsigned*)(P + (size_t)ij.x * 128);
            const unsigned* Qj = (const unsigned*)(Q + (size_t)ij.y * 128);
            #pragma unroll
            for (int ks = 0; ks < 4; ++ks) {
                const uint4 pu = *(const uint4*)(Pi + ks * 16 + r * 4);
                const uint4 qu = *(const uint4*)(Qj + ks * 16 + r * 4);
                uint4 h;
                h.x = relu_add_pk(pu.x, qu.x);
                h.y = relu_add_pk(pu.y, qu.y);
                h.z = relu_add_pk(pu.z, qu.z);
                h.w = relu_add_pk(pu.w, qu.w);
                a2[mh][ks] = *(const bf16x8*)&h;
            }
        } else {
            #pragma unroll
            for (int ks = 0; ks < 4; ++ks) a2[mh][ks] = (bf16x8){0,0,0,0,0,0,0,0};
        }
    }

    // ---- layer 2: msg = hidden @ W2 + b2, N=64, K=128
    f32x4 acc2[2][4];
    #pragma unroll
    for (int nt = 0; nt < 4; ++nt) {
        const float bv = b2[nt * 16 + c];
        acc2[0][nt] = (f32x4){bv, bv, bv, bv};
        acc2[1][nt] = (f32x4){bv, bv, bv, bv};
    }
    #pragma unroll
    for (int nt = 0; nt < 4; ++nt)
        #pragma unroll
        for (int ks = 0; ks < 4; ++ks) {
            const bf16x8 b = *(const bf16x8*)(W2p + (size_t)(nt * 4 + ks) * 512 + lane * 8);
            acc2[0][nt] = __builtin_amdgcn_mfma_f32_16x16x32_bf16(a2[0][ks], b, acc2[0][nt], 0, 0, 0);
            acc2[1][nt] = __builtin_amdgcn_mfma_f32_16x16x32_bf16(a2[1][ks], b, acc2[1][nt], 0, 0, 0);
        }

    // ---- msgs to LDS (bf16, RNE)
    #pragma unroll
    for (int mh = 0; mh < 2; ++mh)
        #pragma unroll
        for (int nt = 0; nt < 4; ++nt)
            #pragma unroll
            for (int reg = 0; reg < 4; ++reg) {
                const int row = wv * 32 + mh * 16 + r * 4 + reg;
                s_m[row][nt * 16 + c] = f2bf(acc2[mh][nt][reg]);
            }

    // ---- run detection over slots [0, ne)
    int flag = 0, incl = 0;
    if (tid < EPB) {
        flag = (tid < ne) && (tid == 0 || s_ij[tid].x != s_ij[tid - 1].x);
        incl = flag;
    }
    #pragma unroll
    for (int d = 1; d < 64; d <<= 1) {
        int t = __shfl_up(incl, d, 64);
        if (lane >= d) incl += t;
    }
    if (tid < EPB && lane == 63) s_wsumA[tid >> 6] = incl;
    __syncthreads();                         // also covers s_m writes above
    if (tid < EPB) {
        const int rid = incl + ((tid >= 64) ? s_wsumA[0] : 0);
        if (flag) s_start[rid - 1] = tid;
    }
    if (tid == 0) {
        const int nr = s_wsumA[0] + s_wsumA[1];
        s_nruns = nr;
        s_start[nr] = ne;
    }
    __syncthreads();

    // ---- segmented reduce: one wave per run, lanes = 64 cols
    for (int rn = wv; rn < s_nruns; rn += 4) {
        const int e0 = s_start[rn], e1 = s_start[rn + 1];
        const int i  = s_ij[e0].x;
        float acc = 0.f;
        for (int e = e0; e < e1; ++e)
            acc += bf2f(s_m[e][lane]);
        atomicAdd(&aggr[(size_t)i * 64 + lane], acc);
    }
}

// ---------------- K5: node MLP (streaming aggr) ----------------

__global__ __launch_bounds__(256) void node_mlp_mfma(
    const float* __restrict__ x, const float* __restrict__ aggr,
    const int* __restrict__ off,
    const unsigned short* __restrict__ W3p, const float* __restrict__ b3,
    const unsigned short* __restrict__ W4p, const float* __restrict__ b4,
    float* __restrict__ out, int N)
{
    __shared__ unsigned short s_a[NPB][136];  // 128 + 8 pad

    const int tid  = threadIdx.x;
    const int wv   = tid >> 6;
    const int lane = tid & 63;
    const int r    = lane >> 4;
    const int c    = lane & 15;
    const int base = blockIdx.x * NPB;

    for (int nl = wv; nl < NPB; nl += 4) {
        const int n = base + nl;
        if (n < N) {
            s_a[nl][lane] = f2bf(x[(size_t)n * 64 + lane]);
            const int deg = off[n + 1] - off[n];
            const float a = aggr[(size_t)n * 64 + lane] / (float)max(deg, 1);
            s_a[nl][64 + lane] = f2bf(a);
        } else {
            s_a[nl][lane] = 0;
            s_a[nl][64 + lane] = 0;
        }
    }
    __syncthreads();

    bf16x8 a1[4];
    #pragma unroll
    for (int ks = 0; ks < 4; ++ks)
        a1[ks] = *(const bf16x8*)&s_a[wv * 16 + c][ks * 32 + r * 8];
    __syncthreads();

    f32x4 acc1[8];
    #pragma unroll
    for (int nt = 0; nt < 8; ++nt) {
        const float bv = b3[nt * 16 + c];
        acc1[nt] = (f32x4){bv, bv, bv, bv};
    }
    #pragma unroll
    for (int nt = 0; nt < 8; ++nt)
        #pragma unroll
        for (int ks = 0; ks < 4; ++ks) {
            const bf16x8 b = *(const bf16x8*)(W3p + (size_t)(nt * 4 + ks) * 512 + lane * 8);
            acc1[nt] = __builtin_amdgcn_mfma_f32_16x16x32_bf16(a1[ks], b, acc1[nt], 0, 0, 0);
        }
    #pragma unroll
    for (int nt = 0; nt < 8; ++nt)
        #pragma unroll
        for (int reg = 0; reg < 4; ++reg)
            s_a[wv * 16 + r * 4 + reg][nt * 16 + c] = f2bf(fmaxf(acc1[nt][reg], 0.f));
    __syncthreads();

    bf16x8 a2[4];
    #pragma unroll
    for (int ks = 0; ks < 4; ++ks)
        a2[ks] = *(const bf16x8*)&s_a[wv * 16 + c][ks * 32 + r * 8];
    __syncthreads();

    f32x4 acc2[4];
    #pragma unroll
    for (int nt = 0; nt < 4; ++nt) {
        const float bv = b4[nt * 16 + c];
        acc2[nt] = (f32x4){bv, bv, bv, bv};
    }
    #pragma unroll
    for (int nt = 0; nt < 4; ++nt)
        #pragma unroll
        for (int ks = 0; ks < 4; ++ks) {
            const bf16x8 b = *(const bf16x8*)(W4p + (size_t)(nt * 4 + ks) * 512 + lane * 8);
            acc2[nt] = __builtin_amdgcn_mfma_f32_16x16x32_bf16(a2[ks], b, acc2[nt], 0, 0, 0);
        }

    #pragma unroll
    for (int nt = 0; nt < 4; ++nt)
        #pragma unroll
        for (int reg = 0; reg < 4; ++reg) {
            float* row = (float*)&s_a[wv * 16 + r * 4 + reg][0];
            row[nt * 16 + c] = acc2[nt][reg];
        }
    __syncthreads();

    {
        const int nl = tid >> 2, q = tid & 3;
        const int n = base + nl;
        if (n < N) {
            const float4* src = (const float4*)((const float*)&s_a[nl][0] + q * 16);
            float4* dst = (float4*)(out + (size_t)n * 64 + q * 16);
            #pragma unroll
            for (int u = 0; u < 4; ++u) dst[u] = src[u];
        }
    }
}

// ---------------- fallback (atomic fp32 path, if ws too small) ----------------

#define EB 32
#define NB 32

__global__ __launch_bounds__(256) void mpnn_edge_atomic_kernel(
    const float* __restrict__ x, const float* __restrict__ pos,
    const int* __restrict__ ei0, const int* __restrict__ ei1,
    const float* __restrict__ W1, const float* __restrict__ b1,
    const float* __restrict__ W2, const float* __restrict__ b2,
    float* __restrict__ summed, float* __restrict__ counts, int E)
{
    __shared__ float s_in[EB][132];
    __shared__ int   s_idx[EB];

    const int tid  = threadIdx.x;
    const int base = blockIdx.x * EB;
    const int wv   = tid >> 6;
    const int lane = tid & 63;

    for (int e = wv; e < EB; e += 4) {
        const int ei = base + e;
        if (ei < E) {
            const int i = ei0[ei];
            const int j = ei1[ei];
            const float xi = x[(size_t)i * 64 + lane];
            const float xj = x[(size_t)j * 64 + lane];
            s_in[e][lane]      = xi;
            s_in[e][64 + lane] = xj - xi;
            if (lane < 3)
                s_in[e][128 + lane] = pos[(size_t)j * 3 + lane] - pos[(size_t)i * 3 + lane];
            if (lane == 0) s_idx[e] = i;
        } else {
            s_in[e][lane] = 0.f; s_in[e][64 + lane] = 0.f;
            if (lane < 3) s_in[e][128 + lane] = 0.f;
            if (lane == 0) s_idx[e] = -1;
        }
    }
    __syncthreads();

    float acc1[4][4];
    {
        const int cg = tid & 31;
        const int er = tid >> 5;
        const float4 bb = *(const float4*)(b1 + 4 * cg);
        #pragma unroll
        for (int t = 0; t < 4; ++t) {
            acc1[t][0] = bb.x; acc1[t][1] = bb.y; acc1[t][2] = bb.z; acc1[t][3] = bb.w;
        }
        for (int k = 0; k < 128; k += 4) {
            float wv4[4][4];
            #pragma unroll
            for (int kk = 0; kk < 4; ++kk) {
                const float4 w = *(const float4*)(W1 + (size_t)(k + kk) * 128 + 4 * cg);
                wv4[kk][0] = w.x; wv4[kk][1] = w.y; wv4[kk][2] = w.z; wv4[kk][3] = w.w;
            }
            #pragma unroll
            for (int t = 0; t < 4; ++t) {
                const float4 m = *(const float4*)(&s_in[er + 8 * t][k]);
                const float mm[4] = {m.x, m.y, m.z, m.w};
                #pragma unroll
                for (int kk = 0; kk < 4; ++kk)
                    #pragma unroll
                    for (int cc = 0; cc < 4; ++cc)
                        acc1[t][cc] += mm[kk] * wv4[kk][cc];
            }
        }
        for (int k = 128; k < 131; ++k) {
            float wk[4];
            #pragma unroll
            for (int cc = 0; cc < 4; ++cc) wk[cc] = W1[(size_t)k * 128 + 4 * cg + cc];
            #pragma unroll
            for (int t = 0; t < 4; ++t) {
                const float m = s_in[er + 8 * t][k];
                #pragma unroll
                for (int cc = 0; cc < 4; ++cc) acc1[t][cc] += m * wk[cc];
            }
        }
    }
    __syncthreads();
    {
        const int cg = tid & 31;
        const int er = tid >> 5;
        #pragma unroll
        for (int t = 0; t < 4; ++t)
            #pragma unroll
            for (int cc = 0; cc < 4; ++cc)
                s_in[er + 8 * t][4 * cg + cc] = fmaxf(acc1[t][cc], 0.f);
    }
    __syncthreads();
    {
        const int cg = tid & 15;
        const int er = tid >> 4;
        float acc[2][4];
        const float4 bb = *(const float4*)(b2 + 4 * cg);
        #pragma unroll
        for (int t = 0; t < 2; ++t) {
            acc[t][0] = bb.x; acc[t][1] = bb.y; acc[t][2] = bb.z; acc[t][3] = bb.w;
        }
        for (int k = 0; k < 128; k += 4) {
            float wv4[4][4];
            #pragma unroll
            for (int kk = 0; kk < 4; ++kk) {
                const float4 w = *(const float4*)(W2 + (size_t)(k + kk) * 64 + 4 * cg);
                wv4[kk][0] = w.x; wv4[kk][1] = w.y; wv4[kk][2] = w.z; wv4[kk][3] = w.w;
            }
            #pragma unroll
            for (int t = 0; t < 2; ++t) {
                const float4 m = *(const float4*)(&s_in[er + 16 * t][k]);
                const float mm[4] = {m.x, m.y, m.z, m.w};
                #pragma unroll
                for (int kk = 0; kk < 4; ++kk)
                    #pragma unroll
                    for (int cc = 0; cc < 4; ++cc)
                        acc[t][cc] += mm[kk] * wv4[kk][cc];
            }
        }
        #pragma unroll
        for (int t = 0; t < 2; ++t) {
            const int e = er + 16 * t;
            const int i = s_idx[e];
            if (i >= 0) {
                #pragma unroll
                for (int cc = 0; cc < 4; ++cc)
                    atomicAdd(&summed[(size_t)i * 64 + 4 * cg + cc], acc[t][cc]);
            }
        }
    }
    if (tid < EB) {
        const int i = s_idx[tid];
        if (i >= 0) atomicAdd(&counts[i], 1.0f);
    }
}

__global__ __launch_bounds__(256) void mpnn_node_legacy_kernel(
    const float* __restrict__ x, const float* __restrict__ summed,
    const float* __restrict__ counts,
    const float* __restrict__ W3, const float* __restrict__ b3,
    const float* __restrict__ W4, const float* __restrict__ b4,
    float* __restrict__ out, int N)
{
    __shared__ float s_in[NB][132];

    const int tid  = threadIdx.x;
    const int base = blockIdx.x * NB;
    const int wv   = tid >> 6;
    const int lane = tid & 63;

    for (int nl = wv; nl < NB; nl += 4) {
        const int n = base + nl;
        if (n < N) {
            s_in[nl][lane] = x[(size_t)n * 64 + lane];
            const float inv = 1.0f / fmaxf(counts[n], 1.0f);
            s_in[nl][64 + lane] = summed[(size_t)n * 64 + lane] * inv;
        } else {
            s_in[nl][lane] = 0.f; s_in[nl][64 + lane] = 0.f;
        }
    }
    __syncthreads();

    float acc1[4][4];
    {
        const int cg = tid & 31;
        const int er = tid >> 5;
        const float4 bb = *(const float4*)(b3 + 4 * cg);
        #pragma unroll
        for (int t = 0; t < 4; ++t) {
            acc1[t][0] = bb.x; acc1[t][1] = bb.y; acc1[t][2] = bb.z; acc1[t][3] = bb.w;
        }
        for (int k = 0; k < 128; k += 4) {
            float wv4[4][4];
            #pragma unroll
            for (int kk = 0; kk < 4; ++kk) {
                const float4 w = *(const float4*)(W3 + (size_t)(k + kk) * 128 + 4 * cg);
                wv4[kk][0] = w.x; wv4[kk][1] = w.y; wv4[kk][2] = w.z; wv4[kk][3] = w.w;
            }
            #pragma unroll
            for (int t = 0; t < 4; ++t) {
                const float4 m = *(const float4*)(&s_in[er + 8 * t][k]);
                const float mm[4] = {m.x, m.y, m.z, m.w};
                #pragma unroll
                for (int kk = 0; kk < 4; ++kk)
                    #pragma unroll
                    for (int cc = 0; cc < 4; ++cc)
                        acc1[t][cc] += mm[kk] * wv4[kk][cc];
            }
        }
    }
    __syncthreads();
    {
        const int cg = tid & 31;
        const int er = tid >> 5;
        #pragma unroll
        for (int t = 0; t < 4; ++t)
            #pragma unroll
            for (int cc = 0; cc < 4; ++cc)
                s_in[er + 8 * t][4 * cg + cc] = fmaxf(acc1[t][cc], 0.f);
    }
    __syncthreads();
    {
        const int cg = tid & 15;
        const int er = tid >> 4;
        float acc[2][4];
        const float4 bb = *(const float4*)(b4 + 4 * cg);
        #pragma unroll
        for (int t = 0; t < 2; ++t) {
            acc[t][0] = bb.x; acc[t][1] = bb.y; acc[t][2] = bb.z; acc[t][3] = bb.w;
        }
        for (int k = 0; k < 128; k += 4) {
            float wv4[4][4];
            #pragma unroll
            for (int kk = 0; kk < 4; ++kk) {
                const float4 w = *(const float4*)(W4 + (size_t)(k + kk) * 64 + 4 * cg);
                wv4[kk][0] = w.x; wv4[kk][1] = w.y; wv4[kk][2] = w.z; wv4[kk][3] = w.w;
            }
            #pragma unroll
            for (int t = 0; t < 2; ++t) {
                const float4 m = *(const float4*)(&s_in[er + 16 * t][k]);
                const float mm[4] = {m.x, m.y, m.z, m.w};
                #pragma unroll
                for (int kk = 0; kk < 4; ++kk)
                    #pragma unroll
                    for (int cc = 0; cc < 4; ++cc)
                        acc[t][cc] += mm[kk] * wv4[kk][cc];
            }
        }
        #pragma unroll
        for (int t = 0; t < 2; ++t) {
            const int n = base + er + 16 * t;
            if (n < N) {
                float4 o;
                o.x = acc[t][0]; o.y = acc[t][1]; o.z = acc[t][2]; o.w = acc[t][3];
                *(float4*)(out + (size_t)n * 64 + 4 * cg) = o;
            }
        }
    }
}

// ---------------- launch ----------------

static inline size_t rup(size_t v) { return (v + 255) & ~(size_t)255; }

extern "C" void kernel_launch(void* const* d_in, const int* in_sizes, int n_in,
                              void* d_out, int out_size, void* d_ws, size_t ws_size,
                              hipStream_t stream) {
    const float* x    = (const float*)d_in[0];
    const float* pos  = (const float*)d_in[1];
    const int*   eidx = (const int*)d_in[2];
    const float* W1   = (const float*)d_in[3];
    const float* b1   = (const float*)d_in[4];
    const float* W2   = (const float*)d_in[5];
    const float* b2   = (const float*)d_in[6];
    const float* W3   = (const float*)d_in[7];
    const float* b3   = (const float*)d_in[8];
    const float* W4   = (const float*)d_in[9];
    const float* b4   = (const float*)d_in[10];

    const int N = in_sizes[0] / 64;
    const int E = in_sizes[2] / 2;
    const int* ei0 = eidx;       // edge_index[0] = aggregation node i
    const int* ei1 = eidx + E;   // edge_index[1] = neighbor j

    const size_t p_b    = rup((size_t)N * 128 * 2);
    const size_t q_b    = rup((size_t)N * 128 * 2);
    const size_t wcp_b  = rup(48 * 512 * 2);
    const size_t w2p_b  = rup(16 * 512 * 2);
    const size_t w3p_b  = rup(32 * 512 * 2);
    const size_t w4p_b  = rup(16 * 512 * 2);
    const size_t aggr_b = rup((size_t)N * 64 * 4);
    const size_t cnt_b  = rup((size_t)N * 4);
    const size_t off_b  = rup((size_t)(N + 1) * 4);
    const size_t bsum_b = rup(256 * 4);
    const size_t rank_b = rup((size_t)E * 4);
    const size_t eij_b  = rup((size_t)E * 8);
    const size_t need = p_b + q_b + wcp_b + w2p_b + w3p_b + w4p_b +
                        aggr_b + cnt_b + off_b + bsum_b + rank_b + eij_b;

    if (ws_size >= need) {
        char* p = (char*)d_ws;
        unsigned short* P   = (unsigned short*)p;  p += p_b;
        unsigned short* Q   = (unsigned short*)p;  p += q_b;
        unsigned short* Wcp = (unsigned short*)p;  p += wcp_b;
        unsigned short* W2p = (unsigned short*)p;  p += w2p_b;
        unsigned short* W3p = (unsigned short*)p;  p += w3p_b;
        unsigned short* W4p = (unsigned short*)p;  p += w4p_b;
        float* aggr = (float*)p;  p += aggr_b;
        int* cnt  = (int*)p;  p += cnt_b;
        int* off  = (int*)p;  p += off_b;
        int* bsum = (int*)p;  p += bsum_b;
        int* rank = (int*)p;  p += rank_b;
        int2* eij = (int2*)p;

        // zero aggr + cnt in one shot (adjacent)
        hipMemsetAsync(aggr, 0, aggr_b + cnt_b, stream);

        // K1: pack (28 blocks) U count (3125 blocks) U bsum sentinels
        const int cntBlocks = (E + 255) / 256;
        prep_kernel<<<28 + cntBlocks, 256, 0, stream>>>(
            W1, W2, W3, W4, Wcp, W2p, W3p, W4p, ei0, cnt, rank, bsum, E);

        // K2: pq (782 blocks) U lookback scan (196 blocks)
        const int pqBlocks   = (N + NPB - 1) / NPB;
        const int scanBlocks = (N + 255) / 256;
        pq_scan_kernel<<<pqBlocks + scanBlocks, 256, 0, stream>>>(
            x, pos, Wcp, b1, P, Q, cnt, bsum, off, N, E);

        // K3: fill
        fill_kernel<<<cntBlocks, 256, 0, stream>>>(ei0, ei1, off, rank, eij, E);

        // K4: edge (grid padded to x8 for XCD-contiguous swizzle)
        const int edgeBlocks = ((E + EPB - 1) / EPB + 7) & ~7;
        edge_aggr_mfma<<<edgeBlocks, 256, 0, stream>>>(
            P, Q, eij, W2p, b2, aggr, E);

        // K5: node
        node_mlp_mfma<<<pqBlocks, 256, 0, stream>>>(
            x, aggr, off, W3p, b3, W4p, b4, (float*)d_out, N);
    } else {
        // fallback: atomic fp32 path
        float* summed = (float*)d_ws;
        float* counts = summed + (size_t)N * 64;
        hipMemsetAsync(d_ws, 0, ((size_t)N * 64 + N) * sizeof(float), stream);

        mpnn_edge_atomic_kernel<<<(E + EB - 1) / EB, 256, 0, stream>>>(
            x, pos, ei0, ei1, W1, b1, W2, b2, summed, counts, E);
        mpnn_node_legacy_kernel<<<(N + NB - 1) / NB, 256, 0, stream>>>(
            x, summed, counts, W3, b3, W4, b4, (float*)d_out, N);
    }
}